// Round 1
// baseline (15642.632 us; speedup 1.0000x reference)
//
#include <hip/hip_runtime.h>
#include <hip/hip_bf16.h>

// ---------------------------------------------------------------------------
// Constants for this problem instance
//   B=4, L=1024, E=512, H=8, NL=2, M=2048, S=256, R=2, Dh=64
// ---------------------------------------------------------------------------

#define NEGF -3.4028235e38f

// ---------------------------------------------------------------------------
// GEMM: C[M,N] = epi(A[M,K] @ W[K,N])
//   val = (acc + bias[n]) * alpha; if(gelu) val = gelu_exact(val);
//   if(res) val += res[m,n];
// fp32, 64x64 tile, 4x4 microtile, BK=16
// ---------------------------------------------------------------------------
__global__ __launch_bounds__(256) void gemm_f32(
    const float* __restrict__ A, const float* __restrict__ W,
    const float* __restrict__ bias, const float* __restrict__ res,
    float* __restrict__ C, int M, int N, int K, float alpha, int gelu_flag)
{
    __shared__ float As[16][64];   // As[k][m]
    __shared__ float Bs[16][64];   // Bs[k][n]
    const int bm = blockIdx.y * 64;
    const int bn = blockIdx.x * 64;
    const int tid = threadIdx.x;
    const int tx = tid & 15;       // 0..15 -> n
    const int ty = tid >> 4;       // 0..15 -> m
    float acc[4][4] = {};

    for (int k0 = 0; k0 < K; k0 += 16) {
        // A tile: 64 rows x 16 k, 1024 elems, 4 per thread
        #pragma unroll
        for (int i = 0; i < 4; ++i) {
            int idx = tid + i * 256;
            int r = idx >> 4;          // 0..63
            int c = idx & 15;          // 0..15
            int gm = bm + r;
            As[c][r] = (gm < M) ? A[(size_t)gm * K + k0 + c] : 0.f;
        }
        // B tile: 16 k x 64 n
        #pragma unroll
        for (int i = 0; i < 4; ++i) {
            int idx = tid + i * 256;
            int r = idx >> 6;          // 0..15
            int c = idx & 63;          // 0..63
            int gn = bn + c;
            Bs[r][c] = (gn < N) ? W[(size_t)(k0 + r) * N + gn] : 0.f;
        }
        __syncthreads();
        #pragma unroll
        for (int kk = 0; kk < 16; ++kk) {
            float a[4], b[4];
            #pragma unroll
            for (int i = 0; i < 4; ++i) a[i] = As[kk][ty * 4 + i];
            #pragma unroll
            for (int j = 0; j < 4; ++j) b[j] = Bs[kk][tx * 4 + j];
            #pragma unroll
            for (int i = 0; i < 4; ++i)
                #pragma unroll
                for (int j = 0; j < 4; ++j)
                    acc[i][j] = fmaf(a[i], b[j], acc[i][j]);
        }
        __syncthreads();
    }

    #pragma unroll
    for (int i = 0; i < 4; ++i) {
        int gm = bm + ty * 4 + i;
        if (gm >= M) continue;
        #pragma unroll
        for (int j = 0; j < 4; ++j) {
            int gn = bn + tx * 4 + j;
            if (gn >= N) continue;
            float v = acc[i][j] + (bias ? bias[gn] : 0.f);
            v *= alpha;
            if (gelu_flag) v = 0.5f * v * (1.0f + erff(v * 0.70710678118654752f));
            if (res) v += res[(size_t)gm * N + gn];
            C[(size_t)gm * N + gn] = v;
        }
    }
}

// ---------------------------------------------------------------------------
// LayerNorm: Y[row] = LN(X[row] (+ X2[row])) * s + b; optional FiLM:
//   Y = fa[batch]*Y + fb[batch],  film layout (B, 2D): [fa | fb]
// One block (256 threads) per row.
// ---------------------------------------------------------------------------
__global__ __launch_bounds__(256) void ln_kernel(
    const float* __restrict__ X, const float* __restrict__ X2,
    const float* __restrict__ s, const float* __restrict__ b,
    float* __restrict__ Y, int D, const float* __restrict__ film,
    int rows_per_batch)
{
    const int row = blockIdx.x;
    const int tid = threadIdx.x;
    const float* x = X + (size_t)row * D;
    const float* x2 = X2 ? X2 + (size_t)row * D : nullptr;

    float sum = 0.f, sq = 0.f;
    for (int c = tid; c < D; c += 256) {
        float v = x[c] + (x2 ? x2[c] : 0.f);
        sum += v; sq += v * v;
    }
    __shared__ float r1[4], r2[4];
    __shared__ float s_mean, s_rstd;
    for (int off = 32; off > 0; off >>= 1) {
        sum += __shfl_down(sum, off);
        sq  += __shfl_down(sq,  off);
    }
    if ((tid & 63) == 0) { r1[tid >> 6] = sum; r2[tid >> 6] = sq; }
    __syncthreads();
    if (tid == 0) {
        float ts = r1[0] + r1[1] + r1[2] + r1[3];
        float tq = r2[0] + r2[1] + r2[2] + r2[3];
        float mean = ts / (float)D;
        float var = tq / (float)D - mean * mean;
        s_mean = mean;
        s_rstd = rsqrtf(var + 1e-5f);
    }
    __syncthreads();
    const float mean = s_mean, rstd = s_rstd;
    const float* fa = nullptr; const float* fb = nullptr;
    if (film) {
        int batch = row / rows_per_batch;
        fa = film + (size_t)batch * 2 * D;
        fb = fa + D;
    }
    for (int c = tid; c < D; c += 256) {
        float v = x[c] + (x2 ? x2[c] : 0.f);
        float y = (v - mean) * rstd * s[c] + b[c];
        if (film) y = fa[c] * y + fb[c];
        Y[(size_t)row * D + c] = y;
    }
}

// ---------------------------------------------------------------------------
// t-embedding: temb[b, i<256] = sin(t[b]*f_i), temb[b, 256+i] = cos(t[b]*f_i)
//   f_i = exp(i * -ln(10000)/255)
// ---------------------------------------------------------------------------
__global__ void temb_kernel(const float* __restrict__ t, float* __restrict__ temb)
{
    int b = blockIdx.x;
    int i = threadIdx.x;   // 256 threads
    float f = expf((float)i * (-9.210340371976184f / 255.0f));
    float a = t[b] * f;
    temb[b * 512 + i]       = sinf(a);
    temb[b * 512 + 256 + i] = cosf(a);
}

// ---------------------------------------------------------------------------
// Build h0 for both directions with sinusoidal posenc added.
// d=0: pos0 = temb, pos i = embed[x[b][i-1]];  d=1: pos L-1 = temb, pos i = embed[x[b][i+1]]
// pe[i, 2j] = sin(i * exp(2j * -ln(10000)/512)), pe[i,2j+1] = cos(same)
// ---------------------------------------------------------------------------
__global__ void embed_kernel(const int* __restrict__ x, const float* __restrict__ temb,
                             const float* __restrict__ embed,
                             float* __restrict__ l2r, float* __restrict__ r2l)
{
    const int i = blockIdx.x;      // 0..1023
    const int b = blockIdx.y;      // 0..3
    const int d = blockIdx.z;      // 0..1
    float* out = (d == 0 ? l2r : r2l) + ((size_t)(b * 1024 + i) * 512);
    const float* src;
    if (d == 0) src = (i == 0)    ? temb + b * 512 : embed + (size_t)x[b * 1024 + (i - 1)] * 512;
    else        src = (i == 1023) ? temb + b * 512 : embed + (size_t)x[b * 1024 + (i + 1)] * 512;
    for (int e = threadIdx.x; e < 512; e += 256) {
        int j = e >> 1;
        float div = expf((float)(2 * j) * (-9.210340371976184f / 512.0f));
        float ang = (float)i * div;
        float pe = (e & 1) ? cosf(ang) : sinf(ang);
        out[e] = src[e] + pe;
    }
}

__global__ void add_kernel(const float* __restrict__ A, const float* __restrict__ B,
                           float* __restrict__ C, int n)
{
    int i = blockIdx.x * blockDim.x + threadIdx.x;
    int stride = gridDim.x * blockDim.x;
    for (; i < n; i += stride) C[i] = A[i] + B[i];
}

// allv[b, 0] = temb[b]; allv[b, 1+i] = l2rn[b,i]; allv[b, 1025+i] = r2ln[b,i]
__global__ void build_allv(const float* __restrict__ temb, const float* __restrict__ l2rn,
                           const float* __restrict__ r2ln, float* __restrict__ allv)
{
    const int k = blockIdx.x;  // 0..2048
    const int b = blockIdx.y;
    float* out = allv + ((size_t)b * 2049 + k) * 512;
    const float* src;
    if (k == 0)        src = temb + b * 512;
    else if (k <= 1024) src = l2rn + ((size_t)(b * 1024 + (k - 1)) * 512);
    else               src = r2ln + ((size_t)(b * 1024 + (k - 1025)) * 512);
    for (int e = threadIdx.x; e < 512; e += 256) out[e] = src[e];
}

// ---------------------------------------------------------------------------
// Self-attention, per (b,h,q) block. L=1024 keys, Dh=64.
// dir=0: valid k <= q ; dir=1: valid k >= q
// Q,K,V,O layout: (B, L, E) with head h at cols [h*64, h*64+64)
// Q is pre-scaled by 1/8.
// ---------------------------------------------------------------------------
__global__ __launch_bounds__(256) void attn_self(
    const float* __restrict__ Q, const float* __restrict__ K,
    const float* __restrict__ V, float* __restrict__ O, int dir)
{
    const int L = 1024, E = 512;
    const int q = blockIdx.x, h = blockIdx.y, b = blockIdx.z;
    const int tid = threadIdx.x;
    __shared__ float qv[64];
    __shared__ float sc[1024];
    __shared__ float red[4];
    __shared__ float ored[4][64];
    __shared__ float s_mx, s_sum;

    const float* qp = Q + ((size_t)(b * L + q) * E) + h * 64;
    if (tid < 64) qv[tid] = qp[tid];
    __syncthreads();

    for (int k = tid; k < L; k += 256) {
        bool valid = (dir == 0) ? (k <= q) : (k >= q);
        float dot = NEGF;
        if (valid) {
            const float* kp = K + ((size_t)(b * L + k) * E) + h * 64;
            float acc = 0.f;
            #pragma unroll
            for (int d0 = 0; d0 < 64; d0 += 4) {
                float4 kk = *(const float4*)(kp + d0);
                acc = fmaf(qv[d0 + 0], kk.x, acc);
                acc = fmaf(qv[d0 + 1], kk.y, acc);
                acc = fmaf(qv[d0 + 2], kk.z, acc);
                acc = fmaf(qv[d0 + 3], kk.w, acc);
            }
            dot = acc;
        }
        sc[k] = dot;
    }
    __syncthreads();

    float mx = NEGF;
    for (int k = tid; k < L; k += 256) mx = fmaxf(mx, sc[k]);
    for (int off = 32; off > 0; off >>= 1) mx = fmaxf(mx, __shfl_down(mx, off));
    if ((tid & 63) == 0) red[tid >> 6] = mx;
    __syncthreads();
    if (tid == 0) s_mx = fmaxf(fmaxf(red[0], red[1]), fmaxf(red[2], red[3]));
    __syncthreads();
    mx = s_mx;

    float sum = 0.f;
    for (int k = tid; k < L; k += 256) {
        float p = expf(sc[k] - mx);
        sc[k] = p;
        sum += p;
    }
    for (int off = 32; off > 0; off >>= 1) sum += __shfl_down(sum, off);
    __syncthreads();
    if ((tid & 63) == 0) red[tid >> 6] = sum;
    __syncthreads();
    if (tid == 0) s_sum = red[0] + red[1] + red[2] + red[3];
    __syncthreads();
    const float inv = 1.f / s_sum;

    const int lane = tid & 63, grp = tid >> 6;
    float o = 0.f;
    for (int k = grp; k < L; k += 4)
        o = fmaf(sc[k], V[((size_t)(b * L + k) * E) + h * 64 + lane], o);
    ored[grp][lane] = o;
    __syncthreads();
    if (tid < 64) {
        float r = (ored[0][tid] + ored[1][tid] + ored[2][tid] + ored[3][tid]) * inv;
        O[((size_t)(b * L + q) * E) + h * 64 + tid] = r;
    }
}

// ---------------------------------------------------------------------------
// Cross-attention, per (b,h,q). 2049 keys.
// mask: k==0 valid; k in [1,1024]: (k-1) > q; k in [1025,2048]: (k-1025) < q
// K2,V2 layout: (B, 2049, E)
// ---------------------------------------------------------------------------
__global__ __launch_bounds__(256) void attn_cross(
    const float* __restrict__ Q, const float* __restrict__ K2,
    const float* __restrict__ V2, float* __restrict__ O)
{
    const int L = 1024, E = 512, LK = 2049;
    const int q = blockIdx.x, h = blockIdx.y, b = blockIdx.z;
    const int tid = threadIdx.x;
    __shared__ float qv[64];
    __shared__ float sc[2049];
    __shared__ float red[4];
    __shared__ float ored[4][64];
    __shared__ float s_mx, s_sum;

    const float* qp = Q + ((size_t)(b * L + q) * E) + h * 64;
    if (tid < 64) qv[tid] = qp[tid];
    __syncthreads();

    for (int k = tid; k < LK; k += 256) {
        bool valid;
        if (k == 0) valid = true;
        else if (k <= 1024) valid = (k - 1) > q;
        else valid = (k - 1025) < q;
        float dot = NEGF;
        if (valid) {
            const float* kp = K2 + ((size_t)(b * LK + k) * E) + h * 64;
            float acc = 0.f;
            #pragma unroll
            for (int d0 = 0; d0 < 64; d0 += 4) {
                float4 kk = *(const float4*)(kp + d0);
                acc = fmaf(qv[d0 + 0], kk.x, acc);
                acc = fmaf(qv[d0 + 1], kk.y, acc);
                acc = fmaf(qv[d0 + 2], kk.z, acc);
                acc = fmaf(qv[d0 + 3], kk.w, acc);
            }
            dot = acc;
        }
        sc[k] = dot;
    }
    __syncthreads();

    float mx = NEGF;
    for (int k = tid; k < LK; k += 256) mx = fmaxf(mx, sc[k]);
    for (int off = 32; off > 0; off >>= 1) mx = fmaxf(mx, __shfl_down(mx, off));
    if ((tid & 63) == 0) red[tid >> 6] = mx;
    __syncthreads();
    if (tid == 0) s_mx = fmaxf(fmaxf(red[0], red[1]), fmaxf(red[2], red[3]));
    __syncthreads();
    mx = s_mx;

    float sum = 0.f;
    for (int k = tid; k < LK; k += 256) {
        float p = expf(sc[k] - mx);
        sc[k] = p;
        sum += p;
    }
    for (int off = 32; off > 0; off >>= 1) sum += __shfl_down(sum, off);
    __syncthreads();
    if ((tid & 63) == 0) red[tid >> 6] = sum;
    __syncthreads();
    if (tid == 0) s_sum = red[0] + red[1] + red[2] + red[3];
    __syncthreads();
    const float inv = 1.f / s_sum;

    const int lane = tid & 63, grp = tid >> 6;
    float o = 0.f;
    for (int k = grp; k < LK; k += 4)
        o = fmaf(sc[k], V2[((size_t)(b * LK + k) * E) + h * 64 + lane], o);
    ored[grp][lane] = o;
    __syncthreads();
    if (tid < 64) {
        float r = (ored[0][tid] + ored[1][tid] + ored[2][tid] + ored[3][tid]) * inv;
        O[((size_t)(b * L + q) * E) + h * 64 + tid] = r;
    }
}

// ---------------------------------------------------------------------------

static inline void gemm(hipStream_t st, const float* A, const float* W, const float* bias,
                        const float* res, float* C, int M, int N, int K,
                        float alpha, int gelu)
{
    dim3 g((N + 63) / 64, (M + 63) / 64);
    gemm_f32<<<g, dim3(256), 0, st>>>(A, W, bias, res, C, M, N, K, alpha, gelu);
}

extern "C" void kernel_launch(void* const* d_in, const int* in_sizes, int n_in,
                              void* d_out, int out_size, void* d_ws, size_t ws_size,
                              hipStream_t stream)
{
    const int*   x      = (const int*)  d_in[0];
    const float* t      = (const float*)d_in[1];
    const float* embedW = (const float*)d_in[2];
    const float* attn_W = (const float*)d_in[3];
    const float* attn_b = (const float*)d_in[4];
    const float* ln_s   = (const float*)d_in[5];
    const float* ln_b   = (const float*)d_in[6];
    const float* mlp_W1 = (const float*)d_in[7];
    const float* mlp_b1 = (const float*)d_in[8];
    const float* mlp_W2 = (const float*)d_in[9];
    const float* mlp_b2 = (const float*)d_in[10];
    const float* ca_Wq  = (const float*)d_in[11];
    const float* ca_Wk  = (const float*)d_in[12];
    const float* ca_bk  = (const float*)d_in[13];
    const float* ca_Wv  = (const float*)d_in[14];
    const float* ca_bv  = (const float*)d_in[15];
    const float* ca_Wo  = (const float*)d_in[16];
    const float* ca_bo  = (const float*)d_in[17];
    const float* ro1s   = (const float*)d_in[18];
    const float* ro1b   = (const float*)d_in[19];
    const float* ro2s   = (const float*)d_in[20];
    const float* ro2b   = (const float*)d_in[21];
    const float* in_W   = (const float*)d_in[22];
    const float* in_b   = (const float*)d_in[23];
    const float* tm_W1  = (const float*)d_in[24];
    const float* tm_b1  = (const float*)d_in[25];
    const float* tm_W2  = (const float*)d_in[26];
    const float* tm_b2  = (const float*)d_in[27];
    const float* res_W1 = (const float*)d_in[28];
    const float* res_b1 = (const float*)d_in[29];
    const float* res_W2 = (const float*)d_in[30];
    const float* res_b2 = (const float*)d_in[31];
    const float* rls    = (const float*)d_in[32];
    const float* rlb    = (const float*)d_in[33];
    const float* film_W = (const float*)d_in[34];
    const float* film_b = (const float*)d_in[35];
    const float* out_W  = (const float*)d_in[36];
    const float* out_b  = (const float*)d_in[37];
    float* out = (float*)d_out;
    float* ws  = (float*)d_ws;

    // ---- workspace layout (floats) ----
    const size_t SZ_BLE  = 4u * 1024u * 512u;          // 2,097,152
    const size_t SZ_ALLV = 4u * 2049u * 512u;          // 4,196,352
    const size_t SZ_BL2E = 4u * 1024u * 1024u;         // 4,194,304
    size_t o = 0;
    float* TEMB = ws + o; o += 2048;
    float* T4   = ws + o; o += 8192;
    float* TM1  = ws + o; o += 8192;
    float* FILM = ws + o; o += 8192;
    o = 32768;
    float* L2R  = ws + o; o += SZ_BLE;
    float* R2L  = ws + o; o += SZ_BLE;
    float* Z    = ws + o; o += SZ_BLE;
    float* QB   = ws + o; o += SZ_BLE;
    float* KB   = ws + o; o += SZ_BLE;
    float* VB   = ws + o; o += SZ_BLE;
    float* OB   = ws + o; o += SZ_BLE;
    float* MID  = ws + o; o += 2 * SZ_ALLV;  // also holds ALLV | K2 during readout
    float* V2   = ws + o; o += SZ_ALLV;
    float* H2   = ws + o; o += SZ_BL2E;
    float* Z2   = ws + o; o += SZ_BL2E;
    float* ALLV = MID;
    float* K2   = MID + SZ_ALLV;
    (void)ws_size; (void)in_sizes; (void)n_in; (void)out_size;

    // ---- embeddings ----
    temb_kernel<<<dim3(4), dim3(256), 0, stream>>>(t, TEMB);
    embed_kernel<<<dim3(1024, 4, 2), dim3(256), 0, stream>>>(x, TEMB, embedW, L2R, R2L);

    // ---- transformer blocks ----
    for (int d = 0; d < 2; ++d) {
        float* h = (d == 0) ? L2R : R2L;
        for (int l = 0; l < 2; ++l) {
            const int dl = d * 2 + l;
            ln_kernel<<<4096, 256, 0, stream>>>(h, nullptr, ln_s + (dl * 2 + 0) * 512,
                                                ln_b + (dl * 2 + 0) * 512, Z, 512, nullptr, 1024);
            gemm(stream, Z, attn_W + (size_t)(dl * 4 + 0) * 262144, attn_b + (dl * 4 + 0) * 512,
                 nullptr, QB, 4096, 512, 512, 0.125f, 0);
            gemm(stream, Z, attn_W + (size_t)(dl * 4 + 1) * 262144, attn_b + (dl * 4 + 1) * 512,
                 nullptr, KB, 4096, 512, 512, 1.f, 0);
            gemm(stream, Z, attn_W + (size_t)(dl * 4 + 2) * 262144, attn_b + (dl * 4 + 2) * 512,
                 nullptr, VB, 4096, 512, 512, 1.f, 0);
            attn_self<<<dim3(1024, 8, 4), dim3(256), 0, stream>>>(QB, KB, VB, OB, d);
            gemm(stream, OB, attn_W + (size_t)(dl * 4 + 3) * 262144, attn_b + (dl * 4 + 3) * 512,
                 h, h, 4096, 512, 512, 1.f, 0);
            ln_kernel<<<4096, 256, 0, stream>>>(h, nullptr, ln_s + (dl * 2 + 1) * 512,
                                                ln_b + (dl * 2 + 1) * 512, Z, 512, nullptr, 1024);
            gemm(stream, Z, mlp_W1 + (size_t)dl * 1048576, mlp_b1 + dl * 2048,
                 nullptr, MID, 4096, 2048, 512, 1.f, 1);
            gemm(stream, MID, mlp_W2 + (size_t)dl * 1048576, mlp_b2 + dl * 512,
                 h, h, 4096, 512, 2048, 1.f, 0);
        }
    }

    // ---- readout / cross-attention ----
    add_kernel<<<2048, 256, 0, stream>>>(L2R, R2L, Z, (int)SZ_BLE);              // inputs
    ln_kernel<<<4096, 256, 0, stream>>>(L2R, nullptr, ro1s, ro1b, QB, 512, nullptr, 1024); // l2r_n
    ln_kernel<<<4096, 256, 0, stream>>>(R2L, nullptr, ro2s, ro2b, KB, 512, nullptr, 1024); // r2l_n
    add_kernel<<<2048, 256, 0, stream>>>(QB, KB, VB, (int)SZ_BLE);               // l2r_n + r2l_n
    build_allv<<<dim3(2049, 4), dim3(256), 0, stream>>>(TEMB, QB, KB, ALLV);
    gemm(stream, VB, ca_Wq, nullptr, nullptr, OB, 4096, 512, 512, 0.125f, 0);    // q
    gemm(stream, ALLV, ca_Wk, ca_bk, nullptr, K2, 8196, 512, 512, 1.f, 0);
    gemm(stream, ALLV, ca_Wv, ca_bv, nullptr, V2, 8196, 512, 512, 1.f, 0);
    attn_cross<<<dim3(1024, 8, 4), dim3(256), 0, stream>>>(OB, K2, V2, L2R);     // xat -> L2R
    gemm(stream, L2R, ca_Wo, ca_bo, Z, R2L, 4096, 512, 512, 1.f, 0);             // + inputs

    // ---- t-MLP ----
    gemm(stream, TEMB, tm_W1, tm_b1, nullptr, TM1, 4, 2048, 512, 1.f, 1);
    gemm(stream, TM1, tm_W2, tm_b2, nullptr, T4, 4, 2048, 2048, 1.f, 0);

    // ---- residual FiLM blocks ----
    gemm(stream, R2L, in_W, in_b, nullptr, H2, 4096, 1024, 512, 1.f, 0);
    for (int i = 0; i < 2; ++i) {
        gemm(stream, T4, film_W + (size_t)i * 4194304, film_b + i * 2048,
             nullptr, FILM, 4, 2048, 2048, 1.f, 0);
        gemm(stream, H2, res_W1 + (size_t)i * 2097152, res_b1 + i * 2048,
             nullptr, MID, 4096, 2048, 1024, 1.f, 1);
        gemm(stream, MID, res_W2 + (size_t)i * 2097152, res_b2 + i * 1024,
             nullptr, Z2, 4096, 1024, 2048, 1.f, 0);
        ln_kernel<<<4096, 256, 0, stream>>>(H2, Z2, rls + i * 1024, rlb + i * 1024,
                                            H2, 1024, FILM, 1024);
    }

    // ---- output projection ----
    gemm(stream, H2, out_W, out_b, nullptr, out, 4096, 256, 1024, 1.f, 0);
}

// Round 2
// 6627.763 us; speedup vs baseline: 2.3602x; 2.3602x over previous
//
#include <hip/hip_runtime.h>
#include <hip/hip_bf16.h>

// ---------------------------------------------------------------------------
// B=4, L=1024, E=512, H=8, NL=2, M=2048, S=256, R=2, Dh=64
// ---------------------------------------------------------------------------

#define NEGF -3.4028235e38f

// ---------------------------------------------------------------------------
// GEMM: C[M,N] = epi(A[M,K] @ W[K,N])  (fp32, 64x64 tile, 4x4 microtile)
// ---------------------------------------------------------------------------
__global__ __launch_bounds__(256) void gemm_f32(
    const float* __restrict__ A, const float* __restrict__ W,
    const float* __restrict__ bias, const float* __restrict__ res,
    float* __restrict__ C, int M, int N, int K, float alpha, int gelu_flag)
{
    __shared__ float As[16][64];
    __shared__ float Bs[16][64];
    const int bm = blockIdx.y * 64;
    const int bn = blockIdx.x * 64;
    const int tid = threadIdx.x;
    const int tx = tid & 15;
    const int ty = tid >> 4;
    float acc[4][4] = {};

    for (int k0 = 0; k0 < K; k0 += 16) {
        #pragma unroll
        for (int i = 0; i < 4; ++i) {
            int idx = tid + i * 256;
            int r = idx >> 4;
            int c = idx & 15;
            int gm = bm + r;
            As[c][r] = (gm < M) ? A[(size_t)gm * K + k0 + c] : 0.f;
        }
        #pragma unroll
        for (int i = 0; i < 4; ++i) {
            int idx = tid + i * 256;
            int r = idx >> 6;
            int c = idx & 63;
            int gn = bn + c;
            Bs[r][c] = (gn < N) ? W[(size_t)(k0 + r) * N + gn] : 0.f;
        }
        __syncthreads();
        #pragma unroll
        for (int kk = 0; kk < 16; ++kk) {
            float a[4], b[4];
            #pragma unroll
            for (int i = 0; i < 4; ++i) a[i] = As[kk][ty * 4 + i];
            #pragma unroll
            for (int j = 0; j < 4; ++j) b[j] = Bs[kk][tx * 4 + j];
            #pragma unroll
            for (int i = 0; i < 4; ++i)
                #pragma unroll
                for (int j = 0; j < 4; ++j)
                    acc[i][j] = fmaf(a[i], b[j], acc[i][j]);
        }
        __syncthreads();
    }

    #pragma unroll
    for (int i = 0; i < 4; ++i) {
        int gm = bm + ty * 4 + i;
        if (gm >= M) continue;
        #pragma unroll
        for (int j = 0; j < 4; ++j) {
            int gn = bn + tx * 4 + j;
            if (gn >= N) continue;
            float v = acc[i][j] + (bias ? bias[gn] : 0.f);
            v *= alpha;
            if (gelu_flag) v = 0.5f * v * (1.0f + erff(v * 0.70710678118654752f));
            if (res) v += res[(size_t)gm * N + gn];
            C[(size_t)gm * N + gn] = v;
        }
    }
}

// ---------------------------------------------------------------------------
// LayerNorm (+optional add, +optional FiLM)
// ---------------------------------------------------------------------------
__global__ __launch_bounds__(256) void ln_kernel(
    const float* __restrict__ X, const float* __restrict__ X2,
    const float* __restrict__ s, const float* __restrict__ b,
    float* __restrict__ Y, int D, const float* __restrict__ film,
    int rows_per_batch)
{
    const int row = blockIdx.x;
    const int tid = threadIdx.x;
    const float* x = X + (size_t)row * D;
    const float* x2 = X2 ? X2 + (size_t)row * D : nullptr;

    float sum = 0.f, sq = 0.f;
    for (int c = tid; c < D; c += 256) {
        float v = x[c] + (x2 ? x2[c] : 0.f);
        sum += v; sq += v * v;
    }
    __shared__ float r1[4], r2[4];
    __shared__ float s_mean, s_rstd;
    for (int off = 32; off > 0; off >>= 1) {
        sum += __shfl_down(sum, off);
        sq  += __shfl_down(sq,  off);
    }
    if ((tid & 63) == 0) { r1[tid >> 6] = sum; r2[tid >> 6] = sq; }
    __syncthreads();
    if (tid == 0) {
        float ts = r1[0] + r1[1] + r1[2] + r1[3];
        float tq = r2[0] + r2[1] + r2[2] + r2[3];
        float mean = ts / (float)D;
        float var = tq / (float)D - mean * mean;
        s_mean = mean;
        s_rstd = rsqrtf(var + 1e-5f);
    }
    __syncthreads();
    const float mean = s_mean, rstd = s_rstd;
    const float* fa = nullptr; const float* fb = nullptr;
    if (film) {
        int batch = row / rows_per_batch;
        fa = film + (size_t)batch * 2 * D;
        fb = fa + D;
    }
    for (int c = tid; c < D; c += 256) {
        float v = x[c] + (x2 ? x2[c] : 0.f);
        float y = (v - mean) * rstd * s[c] + b[c];
        if (film) y = fa[c] * y + fb[c];
        Y[(size_t)row * D + c] = y;
    }
}

__global__ void temb_kernel(const float* __restrict__ t, float* __restrict__ temb)
{
    int b = blockIdx.x;
    int i = threadIdx.x;
    float f = expf((float)i * (-9.210340371976184f / 255.0f));
    float a = t[b] * f;
    temb[b * 512 + i]       = sinf(a);
    temb[b * 512 + 256 + i] = cosf(a);
}

__global__ void embed_kernel(const int* __restrict__ x, const float* __restrict__ temb,
                             const float* __restrict__ embed,
                             float* __restrict__ l2r, float* __restrict__ r2l)
{
    const int i = blockIdx.x;
    const int b = blockIdx.y;
    const int d = blockIdx.z;
    float* out = (d == 0 ? l2r : r2l) + ((size_t)(b * 1024 + i) * 512);
    const float* src;
    if (d == 0) src = (i == 0)    ? temb + b * 512 : embed + (size_t)x[b * 1024 + (i - 1)] * 512;
    else        src = (i == 1023) ? temb + b * 512 : embed + (size_t)x[b * 1024 + (i + 1)] * 512;
    for (int e = threadIdx.x; e < 512; e += 256) {
        int j = e >> 1;
        float div = expf((float)(2 * j) * (-9.210340371976184f / 512.0f));
        float ang = (float)i * div;
        float pe = (e & 1) ? cosf(ang) : sinf(ang);
        out[e] = src[e] + pe;
    }
}

__global__ void add_kernel(const float* __restrict__ A, const float* __restrict__ B,
                           float* __restrict__ C, int n)
{
    int i = blockIdx.x * blockDim.x + threadIdx.x;
    int stride = gridDim.x * blockDim.x;
    for (; i < n; i += stride) C[i] = A[i] + B[i];
}

__global__ void build_allv(const float* __restrict__ temb, const float* __restrict__ l2rn,
                           const float* __restrict__ r2ln, float* __restrict__ allv)
{
    const int k = blockIdx.x;
    const int b = blockIdx.y;
    float* out = allv + ((size_t)b * 2049 + k) * 512;
    const float* src;
    if (k == 0)        src = temb + b * 512;
    else if (k <= 1024) src = l2rn + ((size_t)(b * 1024 + (k - 1)) * 512);
    else               src = r2ln + ((size_t)(b * 1024 + (k - 1025)) * 512);
    for (int e = threadIdx.x; e < 512; e += 256) out[e] = src[e];
}

// ---------------------------------------------------------------------------
// Tiled flash attention (fp32). One block = (b, h, 64-query tile).
// mode 0: self causal (k<=q); mode 1: self anti-causal (k>=q);
// mode 2: cross over 2049 keys: k==0 valid; k in [1,1024]: (k-1)>q;
//         k in [1025,2048]: (k-1025)<q.  (k=2048 never valid -> 32 key tiles)
// Q pre-scaled by 1/sqrt(Dh). Layouts: Q,O (B,1024,E); K,V (B,LK,E), head
// slice cols [h*64, h*64+64). 256 threads: tx=tid&15 (key/dh), ty=tid>>4 (q).
// ---------------------------------------------------------------------------
__global__ __launch_bounds__(256) void attn_tiled(
    const float* __restrict__ Q, const float* __restrict__ K,
    const float* __restrict__ V, float* __restrict__ O, int mode)
{
    const int E = 512;
    const int LK = (mode == 2) ? 2049 : 1024;
    const int qt = blockIdx.x, h = blockIdx.y, b = blockIdx.z;
    const int q0 = qt * 64;
    const int tid = threadIdx.x;
    const int tx = tid & 15, ty = tid >> 4;
    const int tx4 = tx * 4, ty4 = ty * 4;

    __shared__ float Qs[64][68];   // [d][q] transposed
    __shared__ float Ks[64][68];   // [d][k] transposed
    __shared__ float Vs[64][68];   // [k][d]
    __shared__ float Ss[64][67];   // [k][q]
    __shared__ float red[4][64];
    __shared__ float m_lds[64], l_lds[64], c_lds[64];

    // stage Q tile (transposed)
    {
        const float* Qbase = Q + ((size_t)b * 1024 + q0) * E + h * 64;
        for (int i = tid; i < 1024; i += 256) {
            int r = i >> 4;
            int c4 = (i & 15) << 2;
            float4 v = *(const float4*)(Qbase + (size_t)r * E + c4);
            Qs[c4 + 0][r] = v.x; Qs[c4 + 1][r] = v.y;
            Qs[c4 + 2][r] = v.z; Qs[c4 + 3][r] = v.w;
        }
    }
    if (tid < 64) { m_lds[tid] = NEGF; l_lds[tid] = 0.f; }

    float acc[4][4] = {};

    int kt0, kt1;
    if (mode == 0)      { kt0 = 0;  kt1 = qt; }
    else if (mode == 1) { kt0 = qt; kt1 = 15; }
    else                { kt0 = 0;  kt1 = 31; }

    for (int kt = kt0; kt <= kt1; ++kt) {
        if (mode == 2) {
            if (kt >= 1 && kt <= 15 && 64 * kt + 62 <= q0) continue;       // l2r all-invalid
            if (kt >= 17 && 64 * kt - 1025 >= q0 + 63) continue;           // r2l all-invalid
        }
        const int k0 = kt * 64;

        // stage K (transposed) and V tiles
        {
            const float* Kbase = K + ((size_t)b * LK + k0) * E + h * 64;
            const float* Vbase = V + ((size_t)b * LK + k0) * E + h * 64;
            for (int i = tid; i < 1024; i += 256) {
                int r = i >> 4;
                int c4 = (i & 15) << 2;
                float4 kv = *(const float4*)(Kbase + (size_t)r * E + c4);
                Ks[c4 + 0][r] = kv.x; Ks[c4 + 1][r] = kv.y;
                Ks[c4 + 2][r] = kv.z; Ks[c4 + 3][r] = kv.w;
                float4 vv = *(const float4*)(Vbase + (size_t)r * E + c4);
                *(float4*)&Vs[r][c4] = vv;
            }
        }
        __syncthreads();

        // S = Q @ K^T  (64x64, 4x4 microtile)
        float s[4][4] = {};
        #pragma unroll 16
        for (int kk = 0; kk < 64; ++kk) {
            float a[4], bb[4];
            #pragma unroll
            for (int i = 0; i < 4; ++i) a[i] = Qs[kk][ty4 + i];
            #pragma unroll
            for (int j = 0; j < 4; ++j) bb[j] = Ks[kk][tx4 + j];
            #pragma unroll
            for (int i = 0; i < 4; ++i)
                #pragma unroll
                for (int j = 0; j < 4; ++j)
                    s[i][j] = fmaf(a[i], bb[j], s[i][j]);
        }

        // masked store S -> Ss[k][q]
        #pragma unroll
        for (int j = 0; j < 4; ++j) {
            int k = k0 + tx4 + j;
            #pragma unroll
            for (int i = 0; i < 4; ++i) {
                int q = q0 + ty4 + i;
                bool valid;
                if (mode == 0)      valid = (k <= q);
                else if (mode == 1) valid = (k >= q);
                else valid = (k == 0) || (k <= 1024 ? (k - 1) > q : (k - 1025) < q);
                Ss[tx4 + j][ty4 + i] = valid ? s[i][j] : NEGF;
            }
        }
        __syncthreads();

        // per-row tile max (4 partials per row)
        {
            int qq = tid & 63, qr = tid >> 6;
            float mx = NEGF;
            #pragma unroll
            for (int kk = 0; kk < 16; ++kk) mx = fmaxf(mx, Ss[qr * 16 + kk][qq]);
            red[qr][qq] = mx;
        }
        __syncthreads();
        if (tid < 64) {
            float m_tile = fmaxf(fmaxf(red[0][tid], red[1][tid]),
                                 fmaxf(red[2][tid], red[3][tid]));
            float m_old = m_lds[tid];
            float m_new = fmaxf(m_old, m_tile);
            c_lds[tid] = expf(m_old - m_new);
            m_lds[tid] = m_new;
        }
        __syncthreads();

        // P = exp(S - m), partial row sums; rescale O acc by c
        {
            int qq = tid & 63, qr = tid >> 6;
            float mrow = m_lds[qq];
            float sm = 0.f;
            #pragma unroll
            for (int kk = 0; kk < 16; ++kk) {
                int ki = qr * 16 + kk;
                float p = expf(Ss[ki][qq] - mrow);
                Ss[ki][qq] = p;
                sm += p;
            }
            red[qr][qq] = sm;
        }
        #pragma unroll
        for (int i = 0; i < 4; ++i) {
            float cc = c_lds[ty4 + i];
            #pragma unroll
            for (int j = 0; j < 4; ++j) acc[i][j] *= cc;
        }
        __syncthreads();
        if (tid < 64)
            l_lds[tid] = l_lds[tid] * c_lds[tid] +
                         red[0][tid] + red[1][tid] + red[2][tid] + red[3][tid];

        // O += P @ V
        #pragma unroll 16
        for (int kk = 0; kk < 64; ++kk) {
            float a[4], bb[4];
            #pragma unroll
            for (int i = 0; i < 4; ++i) a[i] = Ss[kk][ty4 + i];
            #pragma unroll
            for (int j = 0; j < 4; ++j) bb[j] = Vs[kk][tx4 + j];
            #pragma unroll
            for (int i = 0; i < 4; ++i)
                #pragma unroll
                for (int j = 0; j < 4; ++j)
                    acc[i][j] = fmaf(a[i], bb[j], acc[i][j]);
        }
        __syncthreads();   // before next tile overwrites Ks/Vs/Ss
    }

    // epilogue: O = acc / l
    float* Obase = O + ((size_t)b * 1024 + q0) * E + h * 64;
    #pragma unroll
    for (int i = 0; i < 4; ++i) {
        float invl = 1.f / l_lds[ty4 + i];
        float4 o;
        o.x = acc[i][0] * invl; o.y = acc[i][1] * invl;
        o.z = acc[i][2] * invl; o.w = acc[i][3] * invl;
        *(float4*)(Obase + (size_t)(ty4 + i) * E + tx4) = o;
    }
}

// ---------------------------------------------------------------------------

static inline void gemm(hipStream_t st, const float* A, const float* W, const float* bias,
                        const float* res, float* C, int M, int N, int K,
                        float alpha, int gelu)
{
    dim3 g((N + 63) / 64, (M + 63) / 64);
    gemm_f32<<<g, dim3(256), 0, st>>>(A, W, bias, res, C, M, N, K, alpha, gelu);
}

extern "C" void kernel_launch(void* const* d_in, const int* in_sizes, int n_in,
                              void* d_out, int out_size, void* d_ws, size_t ws_size,
                              hipStream_t stream)
{
    const int*   x      = (const int*)  d_in[0];
    const float* t      = (const float*)d_in[1];
    const float* embedW = (const float*)d_in[2];
    const float* attn_W = (const float*)d_in[3];
    const float* attn_b = (const float*)d_in[4];
    const float* ln_s   = (const float*)d_in[5];
    const float* ln_b   = (const float*)d_in[6];
    const float* mlp_W1 = (const float*)d_in[7];
    const float* mlp_b1 = (const float*)d_in[8];
    const float* mlp_W2 = (const float*)d_in[9];
    const float* mlp_b2 = (const float*)d_in[10];
    const float* ca_Wq  = (const float*)d_in[11];
    const float* ca_Wk  = (const float*)d_in[12];
    const float* ca_bk  = (const float*)d_in[13];
    const float* ca_Wv  = (const float*)d_in[14];
    const float* ca_bv  = (const float*)d_in[15];
    const float* ca_Wo  = (const float*)d_in[16];
    const float* ca_bo  = (const float*)d_in[17];
    const float* ro1s   = (const float*)d_in[18];
    const float* ro1b   = (const float*)d_in[19];
    const float* ro2s   = (const float*)d_in[20];
    const float* ro2b   = (const float*)d_in[21];
    const float* in_W   = (const float*)d_in[22];
    const float* in_b   = (const float*)d_in[23];
    const float* tm_W1  = (const float*)d_in[24];
    const float* tm_b1  = (const float*)d_in[25];
    const float* tm_W2  = (const float*)d_in[26];
    const float* tm_b2  = (const float*)d_in[27];
    const float* res_W1 = (const float*)d_in[28];
    const float* res_b1 = (const float*)d_in[29];
    const float* res_W2 = (const float*)d_in[30];
    const float* res_b2 = (const float*)d_in[31];
    const float* rls    = (const float*)d_in[32];
    const float* rlb    = (const float*)d_in[33];
    const float* film_W = (const float*)d_in[34];
    const float* film_b = (const float*)d_in[35];
    const float* out_W  = (const float*)d_in[36];
    const float* out_b  = (const float*)d_in[37];
    float* out = (float*)d_out;
    float* ws  = (float*)d_ws;

    const size_t SZ_BLE  = 4u * 1024u * 512u;
    const size_t SZ_ALLV = 4u * 2049u * 512u;
    const size_t SZ_BL2E = 4u * 1024u * 1024u;
    size_t o = 0;
    float* TEMB = ws + o; o += 2048;
    float* T4   = ws + o; o += 8192;
    float* TM1  = ws + o; o += 8192;
    float* FILM = ws + o; o += 8192;
    o = 32768;
    float* L2R  = ws + o; o += SZ_BLE;
    float* R2L  = ws + o; o += SZ_BLE;
    float* Z    = ws + o; o += SZ_BLE;
    float* QB   = ws + o; o += SZ_BLE;
    float* KB   = ws + o; o += SZ_BLE;
    float* VB   = ws + o; o += SZ_BLE;
    float* OB   = ws + o; o += SZ_BLE;
    float* MID  = ws + o; o += 2 * SZ_ALLV;
    float* V2   = ws + o; o += SZ_ALLV;
    float* H2   = ws + o; o += SZ_BL2E;
    float* Z2   = ws + o; o += SZ_BL2E;
    float* ALLV = MID;
    float* K2   = MID + SZ_ALLV;
    (void)ws_size; (void)in_sizes; (void)n_in; (void)out_size;

    temb_kernel<<<dim3(4), dim3(256), 0, stream>>>(t, TEMB);
    embed_kernel<<<dim3(1024, 4, 2), dim3(256), 0, stream>>>(x, TEMB, embedW, L2R, R2L);

    for (int d = 0; d < 2; ++d) {
        float* h = (d == 0) ? L2R : R2L;
        for (int l = 0; l < 2; ++l) {
            const int dl = d * 2 + l;
            ln_kernel<<<4096, 256, 0, stream>>>(h, nullptr, ln_s + (dl * 2 + 0) * 512,
                                                ln_b + (dl * 2 + 0) * 512, Z, 512, nullptr, 1024);
            gemm(stream, Z, attn_W + (size_t)(dl * 4 + 0) * 262144, attn_b + (dl * 4 + 0) * 512,
                 nullptr, QB, 4096, 512, 512, 0.125f, 0);
            gemm(stream, Z, attn_W + (size_t)(dl * 4 + 1) * 262144, attn_b + (dl * 4 + 1) * 512,
                 nullptr, KB, 4096, 512, 512, 1.f, 0);
            gemm(stream, Z, attn_W + (size_t)(dl * 4 + 2) * 262144, attn_b + (dl * 4 + 2) * 512,
                 nullptr, VB, 4096, 512, 512, 1.f, 0);
            attn_tiled<<<dim3(16, 8, 4), dim3(256), 0, stream>>>(QB, KB, VB, OB, d);
            gemm(stream, OB, attn_W + (size_t)(dl * 4 + 3) * 262144, attn_b + (dl * 4 + 3) * 512,
                 h, h, 4096, 512, 512, 1.f, 0);
            ln_kernel<<<4096, 256, 0, stream>>>(h, nullptr, ln_s + (dl * 2 + 1) * 512,
                                                ln_b + (dl * 2 + 1) * 512, Z, 512, nullptr, 1024);
            gemm(stream, Z, mlp_W1 + (size_t)dl * 1048576, mlp_b1 + dl * 2048,
                 nullptr, MID, 4096, 2048, 512, 1.f, 1);
            gemm(stream, MID, mlp_W2 + (size_t)dl * 1048576, mlp_b2 + dl * 512,
                 h, h, 4096, 512, 2048, 1.f, 0);
        }
    }

    add_kernel<<<2048, 256, 0, stream>>>(L2R, R2L, Z, (int)SZ_BLE);
    ln_kernel<<<4096, 256, 0, stream>>>(L2R, nullptr, ro1s, ro1b, QB, 512, nullptr, 1024);
    ln_kernel<<<4096, 256, 0, stream>>>(R2L, nullptr, ro2s, ro2b, KB, 512, nullptr, 1024);
    add_kernel<<<2048, 256, 0, stream>>>(QB, KB, VB, (int)SZ_BLE);
    build_allv<<<dim3(2049, 4), dim3(256), 0, stream>>>(TEMB, QB, KB, ALLV);
    gemm(stream, VB, ca_Wq, nullptr, nullptr, OB, 4096, 512, 512, 0.125f, 0);
    gemm(stream, ALLV, ca_Wk, ca_bk, nullptr, K2, 8196, 512, 512, 1.f, 0);
    gemm(stream, ALLV, ca_Wv, ca_bv, nullptr, V2, 8196, 512, 512, 1.f, 0);
    attn_tiled<<<dim3(16, 8, 4), dim3(256), 0, stream>>>(OB, K2, V2, L2R, 2);
    gemm(stream, L2R, ca_Wo, ca_bo, Z, R2L, 4096, 512, 512, 1.f, 0);

    gemm(stream, TEMB, tm_W1, tm_b1, nullptr, TM1, 4, 2048, 512, 1.f, 1);
    gemm(stream, TM1, tm_W2, tm_b2, nullptr, T4, 4, 2048, 2048, 1.f, 0);

    gemm(stream, R2L, in_W, in_b, nullptr, H2, 4096, 1024, 512, 1.f, 0);
    for (int i = 0; i < 2; ++i) {
        gemm(stream, T4, film_W + (size_t)i * 4194304, film_b + i * 2048,
             nullptr, FILM, 4, 2048, 2048, 1.f, 0);
        gemm(stream, H2, res_W1 + (size_t)i * 2097152, res_b1 + i * 2048,
             nullptr, MID, 4096, 2048, 1024, 1.f, 1);
        gemm(stream, MID, res_W2 + (size_t)i * 2097152, res_b2 + i * 1024,
             nullptr, Z2, 4096, 1024, 2048, 1.f, 0);
        ln_kernel<<<4096, 256, 0, stream>>>(H2, Z2, rls + i * 1024, rlb + i * 1024,
                                            H2, 1024, FILM, 1024);
    }

    gemm(stream, H2, out_W, out_b, nullptr, out, 4096, 256, 1024, 1.f, 0);
}

// Round 3
// 3014.707 us; speedup vs baseline: 5.1888x; 2.1985x over previous
//
#include <hip/hip_runtime.h>
#include <hip/hip_bf16.h>

// ---------------------------------------------------------------------------
// B=4, L=1024, E=512, H=8, NL=2, M=2048, S=256, R=2, Dh=64
// ---------------------------------------------------------------------------

#define NEGF -3.4028235e38f

using bf16x8 = __attribute__((ext_vector_type(8))) short;
using f32x4  = __attribute__((ext_vector_type(4))) float;

__device__ inline float bf2f(unsigned short u) {
    return __uint_as_float(((unsigned int)u) << 16);
}
__device__ inline unsigned short f2b(float f) {
    unsigned int u = __float_as_uint(f);
    return (unsigned short)((u + 0x7fff + ((u >> 16) & 1)) >> 16);
}

// global -> LDS async copy, 16 B per lane (CK-style addrspace casts)
__device__ inline void gl_lds16(const void* g, void* l) {
    __builtin_amdgcn_global_load_lds(
        (const __attribute__((address_space(1))) void*)(uintptr_t)g,
        (__attribute__((address_space(3))) void*)(unsigned int)(uintptr_t)l,
        16, 0, 0);
}

// ---------------------------------------------------------------------------
// bf16 MFMA GEMM: C = epi(A[M,K] @ W[K,N]) with Wt = W^T stored [N][K] bf16.
// 128x128 tile, BK=32, 4 waves (2x2), wave tile 64x64 (4x4 16x16 frags).
// LDS packed: chunk c (16B = 8 bf16) = [mb(0..7)][koff(0..3)][r16(0..15)]
//   holding A[m0+mb*16+r16][k0+koff*8 .. +8]  (same for Wt rows = N cols).
// epi: v = (acc + bias[n]) * alpha; gelu?; += res; -> Cf (f32) / Cb (bf16)
// M, N multiples of 128 (callers pad). fp32 accumulate.
// ---------------------------------------------------------------------------
__global__ __launch_bounds__(256) void gemm_bf16(
    const unsigned short* __restrict__ A, const unsigned short* __restrict__ Wt,
    const float* __restrict__ bias, const float* __restrict__ res,
    float* __restrict__ Cf, unsigned short* __restrict__ Cb,
    int M, int N, int K, float alpha, int gelu_flag)
{
    __shared__ unsigned short As[4096];   // 8 KB
    __shared__ unsigned short Bs[4096];   // 8 KB
    const int tid  = threadIdx.x;
    const int wid  = tid >> 6, lane = tid & 63;
    const int wy   = wid >> 1, wx = wid & 1;
    const int koff = lane >> 4, l16 = lane & 15;
    const int m0 = blockIdx.y * 128, n0 = blockIdx.x * 128;

    // staging chunk assignment: this thread handles chunks tid and tid+256
    const int c0 = tid, c1 = tid + 256;
    const int rA0 = ((c0 >> 6) << 4) | (c0 & 15), kA0 = ((c0 >> 4) & 3) << 3;
    const int rA1 = ((c1 >> 6) << 4) | (c1 & 15), kA1 = ((c1 >> 4) & 3) << 3;

    const unsigned short* a0 = A  + (size_t)(m0 + rA0) * K + kA0;
    const unsigned short* a1 = A  + (size_t)(m0 + rA1) * K + kA1;
    const unsigned short* b0 = Wt + (size_t)(n0 + rA0) * K + kA0;
    const unsigned short* b1 = Wt + (size_t)(n0 + rA1) * K + kA1;

    unsigned short* ldsA0 = As + (size_t)(wid * 64) * 8;
    unsigned short* ldsA1 = As + (size_t)(256 + wid * 64) * 8;
    unsigned short* ldsB0 = Bs + (size_t)(wid * 64) * 8;
    unsigned short* ldsB1 = Bs + (size_t)(256 + wid * 64) * 8;

    f32x4 acc[4][4] = {};

    for (int k0 = 0; k0 < K; k0 += 32) {
        gl_lds16(a0 + k0, ldsA0);
        gl_lds16(a1 + k0, ldsA1);
        gl_lds16(b0 + k0, ldsB0);
        gl_lds16(b1 + k0, ldsB1);
        __syncthreads();

        bf16x8 af[4], bfr[4];
        const int foff = (koff * 16 + l16) * 8;
        #pragma unroll
        for (int i = 0; i < 4; ++i)
            af[i] = *(const bf16x8*)(As + (size_t)((wy * 4 + i) * 64) * 8 + foff);
        #pragma unroll
        for (int j = 0; j < 4; ++j)
            bfr[j] = *(const bf16x8*)(Bs + (size_t)((wx * 4 + j) * 64) * 8 + foff);

        #pragma unroll
        for (int i = 0; i < 4; ++i)
            #pragma unroll
            for (int j = 0; j < 4; ++j)
                acc[i][j] = __builtin_amdgcn_mfma_f32_16x16x32_bf16(
                    af[i], bfr[j], acc[i][j], 0, 0, 0);
        __syncthreads();
    }

    // epilogue: D layout col = lane&15, row = (lane>>4)*4 + reg
    #pragma unroll
    for (int i = 0; i < 4; ++i) {
        const int rbase = m0 + wy * 64 + i * 16 + koff * 4;
        #pragma unroll
        for (int j = 0; j < 4; ++j) {
            const int gn = n0 + wx * 64 + j * 16 + l16;
            const float bs = bias ? bias[gn] : 0.f;
            #pragma unroll
            for (int r = 0; r < 4; ++r) {
                float v = (acc[i][j][r] + bs) * alpha;
                if (gelu_flag) v = 0.5f * v * (1.0f + erff(v * 0.70710678118654752f));
                const size_t idx = (size_t)(rbase + r) * N + gn;
                if (res) v += res[idx];
                if (Cf) Cf[idx] = v;
                if (Cb) Cb[idx] = f2b(v);
            }
        }
    }
}

// ---------------------------------------------------------------------------
// weight transpose-convert: src fp32 [K][N] -> dst bf16 [N][K]
// grid: (N/64, K/64, batch)
// ---------------------------------------------------------------------------
__global__ __launch_bounds__(256) void wconv(
    const float* __restrict__ src, unsigned short* __restrict__ dst,
    int K, int N, long sstride, long dstride)
{
    __shared__ float t[64][65];
    const int n0 = blockIdx.x * 64, k0 = blockIdx.y * 64;
    const float* s = src + (size_t)blockIdx.z * sstride;
    unsigned short* d = dst + (size_t)blockIdx.z * dstride;
    const int tid = threadIdx.x;
    #pragma unroll
    for (int i = 0; i < 4; ++i) {
        int lin = i * 1024 + tid * 4;
        int r = lin >> 6, c = lin & 63;
        float4 v = *(const float4*)(s + (size_t)(k0 + r) * N + n0 + c);
        t[r][c] = v.x; t[r][c + 1] = v.y; t[r][c + 2] = v.z; t[r][c + 3] = v.w;
    }
    __syncthreads();
    #pragma unroll
    for (int i = 0; i < 8; ++i) {
        int lin = i * 512 + tid * 2;
        int rn = lin >> 6, ck = lin & 63;
        ushort2 o;
        o.x = f2b(t[ck][rn]); o.y = f2b(t[ck + 1][rn]);
        *(ushort2*)(d + (size_t)(n0 + rn) * K + k0 + ck) = o;
    }
}

// ---------------------------------------------------------------------------
// fp32 GEMM (kept for tiny M=4 GEMMs: t-MLP, FiLM)
// ---------------------------------------------------------------------------
__global__ __launch_bounds__(256) void gemm_f32(
    const float* __restrict__ A, const float* __restrict__ W,
    const float* __restrict__ bias, const float* __restrict__ res,
    float* __restrict__ C, int M, int N, int K, float alpha, int gelu_flag)
{
    __shared__ float As[16][64];
    __shared__ float Bs[16][64];
    const int bm = blockIdx.y * 64;
    const int bn = blockIdx.x * 64;
    const int tid = threadIdx.x;
    const int tx = tid & 15;
    const int ty = tid >> 4;
    float acc[4][4] = {};

    for (int k0 = 0; k0 < K; k0 += 16) {
        #pragma unroll
        for (int i = 0; i < 4; ++i) {
            int idx = tid + i * 256;
            int r = idx >> 4;
            int c = idx & 15;
            int gm = bm + r;
            As[c][r] = (gm < M) ? A[(size_t)gm * K + k0 + c] : 0.f;
        }
        #pragma unroll
        for (int i = 0; i < 4; ++i) {
            int idx = tid + i * 256;
            int r = idx >> 6;
            int c = idx & 63;
            int gn = bn + c;
            Bs[r][c] = (gn < N) ? W[(size_t)(k0 + r) * N + gn] : 0.f;
        }
        __syncthreads();
        #pragma unroll
        for (int kk = 0; kk < 16; ++kk) {
            float a[4], b[4];
            #pragma unroll
            for (int i = 0; i < 4; ++i) a[i] = As[kk][ty * 4 + i];
            #pragma unroll
            for (int j = 0; j < 4; ++j) b[j] = Bs[kk][tx * 4 + j];
            #pragma unroll
            for (int i = 0; i < 4; ++i)
                #pragma unroll
                for (int j = 0; j < 4; ++j)
                    acc[i][j] = fmaf(a[i], b[j], acc[i][j]);
        }
        __syncthreads();
    }

    #pragma unroll
    for (int i = 0; i < 4; ++i) {
        int gm = bm + ty * 4 + i;
        if (gm >= M) continue;
        #pragma unroll
        for (int j = 0; j < 4; ++j) {
            int gn = bn + tx * 4 + j;
            if (gn >= N) continue;
            float v = acc[i][j] + (bias ? bias[gn] : 0.f);
            v *= alpha;
            if (gelu_flag) v = 0.5f * v * (1.0f + erff(v * 0.70710678118654752f));
            if (res) v += res[(size_t)gm * N + gn];
            C[(size_t)gm * N + gn] = v;
        }
    }
}

// ---------------------------------------------------------------------------
// LayerNorm (+optional add, +optional FiLM); fp32 in, fp32 and/or bf16 out
// ---------------------------------------------------------------------------
__global__ __launch_bounds__(256) void ln_kernel(
    const float* __restrict__ X, const float* __restrict__ X2,
    const float* __restrict__ s, const float* __restrict__ b,
    float* __restrict__ Yf, unsigned short* __restrict__ Yb,
    int D, const float* __restrict__ film, int rows_per_batch)
{
    const int row = blockIdx.x;
    const int tid = threadIdx.x;
    const float* x = X + (size_t)row * D;
    const float* x2 = X2 ? X2 + (size_t)row * D : nullptr;

    float sum = 0.f, sq = 0.f;
    for (int c = tid; c < D; c += 256) {
        float v = x[c] + (x2 ? x2[c] : 0.f);
        sum += v; sq += v * v;
    }
    __shared__ float r1[4], r2[4];
    __shared__ float s_mean, s_rstd;
    for (int off = 32; off > 0; off >>= 1) {
        sum += __shfl_down(sum, off);
        sq  += __shfl_down(sq,  off);
    }
    if ((tid & 63) == 0) { r1[tid >> 6] = sum; r2[tid >> 6] = sq; }
    __syncthreads();
    if (tid == 0) {
        float ts = r1[0] + r1[1] + r1[2] + r1[3];
        float tq = r2[0] + r2[1] + r2[2] + r2[3];
        float mean = ts / (float)D;
        float var = tq / (float)D - mean * mean;
        s_mean = mean;
        s_rstd = rsqrtf(var + 1e-5f);
    }
    __syncthreads();
    const float mean = s_mean, rstd = s_rstd;
    const float* fa = nullptr; const float* fb = nullptr;
    if (film) {
        int batch = row / rows_per_batch;
        fa = film + (size_t)batch * 2 * D;
        fb = fa + D;
    }
    for (int c = tid; c < D; c += 256) {
        float v = x[c] + (x2 ? x2[c] : 0.f);
        float y = (v - mean) * rstd * s[c] + b[c];
        if (film) y = fa[c] * y + fb[c];
        if (Yf) Yf[(size_t)row * D + c] = y;
        if (Yb) Yb[(size_t)row * D + c] = f2b(y);
    }
}

__global__ void temb_kernel(const float* __restrict__ t, float* __restrict__ temb,
                            unsigned short* __restrict__ tembb)
{
    int b = blockIdx.x;
    int i = threadIdx.x;
    float f = expf((float)i * (-9.210340371976184f / 255.0f));
    float a = t[b] * f;
    float sv = sinf(a), cv = cosf(a);
    temb[b * 512 + i]        = sv;
    temb[b * 512 + 256 + i]  = cv;
    tembb[b * 512 + i]       = f2b(sv);
    tembb[b * 512 + 256 + i] = f2b(cv);
}

__global__ void embed_kernel(const int* __restrict__ x, const float* __restrict__ temb,
                             const float* __restrict__ embed,
                             float* __restrict__ l2r, float* __restrict__ r2l)
{
    const int i = blockIdx.x;
    const int b = blockIdx.y;
    const int d = blockIdx.z;
    float* out = (d == 0 ? l2r : r2l) + ((size_t)(b * 1024 + i) * 512);
    const float* src;
    if (d == 0) src = (i == 0)    ? temb + b * 512 : embed + (size_t)x[b * 1024 + (i - 1)] * 512;
    else        src = (i == 1023) ? temb + b * 512 : embed + (size_t)x[b * 1024 + (i + 1)] * 512;
    for (int e = threadIdx.x; e < 512; e += 256) {
        int j = e >> 1;
        float div = expf((float)(2 * j) * (-9.210340371976184f / 512.0f));
        float ang = (float)i * div;
        float pe = (e & 1) ? cosf(ang) : sinf(ang);
        out[e] = src[e] + pe;
    }
}

__global__ void add_kernel(const float* __restrict__ A, const float* __restrict__ B,
                           float* __restrict__ C, int n)
{
    int i = blockIdx.x * blockDim.x + threadIdx.x;
    int stride = gridDim.x * blockDim.x;
    for (; i < n; i += stride) C[i] = A[i] + B[i];
}

// bf16 + bf16 -> bf16, packed 2/word; nwords = elems/2
__global__ void add_bf16(const unsigned int* __restrict__ A,
                         const unsigned int* __restrict__ B,
                         unsigned int* __restrict__ C, int nwords)
{
    int i = blockIdx.x * blockDim.x + threadIdx.x;
    int stride = gridDim.x * blockDim.x;
    for (; i < nwords; i += stride) {
        unsigned int a = A[i], b = B[i];
        float lo = __uint_as_float(a << 16) + __uint_as_float(b << 16);
        float hi = __uint_as_float(a & 0xffff0000u) + __uint_as_float(b & 0xffff0000u);
        C[i] = (unsigned int)f2b(lo) | ((unsigned int)f2b(hi) << 16);
    }
}

// allv (bf16, batch stride 2080 rows): row0 = temb; 1+i = l2rn; 1025+i = r2ln
__global__ void build_allv_b(const unsigned short* __restrict__ tembb,
                             const unsigned short* __restrict__ l2rn,
                             const unsigned short* __restrict__ r2ln,
                             unsigned short* __restrict__ allv)
{
    const int k = blockIdx.x;   // 0..2048
    const int b = blockIdx.y;
    unsigned short* out = allv + ((size_t)b * 2080 + k) * 512;
    const unsigned short* src;
    if (k == 0)         src = tembb + b * 512;
    else if (k <= 1024) src = l2rn + ((size_t)(b * 1024 + (k - 1)) * 512);
    else                src = r2ln + ((size_t)(b * 1024 + (k - 1025)) * 512);
    ((uint4*)out)[threadIdx.x] = ((const uint4*)src)[threadIdx.x];   // 64 thr x 16B
}

// ---------------------------------------------------------------------------
// Tiled flash attention, bf16 in/out, fp32 math. One block = (b,h,64-q tile).
// mode 0: k<=q; mode 1: k>=q; mode 2: cross (2049 keys, batch stride 2080)
// ---------------------------------------------------------------------------
__global__ __launch_bounds__(256) void attn_tiled(
    const unsigned short* __restrict__ Q, const unsigned short* __restrict__ K,
    const unsigned short* __restrict__ V, unsigned short* __restrict__ O, int mode)
{
    const int E = 512;
    const int LKP = (mode == 2) ? 2080 : 1024;   // K/V batch row stride
    const int qt = blockIdx.x, h = blockIdx.y, b = blockIdx.z;
    const int q0 = qt * 64;
    const int tid = threadIdx.x;
    const int tx = tid & 15, ty = tid >> 4;
    const int tx4 = tx * 4, ty4 = ty * 4;

    __shared__ float Qs[64][68];
    __shared__ float Ks[64][68];
    __shared__ float Vs[64][68];
    __shared__ float Ss[64][67];
    __shared__ float red[4][64];
    __shared__ float m_lds[64], l_lds[64], c_lds[64];

    {
        const unsigned short* Qbase = Q + ((size_t)b * 1024 + q0) * E + h * 64;
        for (int i = tid; i < 512; i += 256) {
            int r = i >> 3, c8 = (i & 7) << 3;
            uint4 raw = *(const uint4*)(Qbase + (size_t)r * E + c8);
            Qs[c8 + 0][r] = __uint_as_float(raw.x << 16);
            Qs[c8 + 1][r] = __uint_as_float(raw.x & 0xffff0000u);
            Qs[c8 + 2][r] = __uint_as_float(raw.y << 16);
            Qs[c8 + 3][r] = __uint_as_float(raw.y & 0xffff0000u);
            Qs[c8 + 4][r] = __uint_as_float(raw.z << 16);
            Qs[c8 + 5][r] = __uint_as_float(raw.z & 0xffff0000u);
            Qs[c8 + 6][r] = __uint_as_float(raw.w << 16);
            Qs[c8 + 7][r] = __uint_as_float(raw.w & 0xffff0000u);
        }
    }
    if (tid < 64) { m_lds[tid] = NEGF; l_lds[tid] = 0.f; }

    float acc[4][4] = {};

    int kt0, kt1;
    if (mode == 0)      { kt0 = 0;  kt1 = qt; }
    else if (mode == 1) { kt0 = qt; kt1 = 15; }
    else                { kt0 = 0;  kt1 = 31; }

    for (int kt = kt0; kt <= kt1; ++kt) {
        if (mode == 2) {
            if (kt >= 1 && kt <= 15 && 64 * kt + 62 <= q0) continue;
            if (kt >= 17 && 64 * kt - 1025 >= q0 + 63) continue;
        }
        const int k0 = kt * 64;

        {
            const unsigned short* Kbase = K + ((size_t)b * LKP + k0) * E + h * 64;
            const unsigned short* Vbase = V + ((size_t)b * LKP + k0) * E + h * 64;
            for (int i = tid; i < 512; i += 256) {
                int r = i >> 3, c8 = (i & 7) << 3;
                uint4 kw = *(const uint4*)(Kbase + (size_t)r * E + c8);
                Ks[c8 + 0][r] = __uint_as_float(kw.x << 16);
                Ks[c8 + 1][r] = __uint_as_float(kw.x & 0xffff0000u);
                Ks[c8 + 2][r] = __uint_as_float(kw.y << 16);
                Ks[c8 + 3][r] = __uint_as_float(kw.y & 0xffff0000u);
                Ks[c8 + 4][r] = __uint_as_float(kw.z << 16);
                Ks[c8 + 5][r] = __uint_as_float(kw.z & 0xffff0000u);
                Ks[c8 + 6][r] = __uint_as_float(kw.w << 16);
                Ks[c8 + 7][r] = __uint_as_float(kw.w & 0xffff0000u);
                uint4 vw = *(const uint4*)(Vbase + (size_t)r * E + c8);
                Vs[r][c8 + 0] = __uint_as_float(vw.x << 16);
                Vs[r][c8 + 1] = __uint_as_float(vw.x & 0xffff0000u);
                Vs[r][c8 + 2] = __uint_as_float(vw.y << 16);
                Vs[r][c8 + 3] = __uint_as_float(vw.y & 0xffff0000u);
                Vs[r][c8 + 4] = __uint_as_float(vw.z << 16);
                Vs[r][c8 + 5] = __uint_as_float(vw.z & 0xffff0000u);
                Vs[r][c8 + 6] = __uint_as_float(vw.w << 16);
                Vs[r][c8 + 7] = __uint_as_float(vw.w & 0xffff0000u);
            }
        }
        __syncthreads();

        float s[4][4] = {};
        #pragma unroll 16
        for (int kk = 0; kk < 64; ++kk) {
            float a[4], bb[4];
            #pragma unroll
            for (int i = 0; i < 4; ++i) a[i] = Qs[kk][ty4 + i];
            #pragma unroll
            for (int j = 0; j < 4; ++j) bb[j] = Ks[kk][tx4 + j];
            #pragma unroll
            for (int i = 0; i < 4; ++i)
                #pragma unroll
                for (int j = 0; j < 4; ++j)
                    s[i][j] = fmaf(a[i], bb[j], s[i][j]);
        }

        #pragma unroll
        for (int j = 0; j < 4; ++j) {
            int k = k0 + tx4 + j;
            #pragma unroll
            for (int i = 0; i < 4; ++i) {
                int q = q0 + ty4 + i;
                bool valid;
                if (mode == 0)      valid = (k <= q);
                else if (mode == 1) valid = (k >= q);
                else valid = (k == 0) || (k <= 1024 ? (k - 1) > q : (k - 1025) < q);
                Ss[tx4 + j][ty4 + i] = valid ? s[i][j] : NEGF;
            }
        }
        __syncthreads();

        {
            int qq = tid & 63, qr = tid >> 6;
            float mx = NEGF;
            #pragma unroll
            for (int kk = 0; kk < 16; ++kk) mx = fmaxf(mx, Ss[qr * 16 + kk][qq]);
            red[qr][qq] = mx;
        }
        __syncthreads();
        if (tid < 64) {
            float m_tile = fmaxf(fmaxf(red[0][tid], red[1][tid]),
                                 fmaxf(red[2][tid], red[3][tid]));
            float m_old = m_lds[tid];
            float m_new = fmaxf(m_old, m_tile);
            c_lds[tid] = expf(m_old - m_new);
            m_lds[tid] = m_new;
        }
        __syncthreads();

        {
            int qq = tid & 63, qr = tid >> 6;
            float mrow = m_lds[qq];
            float sm = 0.f;
            #pragma unroll
            for (int kk = 0; kk < 16; ++kk) {
                int ki = qr * 16 + kk;
                float p = expf(Ss[ki][qq] - mrow);
                Ss[ki][qq] = p;
                sm += p;
            }
            red[qr][qq] = sm;
        }
        #pragma unroll
        for (int i = 0; i < 4; ++i) {
            float cc = c_lds[ty4 + i];
            #pragma unroll
            for (int j = 0; j < 4; ++j) acc[i][j] *= cc;
        }
        __syncthreads();
        if (tid < 64)
            l_lds[tid] = l_lds[tid] * c_lds[tid] +
                         red[0][tid] + red[1][tid] + red[2][tid] + red[3][tid];

        #pragma unroll 16
        for (int kk = 0; kk < 64; ++kk) {
            float a[4], bb[4];
            #pragma unroll
            for (int i = 0; i < 4; ++i) a[i] = Ss[kk][ty4 + i];
            #pragma unroll
            for (int j = 0; j < 4; ++j) bb[j] = Vs[kk][tx4 + j];
            #pragma unroll
            for (int i = 0; i < 4; ++i)
                #pragma unroll
                for (int j = 0; j < 4; ++j)
                    acc[i][j] = fmaf(a[i], bb[j], acc[i][j]);
        }
        __syncthreads();
    }

    unsigned short* Obase = O + ((size_t)b * 1024 + q0) * E + h * 64;
    #pragma unroll
    for (int i = 0; i < 4; ++i) {
        float invl = 1.f / l_lds[ty4 + i];
        ushort4 o4;
        o4.x = f2b(acc[i][0] * invl); o4.y = f2b(acc[i][1] * invl);
        o4.z = f2b(acc[i][2] * invl); o4.w = f2b(acc[i][3] * invl);
        *(ushort4*)(Obase + (size_t)(ty4 + i) * E + tx4) = o4;
    }
}

// ---------------------------------------------------------------------------

static inline void gemm(hipStream_t st, const float* A, const float* W, const float* bias,
                        const float* res, float* C, int M, int N, int K,
                        float alpha, int gelu)
{
    dim3 g((N + 63) / 64, (M + 63) / 64);
    gemm_f32<<<g, dim3(256), 0, st>>>(A, W, bias, res, C, M, N, K, alpha, gelu);
}

static inline void gemmb(hipStream_t st, const unsigned short* A, const unsigned short* Wt,
                         const float* bias, const float* res, float* Cf,
                         unsigned short* Cb, int M, int N, int K, float alpha, int gelu)
{
    dim3 g(N / 128, M / 128);
    gemm_bf16<<<g, dim3(256), 0, st>>>(A, Wt, bias, res, Cf, Cb, M, N, K, alpha, gelu);
}

extern "C" void kernel_launch(void* const* d_in, const int* in_sizes, int n_in,
                              void* d_out, int out_size, void* d_ws, size_t ws_size,
                              hipStream_t stream)
{
    const int*   x      = (const int*)  d_in[0];
    const float* t      = (const float*)d_in[1];
    const float* embedW = (const float*)d_in[2];
    const float* attn_W = (const float*)d_in[3];
    const float* attn_b = (const float*)d_in[4];
    const float* ln_s   = (const float*)d_in[5];
    const float* ln_b   = (const float*)d_in[6];
    const float* mlp_W1 = (const float*)d_in[7];
    const float* mlp_b1 = (const float*)d_in[8];
    const float* mlp_W2 = (const float*)d_in[9];
    const float* mlp_b2 = (const float*)d_in[10];
    const float* ca_Wq  = (const float*)d_in[11];
    const float* ca_Wk  = (const float*)d_in[12];
    const float* ca_bk  = (const float*)d_in[13];
    const float* ca_Wv  = (const float*)d_in[14];
    const float* ca_bv  = (const float*)d_in[15];
    const float* ca_Wo  = (const float*)d_in[16];
    const float* ca_bo  = (const float*)d_in[17];
    const float* ro1s   = (const float*)d_in[18];
    const float* ro1b   = (const float*)d_in[19];
    const float* ro2s   = (const float*)d_in[20];
    const float* ro2b   = (const float*)d_in[21];
    const float* in_W   = (const float*)d_in[22];
    const float* in_b   = (const float*)d_in[23];
    const float* tm_W1  = (const float*)d_in[24];
    const float* tm_b1  = (const float*)d_in[25];
    const float* tm_W2  = (const float*)d_in[26];
    const float* tm_b2  = (const float*)d_in[27];
    const float* res_W1 = (const float*)d_in[28];
    const float* res_b1 = (const float*)d_in[29];
    const float* res_W2 = (const float*)d_in[30];
    const float* res_b2 = (const float*)d_in[31];
    const float* rls    = (const float*)d_in[32];
    const float* rlb    = (const float*)d_in[33];
    const float* film_W = (const float*)d_in[34];
    const float* film_b = (const float*)d_in[35];
    const float* out_W  = (const float*)d_in[36];
    const float* out_b  = (const float*)d_in[37];
    float* out = (float*)d_out;
    (void)ws_size; (void)in_sizes; (void)n_in; (void)out_size;

    // ---- workspace layout (bytes, 256-aligned) ----
    char* base = (char*)d_ws;
    size_t off = 0;
    auto alloc = [&](size_t bytes) -> char* {
        char* p = base + off;
        off = (off + bytes + 255) & ~(size_t)255;
        return p;
    };
    float* TEMB  = (float*)alloc(8192);
    float* TM1   = (float*)alloc(32768);
    float* T4    = (float*)alloc(32768);
    float* FILM  = (float*)alloc(32768);
    unsigned short* TEMBb = (unsigned short*)alloc(4096);

    float* L2R = (float*)alloc(8388608);
    float* R2L = (float*)alloc(8388608);
    float* Z   = (float*)alloc(8388608);
    float* H2  = (float*)alloc(16777216);
    float* Z2  = (float*)alloc(16777216);

    unsigned short* Zb  = (unsigned short*)alloc(4194304);
    unsigned short* Qb  = (unsigned short*)alloc(4194304);
    unsigned short* Kb  = (unsigned short*)alloc(4194304);
    unsigned short* Vb  = (unsigned short*)alloc(4194304);
    unsigned short* Ob  = (unsigned short*)alloc(4194304);
    unsigned short* H2b = (unsigned short*)alloc(8388608);

    unsigned short* BIG = (unsigned short*)alloc(25559040);
    unsigned short* MIDb  = BIG;                    // 4096x2048
    unsigned short* ALLVb = BIG;                    // 8320x512
    unsigned short* K2b   = BIG + 4259840;          // 8320x512
    unsigned short* V2b   = BIG + 8519680;          // 8320x512

    unsigned short* WT = (unsigned short*)alloc(45613056);
    const size_t wt_attn = 0,        wt_mlp1 = 4194304, wt_mlp2 = 8388608;
    const size_t wt_caq = 12582912,  wt_cak = 12845056, wt_cav = 13107200,
                 wt_cao = 13369344,  wt_in  = 13631488;
    const size_t wt_res1 = 14155776, wt_res2 = 18350080, wt_out = 22544384;

    // ---- weight conversion (fp32 [K][N] -> bf16 [N][K]) ----
    wconv<<<dim3(8, 8, 16), 256, 0, stream>>>(attn_W, WT + wt_attn, 512, 512, 262144, 262144);
    wconv<<<dim3(32, 8, 4), 256, 0, stream>>>(mlp_W1, WT + wt_mlp1, 512, 2048, 1048576, 1048576);
    wconv<<<dim3(8, 32, 4), 256, 0, stream>>>(mlp_W2, WT + wt_mlp2, 2048, 512, 1048576, 1048576);
    wconv<<<dim3(8, 8), 256, 0, stream>>>(ca_Wq, WT + wt_caq, 512, 512, 0, 0);
    wconv<<<dim3(8, 8), 256, 0, stream>>>(ca_Wk, WT + wt_cak, 512, 512, 0, 0);
    wconv<<<dim3(8, 8), 256, 0, stream>>>(ca_Wv, WT + wt_cav, 512, 512, 0, 0);
    wconv<<<dim3(8, 8), 256, 0, stream>>>(ca_Wo, WT + wt_cao, 512, 512, 0, 0);
    wconv<<<dim3(16, 8), 256, 0, stream>>>(in_W, WT + wt_in, 512, 1024, 0, 0);
    wconv<<<dim3(32, 16, 2), 256, 0, stream>>>(res_W1, WT + wt_res1, 1024, 2048, 2097152, 2097152);
    wconv<<<dim3(16, 32, 2), 256, 0, stream>>>(res_W2, WT + wt_res2, 2048, 1024, 2097152, 2097152);
    wconv<<<dim3(4, 16), 256, 0, stream>>>(out_W, WT + wt_out, 1024, 256, 0, 0);

    // ---- embeddings ----
    temb_kernel<<<dim3(4), dim3(256), 0, stream>>>(t, TEMB, TEMBb);
    embed_kernel<<<dim3(1024, 4, 2), dim3(256), 0, stream>>>(x, TEMB, embedW, L2R, R2L);

    // ---- transformer blocks ----
    for (int d = 0; d < 2; ++d) {
        float* h = (d == 0) ? L2R : R2L;
        for (int l = 0; l < 2; ++l) {
            const int dl = d * 2 + l;
            ln_kernel<<<4096, 256, 0, stream>>>(h, nullptr, ln_s + (dl * 2 + 0) * 512,
                                                ln_b + (dl * 2 + 0) * 512, nullptr, Zb,
                                                512, nullptr, 1024);
            gemmb(stream, Zb, WT + wt_attn + (size_t)(dl * 4 + 0) * 262144,
                  attn_b + (dl * 4 + 0) * 512, nullptr, nullptr, Qb, 4096, 512, 512, 0.125f, 0);
            gemmb(stream, Zb, WT + wt_attn + (size_t)(dl * 4 + 1) * 262144,
                  attn_b + (dl * 4 + 1) * 512, nullptr, nullptr, Kb, 4096, 512, 512, 1.f, 0);
            gemmb(stream, Zb, WT + wt_attn + (size_t)(dl * 4 + 2) * 262144,
                  attn_b + (dl * 4 + 2) * 512, nullptr, nullptr, Vb, 4096, 512, 512, 1.f, 0);
            attn_tiled<<<dim3(16, 8, 4), dim3(256), 0, stream>>>(Qb, Kb, Vb, Ob, d);
            gemmb(stream, Ob, WT + wt_attn + (size_t)(dl * 4 + 3) * 262144,
                  attn_b + (dl * 4 + 3) * 512, h, h, nullptr, 4096, 512, 512, 1.f, 0);
            ln_kernel<<<4096, 256, 0, stream>>>(h, nullptr, ln_s + (dl * 2 + 1) * 512,
                                                ln_b + (dl * 2 + 1) * 512, nullptr, Zb,
                                                512, nullptr, 1024);
            gemmb(stream, Zb, WT + wt_mlp1 + (size_t)dl * 1048576, mlp_b1 + dl * 2048,
                  nullptr, nullptr, MIDb, 4096, 2048, 512, 1.f, 1);
            gemmb(stream, MIDb, WT + wt_mlp2 + (size_t)dl * 1048576, mlp_b2 + dl * 512,
                  h, h, nullptr, 4096, 512, 2048, 1.f, 0);
        }
    }

    // ---- readout / cross-attention ----
    add_kernel<<<2048, 256, 0, stream>>>(L2R, R2L, Z, 2097152);                  // inputs (fp32)
    ln_kernel<<<4096, 256, 0, stream>>>(L2R, nullptr, ro1s, ro1b, nullptr, Qb, 512, nullptr, 1024);
    ln_kernel<<<4096, 256, 0, stream>>>(R2L, nullptr, ro2s, ro2b, nullptr, Kb, 512, nullptr, 1024);
    add_bf16<<<1024, 256, 0, stream>>>((const unsigned int*)Qb, (const unsigned int*)Kb,
                                       (unsigned int*)Vb, 1048576);              // l2rn + r2ln
    build_allv_b<<<dim3(2049, 4), 64, 0, stream>>>(TEMBb, Qb, Kb, ALLVb);
    gemmb(stream, Vb, WT + wt_caq, nullptr, nullptr, nullptr, Zb, 4096, 512, 512, 0.125f, 0);
    gemmb(stream, ALLVb, WT + wt_cak, ca_bk, nullptr, nullptr, K2b, 8320, 512, 512, 1.f, 0);
    gemmb(stream, ALLVb, WT + wt_cav, ca_bv, nullptr, nullptr, V2b, 8320, 512, 512, 1.f, 0);
    attn_tiled<<<dim3(16, 8, 4), dim3(256), 0, stream>>>(Zb, K2b, V2b, Ob, 2);
    gemmb(stream, Ob, WT + wt_cao, ca_bo, Z, nullptr, Qb, 4096, 512, 512, 1.f, 0); // xat -> Qb

    // ---- t-MLP (fp32 path, tiny) ----
    gemm(stream, TEMB, tm_W1, tm_b1, nullptr, TM1, 4, 2048, 512, 1.f, 1);
    gemm(stream, TM1, tm_W2, tm_b2, nullptr, T4, 4, 2048, 2048, 1.f, 0);

    // ---- residual FiLM blocks ----
    gemmb(stream, Qb, WT + wt_in, in_b, nullptr, H2, H2b, 4096, 1024, 512, 1.f, 0);
    for (int i = 0; i < 2; ++i) {
        gemm(stream, T4, film_W + (size_t)i * 4194304, film_b + i * 2048,
             nullptr, FILM, 4, 2048, 2048, 1.f, 0);
        gemmb(stream, H2b, WT + wt_res1 + (size_t)i * 2097152, res_b1 + i * 2048,
              nullptr, nullptr, MIDb, 4096, 2048, 1024, 1.f, 1);
        gemmb(stream, MIDb, WT + wt_res2 + (size_t)i * 2097152, res_b2 + i * 1024,
              nullptr, Z2, nullptr, 4096, 1024, 2048, 1.f, 0);
        ln_kernel<<<4096, 256, 0, stream>>>(H2, Z2, rls + i * 1024, rlb + i * 1024,
                                            H2, H2b, 1024, FILM, 1024);
    }

    // ---- output projection ----
    gemmb(stream, H2b, WT + wt_out, out_b, nullptr, out, nullptr, 4096, 256, 1024, 1.f, 0);
}

// Round 4
// 2462.859 us; speedup vs baseline: 6.3514x; 1.2241x over previous
//
#include <hip/hip_runtime.h>
#include <hip/hip_bf16.h>

// ---------------------------------------------------------------------------
// B=4, L=1024, E=512, H=8, NL=2, M=2048, S=256, R=2, Dh=64
// ---------------------------------------------------------------------------

#define NEGF -3.4028235e38f
#define LOG2E 1.4426950408889634f

using bf16x8 = __attribute__((ext_vector_type(8))) short;
using f32x4  = __attribute__((ext_vector_type(4))) float;

__device__ inline float bf2f(unsigned short u) {
    return __uint_as_float(((unsigned int)u) << 16);
}
__device__ inline unsigned short f2b(float f) {
    unsigned int u = __float_as_uint(f);
    return (unsigned short)((u + 0x7fff + ((u >> 16) & 1)) >> 16);
}

// global -> LDS async copy, 16 B per lane
__device__ inline void gl_lds16(const void* g, void* l) {
    __builtin_amdgcn_global_load_lds(
        (const __attribute__((address_space(1))) void*)(uintptr_t)g,
        (__attribute__((address_space(3))) void*)(unsigned int)(uintptr_t)l,
        16, 0, 0);
}

// ---------------------------------------------------------------------------
// bf16 MFMA GEMM: C = epi(A[M,K] @ W[K,N]) with Wt = W^T stored [N][K] bf16.
// 128x128 tile, BK=32, 4 waves (2x2), wave tile 64x64 (4x4 16x16 frags).
// ---------------------------------------------------------------------------
__global__ __launch_bounds__(256) void gemm_bf16(
    const unsigned short* __restrict__ A, const unsigned short* __restrict__ Wt,
    const float* __restrict__ bias, const float* __restrict__ res,
    float* __restrict__ Cf, unsigned short* __restrict__ Cb,
    int M, int N, int K, float alpha, int gelu_flag)
{
    __shared__ unsigned short As[4096];
    __shared__ unsigned short Bs[4096];
    const int tid  = threadIdx.x;
    const int wid  = tid >> 6, lane = tid & 63;
    const int wy   = wid >> 1, wx = wid & 1;
    const int koff = lane >> 4, l16 = lane & 15;
    const int m0 = blockIdx.y * 128, n0 = blockIdx.x * 128;

    const int c0 = tid, c1 = tid + 256;
    const int rA0 = ((c0 >> 6) << 4) | (c0 & 15), kA0 = ((c0 >> 4) & 3) << 3;
    const int rA1 = ((c1 >> 6) << 4) | (c1 & 15), kA1 = ((c1 >> 4) & 3) << 3;

    const unsigned short* a0 = A  + (size_t)(m0 + rA0) * K + kA0;
    const unsigned short* a1 = A  + (size_t)(m0 + rA1) * K + kA1;
    const unsigned short* b0 = Wt + (size_t)(n0 + rA0) * K + kA0;
    const unsigned short* b1 = Wt + (size_t)(n0 + rA1) * K + kA1;

    unsigned short* ldsA0 = As + (size_t)(wid * 64) * 8;
    unsigned short* ldsA1 = As + (size_t)(256 + wid * 64) * 8;
    unsigned short* ldsB0 = Bs + (size_t)(wid * 64) * 8;
    unsigned short* ldsB1 = Bs + (size_t)(256 + wid * 64) * 8;

    f32x4 acc[4][4] = {};

    for (int k0 = 0; k0 < K; k0 += 32) {
        gl_lds16(a0 + k0, ldsA0);
        gl_lds16(a1 + k0, ldsA1);
        gl_lds16(b0 + k0, ldsB0);
        gl_lds16(b1 + k0, ldsB1);
        __syncthreads();

        bf16x8 af[4], bfr[4];
        const int foff = (koff * 16 + l16) * 8;
        #pragma unroll
        for (int i = 0; i < 4; ++i)
            af[i] = *(const bf16x8*)(As + (size_t)((wy * 4 + i) * 64) * 8 + foff);
        #pragma unroll
        for (int j = 0; j < 4; ++j)
            bfr[j] = *(const bf16x8*)(Bs + (size_t)((wx * 4 + j) * 64) * 8 + foff);

        #pragma unroll
        for (int i = 0; i < 4; ++i)
            #pragma unroll
            for (int j = 0; j < 4; ++j)
                acc[i][j] = __builtin_amdgcn_mfma_f32_16x16x32_bf16(
                    af[i], bfr[j], acc[i][j], 0, 0, 0);
        __syncthreads();
    }

    #pragma unroll
    for (int i = 0; i < 4; ++i) {
        const int rbase = m0 + wy * 64 + i * 16 + koff * 4;
        #pragma unroll
        for (int j = 0; j < 4; ++j) {
            const int gn = n0 + wx * 64 + j * 16 + l16;
            const float bs = bias ? bias[gn] : 0.f;
            #pragma unroll
            for (int r = 0; r < 4; ++r) {
                float v = (acc[i][j][r] + bs) * alpha;
                if (gelu_flag) v = 0.5f * v * (1.0f + erff(v * 0.70710678118654752f));
                const size_t idx = (size_t)(rbase + r) * N + gn;
                if (res) v += res[idx];
                if (Cf) Cf[idx] = v;
                if (Cb) Cb[idx] = f2b(v);
            }
        }
    }
}

// ---------------------------------------------------------------------------
// weight transpose-convert: src fp32 [K][N] -> dst bf16 [N][K]
// ---------------------------------------------------------------------------
__global__ __launch_bounds__(256) void wconv(
    const float* __restrict__ src, unsigned short* __restrict__ dst,
    int K, int N, long sstride, long dstride)
{
    __shared__ float t[64][65];
    const int n0 = blockIdx.x * 64, k0 = blockIdx.y * 64;
    const float* s = src + (size_t)blockIdx.z * sstride;
    unsigned short* d = dst + (size_t)blockIdx.z * dstride;
    const int tid = threadIdx.x;
    #pragma unroll
    for (int i = 0; i < 4; ++i) {
        int lin = i * 1024 + tid * 4;
        int r = lin >> 6, c = lin & 63;
        float4 v = *(const float4*)(s + (size_t)(k0 + r) * N + n0 + c);
        t[r][c] = v.x; t[r][c + 1] = v.y; t[r][c + 2] = v.z; t[r][c + 3] = v.w;
    }
    __syncthreads();
    #pragma unroll
    for (int i = 0; i < 8; ++i) {
        int lin = i * 512 + tid * 2;
        int rn = lin >> 6, ck = lin & 63;
        ushort2 o;
        o.x = f2b(t[ck][rn]); o.y = f2b(t[ck + 1][rn]);
        *(ushort2*)(d + (size_t)(n0 + rn) * K + k0 + ck) = o;
    }
}

// ---------------------------------------------------------------------------
// fp32 GEMM (tiny M=4 GEMMs: t-MLP, FiLM)
// ---------------------------------------------------------------------------
__global__ __launch_bounds__(256) void gemm_f32(
    const float* __restrict__ A, const float* __restrict__ W,
    const float* __restrict__ bias, const float* __restrict__ res,
    float* __restrict__ C, int M, int N, int K, float alpha, int gelu_flag)
{
    __shared__ float As[16][64];
    __shared__ float Bs[16][64];
    const int bm = blockIdx.y * 64;
    const int bn = blockIdx.x * 64;
    const int tid = threadIdx.x;
    const int tx = tid & 15;
    const int ty = tid >> 4;
    float acc[4][4] = {};

    for (int k0 = 0; k0 < K; k0 += 16) {
        #pragma unroll
        for (int i = 0; i < 4; ++i) {
            int idx = tid + i * 256;
            int r = idx >> 4;
            int c = idx & 15;
            int gm = bm + r;
            As[c][r] = (gm < M) ? A[(size_t)gm * K + k0 + c] : 0.f;
        }
        #pragma unroll
        for (int i = 0; i < 4; ++i) {
            int idx = tid + i * 256;
            int r = idx >> 6;
            int c = idx & 63;
            int gn = bn + c;
            Bs[r][c] = (gn < N) ? W[(size_t)(k0 + r) * N + gn] : 0.f;
        }
        __syncthreads();
        #pragma unroll
        for (int kk = 0; kk < 16; ++kk) {
            float a[4], b[4];
            #pragma unroll
            for (int i = 0; i < 4; ++i) a[i] = As[kk][ty * 4 + i];
            #pragma unroll
            for (int j = 0; j < 4; ++j) b[j] = Bs[kk][tx * 4 + j];
            #pragma unroll
            for (int i = 0; i < 4; ++i)
                #pragma unroll
                for (int j = 0; j < 4; ++j)
                    acc[i][j] = fmaf(a[i], b[j], acc[i][j]);
        }
        __syncthreads();
    }

    #pragma unroll
    for (int i = 0; i < 4; ++i) {
        int gm = bm + ty * 4 + i;
        if (gm >= M) continue;
        #pragma unroll
        for (int j = 0; j < 4; ++j) {
            int gn = bn + tx * 4 + j;
            if (gn >= N) continue;
            float v = acc[i][j] + (bias ? bias[gn] : 0.f);
            v *= alpha;
            if (gelu_flag) v = 0.5f * v * (1.0f + erff(v * 0.70710678118654752f));
            if (res) v += res[(size_t)gm * N + gn];
            C[(size_t)gm * N + gn] = v;
        }
    }
}

// ---------------------------------------------------------------------------
// LayerNorm (+optional add, +optional FiLM); fp32 in, fp32 and/or bf16 out
// ---------------------------------------------------------------------------
__global__ __launch_bounds__(256) void ln_kernel(
    const float* __restrict__ X, const float* __restrict__ X2,
    const float* __restrict__ s, const float* __restrict__ b,
    float* __restrict__ Yf, unsigned short* __restrict__ Yb,
    int D, const float* __restrict__ film, int rows_per_batch)
{
    const int row = blockIdx.x;
    const int tid = threadIdx.x;
    const float* x = X + (size_t)row * D;
    const float* x2 = X2 ? X2 + (size_t)row * D : nullptr;

    float sum = 0.f, sq = 0.f;
    for (int c = tid; c < D; c += 256) {
        float v = x[c] + (x2 ? x2[c] : 0.f);
        sum += v; sq += v * v;
    }
    __shared__ float r1[4], r2[4];
    __shared__ float s_mean, s_rstd;
    for (int off = 32; off > 0; off >>= 1) {
        sum += __shfl_down(sum, off);
        sq  += __shfl_down(sq,  off);
    }
    if ((tid & 63) == 0) { r1[tid >> 6] = sum; r2[tid >> 6] = sq; }
    __syncthreads();
    if (tid == 0) {
        float ts = r1[0] + r1[1] + r1[2] + r1[3];
        float tq = r2[0] + r2[1] + r2[2] + r2[3];
        float mean = ts / (float)D;
        float var = tq / (float)D - mean * mean;
        s_mean = mean;
        s_rstd = rsqrtf(var + 1e-5f);
    }
    __syncthreads();
    const float mean = s_mean, rstd = s_rstd;
    const float* fa = nullptr; const float* fb = nullptr;
    if (film) {
        int batch = row / rows_per_batch;
        fa = film + (size_t)batch * 2 * D;
        fb = fa + D;
    }
    for (int c = tid; c < D; c += 256) {
        float v = x[c] + (x2 ? x2[c] : 0.f);
        float y = (v - mean) * rstd * s[c] + b[c];
        if (film) y = fa[c] * y + fb[c];
        if (Yf) Yf[(size_t)row * D + c] = y;
        if (Yb) Yb[(size_t)row * D + c] = f2b(y);
    }
}

__global__ void temb_kernel(const float* __restrict__ t, float* __restrict__ temb,
                            unsigned short* __restrict__ tembb)
{
    int b = blockIdx.x;
    int i = threadIdx.x;
    float f = expf((float)i * (-9.210340371976184f / 255.0f));
    float a = t[b] * f;
    float sv = sinf(a), cv = cosf(a);
    temb[b * 512 + i]        = sv;
    temb[b * 512 + 256 + i]  = cv;
    tembb[b * 512 + i]       = f2b(sv);
    tembb[b * 512 + 256 + i] = f2b(cv);
}

__global__ void embed_kernel(const int* __restrict__ x, const float* __restrict__ temb,
                             const float* __restrict__ embed,
                             float* __restrict__ l2r, float* __restrict__ r2l)
{
    const int i = blockIdx.x;
    const int b = blockIdx.y;
    const int d = blockIdx.z;
    float* out = (d == 0 ? l2r : r2l) + ((size_t)(b * 1024 + i) * 512);
    const float* src;
    if (d == 0) src = (i == 0)    ? temb + b * 512 : embed + (size_t)x[b * 1024 + (i - 1)] * 512;
    else        src = (i == 1023) ? temb + b * 512 : embed + (size_t)x[b * 1024 + (i + 1)] * 512;
    for (int e = threadIdx.x; e < 512; e += 256) {
        int j = e >> 1;
        float div = expf((float)(2 * j) * (-9.210340371976184f / 512.0f));
        float ang = (float)i * div;
        float pe = (e & 1) ? cosf(ang) : sinf(ang);
        out[e] = src[e] + pe;
    }
}

__global__ void add_kernel(const float* __restrict__ A, const float* __restrict__ B,
                           float* __restrict__ C, int n)
{
    int i = blockIdx.x * blockDim.x + threadIdx.x;
    int stride = gridDim.x * blockDim.x;
    for (; i < n; i += stride) C[i] = A[i] + B[i];
}

__global__ void add_bf16(const unsigned int* __restrict__ A,
                         const unsigned int* __restrict__ B,
                         unsigned int* __restrict__ C, int nwords)
{
    int i = blockIdx.x * blockDim.x + threadIdx.x;
    int stride = gridDim.x * blockDim.x;
    for (; i < nwords; i += stride) {
        unsigned int a = A[i], b = B[i];
        float lo = __uint_as_float(a << 16) + __uint_as_float(b << 16);
        float hi = __uint_as_float(a & 0xffff0000u) + __uint_as_float(b & 0xffff0000u);
        C[i] = (unsigned int)f2b(lo) | ((unsigned int)f2b(hi) << 16);
    }
}

__global__ void build_allv_b(const unsigned short* __restrict__ tembb,
                             const unsigned short* __restrict__ l2rn,
                             const unsigned short* __restrict__ r2ln,
                             unsigned short* __restrict__ allv)
{
    const int k = blockIdx.x;
    const int b = blockIdx.y;
    unsigned short* out = allv + ((size_t)b * 2080 + k) * 512;
    const unsigned short* src;
    if (k == 0)         src = tembb + b * 512;
    else if (k <= 1024) src = l2rn + ((size_t)(b * 1024 + (k - 1)) * 512);
    else                src = r2ln + ((size_t)(b * 1024 + (k - 1025)) * 512);
    ((uint4*)out)[threadIdx.x] = ((const uint4*)src)[threadIdx.x];
}

// ---------------------------------------------------------------------------
// MFMA flash attention, bf16 in/out, fp32 accumulate.
// One block = (b, h, 64-q tile); 4 waves x 16 q-rows each; KV tile = 64.
// mode 0: k<=q; mode 1: k>=q; mode 2: cross (2049 keys, batch stride 2080)
// LDS rows padded to 72 shorts (36 dwords == 4 mod 32 banks -> conflict-free).
// Fragment layouts (mfma_f32_16x16x32_bf16):
//   A: row=lane&15, k-span=(lane>>4)*8 ; B: col=lane&15, k-span=(lane>>4)*8
//   C: col=lane&15, row=(lane>>4)*4+reg
// ---------------------------------------------------------------------------
__global__ __launch_bounds__(256) void attn_mfma(
    const unsigned short* __restrict__ Q, const unsigned short* __restrict__ K,
    const unsigned short* __restrict__ V, unsigned short* __restrict__ O, int mode)
{
    const int E = 512;
    const int LKP = (mode == 2) ? 2080 : 1024;
    const int qt = blockIdx.x, h = blockIdx.y, b = blockIdx.z;
    const int q0 = qt * 64;
    const int tid = threadIdx.x;
    const int wid = tid >> 6, lane = tid & 63;
    const int fr = lane & 15;       // A/B row-col within 16
    const int fs = lane >> 4;       // k-span selector / C row group
    const int wq0 = q0 + wid * 16;  // this wave's first q row

    __shared__ unsigned short Qs[64][72];
    __shared__ unsigned short Ks[64][72];
    __shared__ unsigned short VTs[64][72];
    __shared__ unsigned short Ps[4][16][72];

    // ---- stage Q tile (64 rows x 64 dh) ----
    {
        const unsigned short* Qbase = Q + ((size_t)b * 1024 + q0) * E + h * 64;
        #pragma unroll
        for (int it = 0; it < 2; ++it) {
            int i = tid + it * 256;
            int r = i >> 3, c = i & 7;
            *(uint4*)&Qs[r][c * 8] = *(const uint4*)(Qbase + (size_t)r * E + c * 8);
        }
    }

    float m_r[4], l_r[4];
    f32x4 o_acc[4] = {};
    #pragma unroll
    for (int r = 0; r < 4; ++r) { m_r[r] = NEGF; l_r[r] = 0.f; }

    int kt0, kt1;
    if (mode == 0)      { kt0 = 0;  kt1 = qt; }
    else if (mode == 1) { kt0 = qt; kt1 = 15; }
    else                { kt0 = 0;  kt1 = 31; }

    for (int kt = kt0; kt <= kt1; ++kt) {
        if (mode == 2) {
            if (kt >= 1 && kt <= 15 && 64 * kt + 62 <= q0) continue;
            if (kt >= 17 && 64 * kt - 1025 >= q0 + 63) continue;
        }
        const int k0 = kt * 64;

        __syncthreads();   // previous tile's reads complete

        // ---- stage K (row-major) and V (transposed) ----
        {
            const unsigned short* Kbase = K + ((size_t)b * LKP + k0) * E + h * 64;
            const unsigned short* Vbase = V + ((size_t)b * LKP + k0) * E + h * 64;
            #pragma unroll
            for (int it = 0; it < 2; ++it) {
                int i = tid + it * 256;
                int r = i >> 3, c = i & 7;
                *(uint4*)&Ks[r][c * 8] = *(const uint4*)(Kbase + (size_t)r * E + c * 8);
                uint4 vw = *(const uint4*)(Vbase + (size_t)r * E + c * 8);
                unsigned short tmp[8];
                *(uint4*)tmp = vw;
                #pragma unroll
                for (int j = 0; j < 8; ++j) VTs[c * 8 + j][r] = tmp[j];
            }
        }
        __syncthreads();

        // ---- S = Q K^T : 4 C-tiles x 2 k-halves ----
        bf16x8 aq0 = *(const bf16x8*)&Qs[wid * 16 + fr][fs * 8];
        bf16x8 aq1 = *(const bf16x8*)&Qs[wid * 16 + fr][fs * 8 + 32];
        f32x4 s[4] = {};
        #pragma unroll
        for (int t = 0; t < 4; ++t) {
            bf16x8 bk0 = *(const bf16x8*)&Ks[t * 16 + fr][fs * 8];
            bf16x8 bk1 = *(const bf16x8*)&Ks[t * 16 + fr][fs * 8 + 32];
            s[t] = __builtin_amdgcn_mfma_f32_16x16x32_bf16(aq0, bk0, s[t], 0, 0, 0);
            s[t] = __builtin_amdgcn_mfma_f32_16x16x32_bf16(aq1, bk1, s[t], 0, 0, 0);
        }

        // ---- mask ----
        #pragma unroll
        for (int t = 0; t < 4; ++t) {
            #pragma unroll
            for (int r = 0; r < 4; ++r) {
                int q = wq0 + fs * 4 + r;
                int k = k0 + t * 16 + fr;
                bool valid;
                if (mode == 0)      valid = (k <= q);
                else if (mode == 1) valid = (k >= q);
                else valid = (k == 0) || (k <= 1024 ? (k - 1) > q : (k - 1025) < q);
                if (!valid) s[t][r] = NEGF;
            }
        }

        // ---- online softmax (row = fs*4+r; 64 k-values live in 16-lane group) ----
        float c_[4], rs[4];
        #pragma unroll
        for (int r = 0; r < 4; ++r) {
            float v = fmaxf(fmaxf(s[0][r], s[1][r]), fmaxf(s[2][r], s[3][r]));
            v = fmaxf(v, __shfl_xor(v, 1));
            v = fmaxf(v, __shfl_xor(v, 2));
            v = fmaxf(v, __shfl_xor(v, 4));
            v = fmaxf(v, __shfl_xor(v, 8));
            float mnew = fmaxf(m_r[r], v);
            c_[r] = exp2f((m_r[r] - mnew) * LOG2E);
            m_r[r] = mnew;
            rs[r] = 0.f;
        }
        #pragma unroll
        for (int t = 0; t < 4; ++t) {
            #pragma unroll
            for (int r = 0; r < 4; ++r) {
                float p = exp2f((s[t][r] - m_r[r]) * LOG2E);
                s[t][r] = p;
                rs[r] += p;
            }
        }
        #pragma unroll
        for (int r = 0; r < 4; ++r) {
            float v = rs[r];
            v += __shfl_xor(v, 1);
            v += __shfl_xor(v, 2);
            v += __shfl_xor(v, 4);
            v += __shfl_xor(v, 8);
            l_r[r] = l_r[r] * c_[r] + v;
            o_acc[0][r] *= c_[r]; o_acc[1][r] *= c_[r];
            o_acc[2][r] *= c_[r]; o_acc[3][r] *= c_[r];
        }

        // ---- P -> bf16, re-fragment via wave-private LDS ----
        #pragma unroll
        for (int t = 0; t < 4; ++t)
            #pragma unroll
            for (int r = 0; r < 4; ++r)
                Ps[wid][fs * 4 + r][t * 16 + fr] = f2b(s[t][r]);
        __syncthreads();

        // ---- O += P V ----
        bf16x8 pa0 = *(const bf16x8*)&Ps[wid][fr][fs * 8];
        bf16x8 pa1 = *(const bf16x8*)&Ps[wid][fr][fs * 8 + 32];
        #pragma unroll
        for (int t = 0; t < 4; ++t) {
            bf16x8 bv0 = *(const bf16x8*)&VTs[t * 16 + fr][fs * 8];
            bf16x8 bv1 = *(const bf16x8*)&VTs[t * 16 + fr][fs * 8 + 32];
            o_acc[t] = __builtin_amdgcn_mfma_f32_16x16x32_bf16(pa0, bv0, o_acc[t], 0, 0, 0);
            o_acc[t] = __builtin_amdgcn_mfma_f32_16x16x32_bf16(pa1, bv1, o_acc[t], 0, 0, 0);
        }
    }

    // ---- epilogue: O = acc / l  (row = fs*4+r, dh = t*16+fr) ----
    unsigned short* Obase = O + ((size_t)b * 1024 + q0) * E + h * 64;
    float invl[4];
    #pragma unroll
    for (int r = 0; r < 4; ++r) invl[r] = 1.f / l_r[r];
    #pragma unroll
    for (int t = 0; t < 4; ++t)
        #pragma unroll
        for (int r = 0; r < 4; ++r)
            Obase[(size_t)(wid * 16 + fs * 4 + r) * E + t * 16 + fr] =
                f2b(o_acc[t][r] * invl[r]);
}

// ---------------------------------------------------------------------------

static inline void gemm(hipStream_t st, const float* A, const float* W, const float* bias,
                        const float* res, float* C, int M, int N, int K,
                        float alpha, int gelu)
{
    dim3 g((N + 63) / 64, (M + 63) / 64);
    gemm_f32<<<g, dim3(256), 0, st>>>(A, W, bias, res, C, M, N, K, alpha, gelu);
}

static inline void gemmb(hipStream_t st, const unsigned short* A, const unsigned short* Wt,
                         const float* bias, const float* res, float* Cf,
                         unsigned short* Cb, int M, int N, int K, float alpha, int gelu)
{
    dim3 g(N / 128, M / 128);
    gemm_bf16<<<g, dim3(256), 0, st>>>(A, Wt, bias, res, Cf, Cb, M, N, K, alpha, gelu);
}

extern "C" void kernel_launch(void* const* d_in, const int* in_sizes, int n_in,
                              void* d_out, int out_size, void* d_ws, size_t ws_size,
                              hipStream_t stream)
{
    const int*   x      = (const int*)  d_in[0];
    const float* t      = (const float*)d_in[1];
    const float* embedW = (const float*)d_in[2];
    const float* attn_W = (const float*)d_in[3];
    const float* attn_b = (const float*)d_in[4];
    const float* ln_s   = (const float*)d_in[5];
    const float* ln_b   = (const float*)d_in[6];
    const float* mlp_W1 = (const float*)d_in[7];
    const float* mlp_b1 = (const float*)d_in[8];
    const float* mlp_W2 = (const float*)d_in[9];
    const float* mlp_b2 = (const float*)d_in[10];
    const float* ca_Wq  = (const float*)d_in[11];
    const float* ca_Wk  = (const float*)d_in[12];
    const float* ca_bk  = (const float*)d_in[13];
    const float* ca_Wv  = (const float*)d_in[14];
    const float* ca_bv  = (const float*)d_in[15];
    const float* ca_Wo  = (const float*)d_in[16];
    const float* ca_bo  = (const float*)d_in[17];
    const float* ro1s   = (const float*)d_in[18];
    const float* ro1b   = (const float*)d_in[19];
    const float* ro2s   = (const float*)d_in[20];
    const float* ro2b   = (const float*)d_in[21];
    const float* in_W   = (const float*)d_in[22];
    const float* in_b   = (const float*)d_in[23];
    const float* tm_W1  = (const float*)d_in[24];
    const float* tm_b1  = (const float*)d_in[25];
    const float* tm_W2  = (const float*)d_in[26];
    const float* tm_b2  = (const float*)d_in[27];
    const float* res_W1 = (const float*)d_in[28];
    const float* res_b1 = (const float*)d_in[29];
    const float* res_W2 = (const float*)d_in[30];
    const float* res_b2 = (const float*)d_in[31];
    const float* rls    = (const float*)d_in[32];
    const float* rlb    = (const float*)d_in[33];
    const float* film_W = (const float*)d_in[34];
    const float* film_b = (const float*)d_in[35];
    const float* out_W  = (const float*)d_in[36];
    const float* out_b  = (const float*)d_in[37];
    float* out = (float*)d_out;
    (void)ws_size; (void)in_sizes; (void)n_in; (void)out_size;

    char* base = (char*)d_ws;
    size_t off = 0;
    auto alloc = [&](size_t bytes) -> char* {
        char* p = base + off;
        off = (off + bytes + 255) & ~(size_t)255;
        return p;
    };
    float* TEMB  = (float*)alloc(8192);
    float* TM1   = (float*)alloc(32768);
    float* T4    = (float*)alloc(32768);
    float* FILM  = (float*)alloc(32768);
    unsigned short* TEMBb = (unsigned short*)alloc(4096);

    float* L2R = (float*)alloc(8388608);
    float* R2L = (float*)alloc(8388608);
    float* Z   = (float*)alloc(8388608);
    float* H2  = (float*)alloc(16777216);
    float* Z2  = (float*)alloc(16777216);

    unsigned short* Zb  = (unsigned short*)alloc(4194304);
    unsigned short* Qb  = (unsigned short*)alloc(4194304);
    unsigned short* Kb  = (unsigned short*)alloc(4194304);
    unsigned short* Vb  = (unsigned short*)alloc(4194304);
    unsigned short* Ob  = (unsigned short*)alloc(4194304);
    unsigned short* H2b = (unsigned short*)alloc(8388608);

    unsigned short* BIG = (unsigned short*)alloc(25559040);
    unsigned short* MIDb  = BIG;
    unsigned short* ALLVb = BIG;
    unsigned short* K2b   = BIG + 4259840;
    unsigned short* V2b   = BIG + 8519680;

    unsigned short* WT = (unsigned short*)alloc(45613056);
    const size_t wt_attn = 0,        wt_mlp1 = 4194304, wt_mlp2 = 8388608;
    const size_t wt_caq = 12582912,  wt_cak = 12845056, wt_cav = 13107200,
                 wt_cao = 13369344,  wt_in  = 13631488;
    const size_t wt_res1 = 14155776, wt_res2 = 18350080, wt_out = 22544384;

    wconv<<<dim3(8, 8, 16), 256, 0, stream>>>(attn_W, WT + wt_attn, 512, 512, 262144, 262144);
    wconv<<<dim3(32, 8, 4), 256, 0, stream>>>(mlp_W1, WT + wt_mlp1, 512, 2048, 1048576, 1048576);
    wconv<<<dim3(8, 32, 4), 256, 0, stream>>>(mlp_W2, WT + wt_mlp2, 2048, 512, 1048576, 1048576);
    wconv<<<dim3(8, 8), 256, 0, stream>>>(ca_Wq, WT + wt_caq, 512, 512, 0, 0);
    wconv<<<dim3(8, 8), 256, 0, stream>>>(ca_Wk, WT + wt_cak, 512, 512, 0, 0);
    wconv<<<dim3(8, 8), 256, 0, stream>>>(ca_Wv, WT + wt_cav, 512, 512, 0, 0);
    wconv<<<dim3(8, 8), 256, 0, stream>>>(ca_Wo, WT + wt_cao, 512, 512, 0, 0);
    wconv<<<dim3(16, 8), 256, 0, stream>>>(in_W, WT + wt_in, 512, 1024, 0, 0);
    wconv<<<dim3(32, 16, 2), 256, 0, stream>>>(res_W1, WT + wt_res1, 1024, 2048, 2097152, 2097152);
    wconv<<<dim3(16, 32, 2), 256, 0, stream>>>(res_W2, WT + wt_res2, 2048, 1024, 2097152, 2097152);
    wconv<<<dim3(4, 16), 256, 0, stream>>>(out_W, WT + wt_out, 1024, 256, 0, 0);

    temb_kernel<<<dim3(4), dim3(256), 0, stream>>>(t, TEMB, TEMBb);
    embed_kernel<<<dim3(1024, 4, 2), dim3(256), 0, stream>>>(x, TEMB, embedW, L2R, R2L);

    for (int d = 0; d < 2; ++d) {
        float* h = (d == 0) ? L2R : R2L;
        for (int l = 0; l < 2; ++l) {
            const int dl = d * 2 + l;
            ln_kernel<<<4096, 256, 0, stream>>>(h, nullptr, ln_s + (dl * 2 + 0) * 512,
                                                ln_b + (dl * 2 + 0) * 512, nullptr, Zb,
                                                512, nullptr, 1024);
            gemmb(stream, Zb, WT + wt_attn + (size_t)(dl * 4 + 0) * 262144,
                  attn_b + (dl * 4 + 0) * 512, nullptr, nullptr, Qb, 4096, 512, 512, 0.125f, 0);
            gemmb(stream, Zb, WT + wt_attn + (size_t)(dl * 4 + 1) * 262144,
                  attn_b + (dl * 4 + 1) * 512, nullptr, nullptr, Kb, 4096, 512, 512, 1.f, 0);
            gemmb(stream, Zb, WT + wt_attn + (size_t)(dl * 4 + 2) * 262144,
                  attn_b + (dl * 4 + 2) * 512, nullptr, nullptr, Vb, 4096, 512, 512, 1.f, 0);
            attn_mfma<<<dim3(16, 8, 4), dim3(256), 0, stream>>>(Qb, Kb, Vb, Ob, d);
            gemmb(stream, Ob, WT + wt_attn + (size_t)(dl * 4 + 3) * 262144,
                  attn_b + (dl * 4 + 3) * 512, h, h, nullptr, 4096, 512, 512, 1.f, 0);
            ln_kernel<<<4096, 256, 0, stream>>>(h, nullptr, ln_s + (dl * 2 + 1) * 512,
                                                ln_b + (dl * 2 + 1) * 512, nullptr, Zb,
                                                512, nullptr, 1024);
            gemmb(stream, Zb, WT + wt_mlp1 + (size_t)dl * 1048576, mlp_b1 + dl * 2048,
                  nullptr, nullptr, MIDb, 4096, 2048, 512, 1.f, 1);
            gemmb(stream, MIDb, WT + wt_mlp2 + (size_t)dl * 1048576, mlp_b2 + dl * 512,
                  h, h, nullptr, 4096, 512, 2048, 1.f, 0);
        }
    }

    add_kernel<<<2048, 256, 0, stream>>>(L2R, R2L, Z, 2097152);
    ln_kernel<<<4096, 256, 0, stream>>>(L2R, nullptr, ro1s, ro1b, nullptr, Qb, 512, nullptr, 1024);
    ln_kernel<<<4096, 256, 0, stream>>>(R2L, nullptr, ro2s, ro2b, nullptr, Kb, 512, nullptr, 1024);
    add_bf16<<<1024, 256, 0, stream>>>((const unsigned int*)Qb, (const unsigned int*)Kb,
                                       (unsigned int*)Vb, 1048576);
    build_allv_b<<<dim3(2049, 4), 64, 0, stream>>>(TEMBb, Qb, Kb, ALLVb);
    gemmb(stream, Vb, WT + wt_caq, nullptr, nullptr, nullptr, Zb, 4096, 512, 512, 0.125f, 0);
    gemmb(stream, ALLVb, WT + wt_cak, ca_bk, nullptr, nullptr, K2b, 8320, 512, 512, 1.f, 0);
    gemmb(stream, ALLVb, WT + wt_cav, ca_bv, nullptr, nullptr, V2b, 8320, 512, 512, 1.f, 0);
    attn_mfma<<<dim3(16, 8, 4), dim3(256), 0, stream>>>(Zb, K2b, V2b, Ob, 2);
    gemmb(stream, Ob, WT + wt_cao, ca_bo, Z, nullptr, Qb, 4096, 512, 512, 1.f, 0);

    gemm(stream, TEMB, tm_W1, tm_b1, nullptr, TM1, 4, 2048, 512, 1.f, 1);
    gemm(stream, TM1, tm_W2, tm_b2, nullptr, T4, 4, 2048, 2048, 1.f, 0);

    gemmb(stream, Qb, WT + wt_in, in_b, nullptr, H2, H2b, 4096, 1024, 512, 1.f, 0);
    for (int i = 0; i < 2; ++i) {
        gemm(stream, T4, film_W + (size_t)i * 4194304, film_b + i * 2048,
             nullptr, FILM, 4, 2048, 2048, 1.f, 0);
        gemmb(stream, H2b, WT + wt_res1 + (size_t)i * 2097152, res_b1 + i * 2048,
              nullptr, nullptr, MIDb, 4096, 2048, 1024, 1.f, 1);
        gemmb(stream, MIDb, WT + wt_res2 + (size_t)i * 2097152, res_b2 + i * 1024,
              nullptr, Z2, nullptr, 4096, 1024, 2048, 1.f, 0);
        ln_kernel<<<4096, 256, 0, stream>>>(H2, Z2, rls + i * 1024, rlb + i * 1024,
                                            H2, H2b, 1024, FILM, 1024);
    }

    gemmb(stream, H2b, WT + wt_out, out_b, nullptr, out, nullptr, 4096, 256, 1024, 1.f, 0);
}

// Round 5
// 1847.895 us; speedup vs baseline: 8.4651x; 1.3328x over previous
//
#include <hip/hip_runtime.h>
#include <hip/hip_bf16.h>

// ---------------------------------------------------------------------------
// B=4, L=1024, E=512, H=8, NL=2, M=2048, S=256, R=2, Dh=64
// ---------------------------------------------------------------------------

#define NEGF -3.4028235e38f
#define LOG2E 1.4426950408889634f

using bf16x8 = __attribute__((ext_vector_type(8))) short;
using f32x4  = __attribute__((ext_vector_type(4))) float;

__device__ inline float bf2f(unsigned short u) {
    return __uint_as_float(((unsigned int)u) << 16);
}
__device__ inline unsigned short f2b(float f) {
    unsigned int u = __float_as_uint(f);
    return (unsigned short)((u + 0x7fff + ((u >> 16) & 1)) >> 16);
}

// global -> LDS async copy, 16 B per lane
__device__ inline void gl_lds16(const void* g, void* l) {
    __builtin_amdgcn_global_load_lds(
        (const __attribute__((address_space(1))) void*)(uintptr_t)g,
        (__attribute__((address_space(3))) void*)(unsigned int)(uintptr_t)l,
        16, 0, 0);
}

// ---------------------------------------------------------------------------
// bf16 MFMA GEMM: C = epi(A[M,K] @ W[K,N]) with Wt = W^T stored [N][K] bf16.
// 128x128 tile, BK=32, 4 waves (2x2), wave tile 64x64 (4x4 16x16 frags).
// ---------------------------------------------------------------------------
__global__ __launch_bounds__(256) void gemm_bf16(
    const unsigned short* __restrict__ A, const unsigned short* __restrict__ Wt,
    const float* __restrict__ bias, const float* __restrict__ res,
    float* __restrict__ Cf, unsigned short* __restrict__ Cb,
    int M, int N, int K, float alpha, int gelu_flag)
{
    __shared__ unsigned short As[4096];
    __shared__ unsigned short Bs[4096];
    const int tid  = threadIdx.x;
    const int wid  = tid >> 6, lane = tid & 63;
    const int wy   = wid >> 1, wx = wid & 1;
    const int koff = lane >> 4, l16 = lane & 15;
    const int m0 = blockIdx.y * 128, n0 = blockIdx.x * 128;

    const int c0 = tid, c1 = tid + 256;
    const int rA0 = ((c0 >> 6) << 4) | (c0 & 15), kA0 = ((c0 >> 4) & 3) << 3;
    const int rA1 = ((c1 >> 6) << 4) | (c1 & 15), kA1 = ((c1 >> 4) & 3) << 3;

    const unsigned short* a0 = A  + (size_t)(m0 + rA0) * K + kA0;
    const unsigned short* a1 = A  + (size_t)(m0 + rA1) * K + kA1;
    const unsigned short* b0 = Wt + (size_t)(n0 + rA0) * K + kA0;
    const unsigned short* b1 = Wt + (size_t)(n0 + rA1) * K + kA1;

    unsigned short* ldsA0 = As + (size_t)(wid * 64) * 8;
    unsigned short* ldsA1 = As + (size_t)(256 + wid * 64) * 8;
    unsigned short* ldsB0 = Bs + (size_t)(wid * 64) * 8;
    unsigned short* ldsB1 = Bs + (size_t)(256 + wid * 64) * 8;

    f32x4 acc[4][4] = {};

    for (int k0 = 0; k0 < K; k0 += 32) {
        gl_lds16(a0 + k0, ldsA0);
        gl_lds16(a1 + k0, ldsA1);
        gl_lds16(b0 + k0, ldsB0);
        gl_lds16(b1 + k0, ldsB1);
        __syncthreads();

        bf16x8 af[4], bfr[4];
        const int foff = (koff * 16 + l16) * 8;
        #pragma unroll
        for (int i = 0; i < 4; ++i)
            af[i] = *(const bf16x8*)(As + (size_t)((wy * 4 + i) * 64) * 8 + foff);
        #pragma unroll
        for (int j = 0; j < 4; ++j)
            bfr[j] = *(const bf16x8*)(Bs + (size_t)((wx * 4 + j) * 64) * 8 + foff);

        #pragma unroll
        for (int i = 0; i < 4; ++i)
            #pragma unroll
            for (int j = 0; j < 4; ++j)
                acc[i][j] = __builtin_amdgcn_mfma_f32_16x16x32_bf16(
                    af[i], bfr[j], acc[i][j], 0, 0, 0);
        __syncthreads();
    }

    #pragma unroll
    for (int i = 0; i < 4; ++i) {
        const int rbase = m0 + wy * 64 + i * 16 + koff * 4;
        #pragma unroll
        for (int j = 0; j < 4; ++j) {
            const int gn = n0 + wx * 64 + j * 16 + l16;
            const float bs = bias ? bias[gn] : 0.f;
            #pragma unroll
            for (int r = 0; r < 4; ++r) {
                float v = (acc[i][j][r] + bs) * alpha;
                if (gelu_flag) v = 0.5f * v * (1.0f + erff(v * 0.70710678118654752f));
                const size_t idx = (size_t)(rbase + r) * N + gn;
                if (res) v += res[idx];
                if (Cf) Cf[idx] = v;
                if (Cb) Cb[idx] = f2b(v);
            }
        }
    }
}

// ---------------------------------------------------------------------------
// weight transpose-convert: src fp32 [K][N] -> dst bf16 [N][K]
// ---------------------------------------------------------------------------
__global__ __launch_bounds__(256) void wconv(
    const float* __restrict__ src, unsigned short* __restrict__ dst,
    int K, int N, long sstride, long dstride)
{
    __shared__ float t[64][65];
    const int n0 = blockIdx.x * 64, k0 = blockIdx.y * 64;
    const float* s = src + (size_t)blockIdx.z * sstride;
    unsigned short* d = dst + (size_t)blockIdx.z * dstride;
    const int tid = threadIdx.x;
    #pragma unroll
    for (int i = 0; i < 4; ++i) {
        int lin = i * 1024 + tid * 4;
        int r = lin >> 6, c = lin & 63;
        float4 v = *(const float4*)(s + (size_t)(k0 + r) * N + n0 + c);
        t[r][c] = v.x; t[r][c + 1] = v.y; t[r][c + 2] = v.z; t[r][c + 3] = v.w;
    }
    __syncthreads();
    #pragma unroll
    for (int i = 0; i < 8; ++i) {
        int lin = i * 512 + tid * 2;
        int rn = lin >> 6, ck = lin & 63;
        ushort2 o;
        o.x = f2b(t[ck][rn]); o.y = f2b(t[ck + 1][rn]);
        *(ushort2*)(d + (size_t)(n0 + rn) * K + k0 + ck) = o;
    }
}

// ---------------------------------------------------------------------------
// Skinny GEMM for M=4 (t-MLP / FiLM): C[4,N] = epi(A[4,K] @ W[K,N] + bias)
// Stage 1: split-K partials. grid (N/256, K/32); thread owns one column.
// Stage 2: reduce partials + epilogue. grid (N/256, 4).
// Deterministic (no atomics).
// ---------------------------------------------------------------------------
__global__ __launch_bounds__(256) void skinny_k(
    const float* __restrict__ A, const float* __restrict__ W,
    float* __restrict__ P, int N, int K)
{
    const int n = blockIdx.x * 256 + threadIdx.x;
    const int s = blockIdx.y;
    const int k0 = s * 32;
    float a0 = 0.f, a1 = 0.f, a2 = 0.f, a3 = 0.f;
    #pragma unroll 8
    for (int k = k0; k < k0 + 32; ++k) {
        float w = W[(size_t)k * N + n];
        a0 = fmaf(A[k], w, a0);
        a1 = fmaf(A[K + k], w, a1);
        a2 = fmaf(A[2 * K + k], w, a2);
        a3 = fmaf(A[3 * K + k], w, a3);
    }
    float* p = P + (size_t)s * 4 * N;
    p[n] = a0; p[N + n] = a1; p[2 * N + n] = a2; p[3 * N + n] = a3;
}

__global__ __launch_bounds__(256) void skinny_red(
    const float* __restrict__ P, const float* __restrict__ bias,
    float* __restrict__ C, int N, int nsplit, int gelu_flag)
{
    const int n = blockIdx.x * 256 + threadIdx.x;
    const int r = blockIdx.y;
    float acc = 0.f;
    for (int s = 0; s < nsplit; ++s) acc += P[((size_t)s * 4 + r) * N + n];
    float v = acc + (bias ? bias[n] : 0.f);
    if (gelu_flag) v = 0.5f * v * (1.0f + erff(v * 0.70710678118654752f));
    C[(size_t)r * N + n] = v;
}

// ---------------------------------------------------------------------------
// LayerNorm (+optional add, +optional FiLM); fp32 in, fp32 and/or bf16 out
// ---------------------------------------------------------------------------
__global__ __launch_bounds__(256) void ln_kernel(
    const float* __restrict__ X, const float* __restrict__ X2,
    const float* __restrict__ s, const float* __restrict__ b,
    float* __restrict__ Yf, unsigned short* __restrict__ Yb,
    int D, const float* __restrict__ film, int rows_per_batch)
{
    const int row = blockIdx.x;
    const int tid = threadIdx.x;
    const float* x = X + (size_t)row * D;
    const float* x2 = X2 ? X2 + (size_t)row * D : nullptr;

    float sum = 0.f, sq = 0.f;
    for (int c = tid; c < D; c += 256) {
        float v = x[c] + (x2 ? x2[c] : 0.f);
        sum += v; sq += v * v;
    }
    __shared__ float r1[4], r2[4];
    __shared__ float s_mean, s_rstd;
    for (int off = 32; off > 0; off >>= 1) {
        sum += __shfl_down(sum, off);
        sq  += __shfl_down(sq,  off);
    }
    if ((tid & 63) == 0) { r1[tid >> 6] = sum; r2[tid >> 6] = sq; }
    __syncthreads();
    if (tid == 0) {
        float ts = r1[0] + r1[1] + r1[2] + r1[3];
        float tq = r2[0] + r2[1] + r2[2] + r2[3];
        float mean = ts / (float)D;
        float var = tq / (float)D - mean * mean;
        s_mean = mean;
        s_rstd = rsqrtf(var + 1e-5f);
    }
    __syncthreads();
    const float mean = s_mean, rstd = s_rstd;
    const float* fa = nullptr; const float* fb = nullptr;
    if (film) {
        int batch = row / rows_per_batch;
        fa = film + (size_t)batch * 2 * D;
        fb = fa + D;
    }
    for (int c = tid; c < D; c += 256) {
        float v = x[c] + (x2 ? x2[c] : 0.f);
        float y = (v - mean) * rstd * s[c] + b[c];
        if (film) y = fa[c] * y + fb[c];
        if (Yf) Yf[(size_t)row * D + c] = y;
        if (Yb) Yb[(size_t)row * D + c] = f2b(y);
    }
}

__global__ void temb_kernel(const float* __restrict__ t, float* __restrict__ temb,
                            unsigned short* __restrict__ tembb)
{
    int b = blockIdx.x;
    int i = threadIdx.x;
    float f = expf((float)i * (-9.210340371976184f / 255.0f));
    float a = t[b] * f;
    float sv = sinf(a), cv = cosf(a);
    temb[b * 512 + i]        = sv;
    temb[b * 512 + 256 + i]  = cv;
    tembb[b * 512 + i]       = f2b(sv);
    tembb[b * 512 + 256 + i] = f2b(cv);
}

__global__ void embed_kernel(const int* __restrict__ x, const float* __restrict__ temb,
                             const float* __restrict__ embed,
                             float* __restrict__ l2r, float* __restrict__ r2l)
{
    const int i = blockIdx.x;
    const int b = blockIdx.y;
    const int d = blockIdx.z;
    float* out = (d == 0 ? l2r : r2l) + ((size_t)(b * 1024 + i) * 512);
    const float* src;
    if (d == 0) src = (i == 0)    ? temb + b * 512 : embed + (size_t)x[b * 1024 + (i - 1)] * 512;
    else        src = (i == 1023) ? temb + b * 512 : embed + (size_t)x[b * 1024 + (i + 1)] * 512;
    for (int e = threadIdx.x; e < 512; e += 256) {
        int j = e >> 1;
        float div = expf((float)(2 * j) * (-9.210340371976184f / 512.0f));
        float ang = (float)i * div;
        float pe = (e & 1) ? cosf(ang) : sinf(ang);
        out[e] = src[e] + pe;
    }
}

__global__ void add_kernel(const float* __restrict__ A, const float* __restrict__ B,
                           float* __restrict__ C, int n)
{
    int i = blockIdx.x * blockDim.x + threadIdx.x;
    int stride = gridDim.x * blockDim.x;
    for (; i < n; i += stride) C[i] = A[i] + B[i];
}

__global__ void add_bf16(const unsigned int* __restrict__ A,
                         const unsigned int* __restrict__ B,
                         unsigned int* __restrict__ C, int nwords)
{
    int i = blockIdx.x * blockDim.x + threadIdx.x;
    int stride = gridDim.x * blockDim.x;
    for (; i < nwords; i += stride) {
        unsigned int a = A[i], b = B[i];
        float lo = __uint_as_float(a << 16) + __uint_as_float(b << 16);
        float hi = __uint_as_float(a & 0xffff0000u) + __uint_as_float(b & 0xffff0000u);
        C[i] = (unsigned int)f2b(lo) | ((unsigned int)f2b(hi) << 16);
    }
}

__global__ void build_allv_b(const unsigned short* __restrict__ tembb,
                             const unsigned short* __restrict__ l2rn,
                             const unsigned short* __restrict__ r2ln,
                             unsigned short* __restrict__ allv)
{
    const int k = blockIdx.x;
    const int b = blockIdx.y;
    unsigned short* out = allv + ((size_t)b * 2080 + k) * 512;
    const unsigned short* src;
    if (k == 0)         src = tembb + b * 512;
    else if (k <= 1024) src = l2rn + ((size_t)(b * 1024 + (k - 1)) * 512);
    else                src = r2ln + ((size_t)(b * 1024 + (k - 1025)) * 512);
    ((uint4*)out)[threadIdx.x] = ((const uint4*)src)[threadIdx.x];
}

// ---------------------------------------------------------------------------
// MFMA flash attention, bf16 in/out, fp32 accumulate.
// One block = (b, h, 64-q tile); 4 waves x 16 q-rows each; KV tile = 64.
// mode 0: k<=q; mode 1: k>=q; mode 2: cross (2049 keys, batch stride 2080)
// ---------------------------------------------------------------------------
__global__ __launch_bounds__(256) void attn_mfma(
    const unsigned short* __restrict__ Q, const unsigned short* __restrict__ K,
    const unsigned short* __restrict__ V, unsigned short* __restrict__ O, int mode)
{
    const int E = 512;
    const int LKP = (mode == 2) ? 2080 : 1024;
    const int qt = blockIdx.x, h = blockIdx.y, b = blockIdx.z;
    const int q0 = qt * 64;
    const int tid = threadIdx.x;
    const int wid = tid >> 6, lane = tid & 63;
    const int fr = lane & 15;
    const int fs = lane >> 4;
    const int wq0 = q0 + wid * 16;

    __shared__ unsigned short Qs[64][72];
    __shared__ unsigned short Ks[64][72];
    __shared__ unsigned short VTs[64][72];
    __shared__ unsigned short Ps[4][16][72];

    {
        const unsigned short* Qbase = Q + ((size_t)b * 1024 + q0) * E + h * 64;
        #pragma unroll
        for (int it = 0; it < 2; ++it) {
            int i = tid + it * 256;
            int r = i >> 3, c = i & 7;
            *(uint4*)&Qs[r][c * 8] = *(const uint4*)(Qbase + (size_t)r * E + c * 8);
        }
    }

    float m_r[4], l_r[4];
    f32x4 o_acc[4] = {};
    #pragma unroll
    for (int r = 0; r < 4; ++r) { m_r[r] = NEGF; l_r[r] = 0.f; }

    int kt0, kt1;
    if (mode == 0)      { kt0 = 0;  kt1 = qt; }
    else if (mode == 1) { kt0 = qt; kt1 = 15; }
    else                { kt0 = 0;  kt1 = 31; }

    for (int kt = kt0; kt <= kt1; ++kt) {
        if (mode == 2) {
            if (kt >= 1 && kt <= 15 && 64 * kt + 62 <= q0) continue;
            if (kt >= 17 && 64 * kt - 1025 >= q0 + 63) continue;
        }
        const int k0 = kt * 64;

        __syncthreads();

        {
            const unsigned short* Kbase = K + ((size_t)b * LKP + k0) * E + h * 64;
            const unsigned short* Vbase = V + ((size_t)b * LKP + k0) * E + h * 64;
            #pragma unroll
            for (int it = 0; it < 2; ++it) {
                int i = tid + it * 256;
                int r = i >> 3, c = i & 7;
                *(uint4*)&Ks[r][c * 8] = *(const uint4*)(Kbase + (size_t)r * E + c * 8);
                uint4 vw = *(const uint4*)(Vbase + (size_t)r * E + c * 8);
                unsigned short tmp[8];
                *(uint4*)tmp = vw;
                #pragma unroll
                for (int j = 0; j < 8; ++j) VTs[c * 8 + j][r] = tmp[j];
            }
        }
        __syncthreads();

        bf16x8 aq0 = *(const bf16x8*)&Qs[wid * 16 + fr][fs * 8];
        bf16x8 aq1 = *(const bf16x8*)&Qs[wid * 16 + fr][fs * 8 + 32];
        f32x4 s[4] = {};
        #pragma unroll
        for (int t = 0; t < 4; ++t) {
            bf16x8 bk0 = *(const bf16x8*)&Ks[t * 16 + fr][fs * 8];
            bf16x8 bk1 = *(const bf16x8*)&Ks[t * 16 + fr][fs * 8 + 32];
            s[t] = __builtin_amdgcn_mfma_f32_16x16x32_bf16(aq0, bk0, s[t], 0, 0, 0);
            s[t] = __builtin_amdgcn_mfma_f32_16x16x32_bf16(aq1, bk1, s[t], 0, 0, 0);
        }

        #pragma unroll
        for (int t = 0; t < 4; ++t) {
            #pragma unroll
            for (int r = 0; r < 4; ++r) {
                int q = wq0 + fs * 4 + r;
                int k = k0 + t * 16 + fr;
                bool valid;
                if (mode == 0)      valid = (k <= q);
                else if (mode == 1) valid = (k >= q);
                else valid = (k == 0) || (k <= 1024 ? (k - 1) > q : (k - 1025) < q);
                if (!valid) s[t][r] = NEGF;
            }
        }

        float c_[4], rs[4];
        #pragma unroll
        for (int r = 0; r < 4; ++r) {
            float v = fmaxf(fmaxf(s[0][r], s[1][r]), fmaxf(s[2][r], s[3][r]));
            v = fmaxf(v, __shfl_xor(v, 1));
            v = fmaxf(v, __shfl_xor(v, 2));
            v = fmaxf(v, __shfl_xor(v, 4));
            v = fmaxf(v, __shfl_xor(v, 8));
            float mnew = fmaxf(m_r[r], v);
            c_[r] = exp2f((m_r[r] - mnew) * LOG2E);
            m_r[r] = mnew;
            rs[r] = 0.f;
        }
        #pragma unroll
        for (int t = 0; t < 4; ++t) {
            #pragma unroll
            for (int r = 0; r < 4; ++r) {
                float p = exp2f((s[t][r] - m_r[r]) * LOG2E);
                s[t][r] = p;
                rs[r] += p;
            }
        }
        #pragma unroll
        for (int r = 0; r < 4; ++r) {
            float v = rs[r];
            v += __shfl_xor(v, 1);
            v += __shfl_xor(v, 2);
            v += __shfl_xor(v, 4);
            v += __shfl_xor(v, 8);
            l_r[r] = l_r[r] * c_[r] + v;
            o_acc[0][r] *= c_[r]; o_acc[1][r] *= c_[r];
            o_acc[2][r] *= c_[r]; o_acc[3][r] *= c_[r];
        }

        #pragma unroll
        for (int t = 0; t < 4; ++t)
            #pragma unroll
            for (int r = 0; r < 4; ++r)
                Ps[wid][fs * 4 + r][t * 16 + fr] = f2b(s[t][r]);
        __syncthreads();

        bf16x8 pa0 = *(const bf16x8*)&Ps[wid][fr][fs * 8];
        bf16x8 pa1 = *(const bf16x8*)&Ps[wid][fr][fs * 8 + 32];
        #pragma unroll
        for (int t = 0; t < 4; ++t) {
            bf16x8 bv0 = *(const bf16x8*)&VTs[t * 16 + fr][fs * 8];
            bf16x8 bv1 = *(const bf16x8*)&VTs[t * 16 + fr][fs * 8 + 32];
            o_acc[t] = __builtin_amdgcn_mfma_f32_16x16x32_bf16(pa0, bv0, o_acc[t], 0, 0, 0);
            o_acc[t] = __builtin_amdgcn_mfma_f32_16x16x32_bf16(pa1, bv1, o_acc[t], 0, 0, 0);
        }
    }

    unsigned short* Obase = O + ((size_t)b * 1024 + q0) * E + h * 64;
    float invl[4];
    #pragma unroll
    for (int r = 0; r < 4; ++r) invl[r] = 1.f / l_r[r];
    #pragma unroll
    for (int t = 0; t < 4; ++t)
        #pragma unroll
        for (int r = 0; r < 4; ++r)
            Obase[(size_t)(wid * 16 + fs * 4 + r) * E + t * 16 + fr] =
                f2b(o_acc[t][r] * invl[r]);
}

// ---------------------------------------------------------------------------

static inline void gemmb(hipStream_t st, const unsigned short* A, const unsigned short* Wt,
                         const float* bias, const float* res, float* Cf,
                         unsigned short* Cb, int M, int N, int K, float alpha, int gelu)
{
    dim3 g(N / 128, M / 128);
    gemm_bf16<<<g, dim3(256), 0, st>>>(A, Wt, bias, res, Cf, Cb, M, N, K, alpha, gelu);
}

// M=4 skinny GEMM: C[4,N] = epi(A[4,K] @ W[K,N] + bias); P = scratch
static inline void sgemm4(hipStream_t st, const float* A, const float* W,
                          const float* bias, float* C, float* P,
                          int N, int K, int gelu)
{
    const int nsplit = K / 32;
    skinny_k<<<dim3(N / 256, nsplit), 256, 0, st>>>(A, W, P, N, K);
    skinny_red<<<dim3(N / 256, 4), 256, 0, st>>>(P, bias, C, N, nsplit, gelu);
}

extern "C" void kernel_launch(void* const* d_in, const int* in_sizes, int n_in,
                              void* d_out, int out_size, void* d_ws, size_t ws_size,
                              hipStream_t stream)
{
    const int*   x      = (const int*)  d_in[0];
    const float* t      = (const float*)d_in[1];
    const float* embedW = (const float*)d_in[2];
    const float* attn_W = (const float*)d_in[3];
    const float* attn_b = (const float*)d_in[4];
    const float* ln_s   = (const float*)d_in[5];
    const float* ln_b   = (const float*)d_in[6];
    const float* mlp_W1 = (const float*)d_in[7];
    const float* mlp_b1 = (const float*)d_in[8];
    const float* mlp_W2 = (const float*)d_in[9];
    const float* mlp_b2 = (const float*)d_in[10];
    const float* ca_Wq  = (const float*)d_in[11];
    const float* ca_Wk  = (const float*)d_in[12];
    const float* ca_bk  = (const float*)d_in[13];
    const float* ca_Wv  = (const float*)d_in[14];
    const float* ca_bv  = (const float*)d_in[15];
    const float* ca_Wo  = (const float*)d_in[16];
    const float* ca_bo  = (const float*)d_in[17];
    const float* ro1s   = (const float*)d_in[18];
    const float* ro1b   = (const float*)d_in[19];
    const float* ro2s   = (const float*)d_in[20];
    const float* ro2b   = (const float*)d_in[21];
    const float* in_W   = (const float*)d_in[22];
    const float* in_b   = (const float*)d_in[23];
    const float* tm_W1  = (const float*)d_in[24];
    const float* tm_b1  = (const float*)d_in[25];
    const float* tm_W2  = (const float*)d_in[26];
    const float* tm_b2  = (const float*)d_in[27];
    const float* res_W1 = (const float*)d_in[28];
    const float* res_b1 = (const float*)d_in[29];
    const float* res_W2 = (const float*)d_in[30];
    const float* res_b2 = (const float*)d_in[31];
    const float* rls    = (const float*)d_in[32];
    const float* rlb    = (const float*)d_in[33];
    const float* film_W = (const float*)d_in[34];
    const float* film_b = (const float*)d_in[35];
    const float* out_W  = (const float*)d_in[36];
    const float* out_b  = (const float*)d_in[37];
    float* out = (float*)d_out;
    (void)ws_size; (void)in_sizes; (void)n_in; (void)out_size;

    char* base = (char*)d_ws;
    size_t off = 0;
    auto alloc = [&](size_t bytes) -> char* {
        char* p = base + off;
        off = (off + bytes + 255) & ~(size_t)255;
        return p;
    };
    float* TEMB  = (float*)alloc(8192);
    float* TM1   = (float*)alloc(32768);
    float* T4    = (float*)alloc(32768);
    float* FILM  = (float*)alloc(32768);
    unsigned short* TEMBb = (unsigned short*)alloc(4096);
    float* SKP   = (float*)alloc(2097152);     // skinny GEMM split-K partials

    float* L2R = (float*)alloc(8388608);
    float* R2L = (float*)alloc(8388608);
    float* Z   = (float*)alloc(8388608);
    float* H2  = (float*)alloc(16777216);
    float* Z2  = (float*)alloc(16777216);

    unsigned short* Zb  = (unsigned short*)alloc(4194304);
    unsigned short* Qb  = (unsigned short*)alloc(4194304);
    unsigned short* Kb  = (unsigned short*)alloc(4194304);
    unsigned short* Vb  = (unsigned short*)alloc(4194304);
    unsigned short* Ob  = (unsigned short*)alloc(4194304);
    unsigned short* H2b = (unsigned short*)alloc(8388608);

    unsigned short* BIG = (unsigned short*)alloc(25559040);
    unsigned short* MIDb  = BIG;
    unsigned short* ALLVb = BIG;
    unsigned short* K2b   = BIG + 4259840;
    unsigned short* V2b   = BIG + 8519680;

    unsigned short* WT = (unsigned short*)alloc(45613056);
    const size_t wt_attn = 0,        wt_mlp1 = 4194304, wt_mlp2 = 8388608;
    const size_t wt_caq = 12582912,  wt_cak = 12845056, wt_cav = 13107200,
                 wt_cao = 13369344,  wt_in  = 13631488;
    const size_t wt_res1 = 14155776, wt_res2 = 18350080, wt_out = 22544384;

    wconv<<<dim3(8, 8, 16), 256, 0, stream>>>(attn_W, WT + wt_attn, 512, 512, 262144, 262144);
    wconv<<<dim3(32, 8, 4), 256, 0, stream>>>(mlp_W1, WT + wt_mlp1, 512, 2048, 1048576, 1048576);
    wconv<<<dim3(8, 32, 4), 256, 0, stream>>>(mlp_W2, WT + wt_mlp2, 2048, 512, 1048576, 1048576);
    wconv<<<dim3(8, 8), 256, 0, stream>>>(ca_Wq, WT + wt_caq, 512, 512, 0, 0);
    wconv<<<dim3(8, 8), 256, 0, stream>>>(ca_Wk, WT + wt_cak, 512, 512, 0, 0);
    wconv<<<dim3(8, 8), 256, 0, stream>>>(ca_Wv, WT + wt_cav, 512, 512, 0, 0);
    wconv<<<dim3(8, 8), 256, 0, stream>>>(ca_Wo, WT + wt_cao, 512, 512, 0, 0);
    wconv<<<dim3(16, 8), 256, 0, stream>>>(in_W, WT + wt_in, 512, 1024, 0, 0);
    wconv<<<dim3(32, 16, 2), 256, 0, stream>>>(res_W1, WT + wt_res1, 1024, 2048, 2097152, 2097152);
    wconv<<<dim3(16, 32, 2), 256, 0, stream>>>(res_W2, WT + wt_res2, 2048, 1024, 2097152, 2097152);
    wconv<<<dim3(4, 16), 256, 0, stream>>>(out_W, WT + wt_out, 1024, 256, 0, 0);

    temb_kernel<<<dim3(4), dim3(256), 0, stream>>>(t, TEMB, TEMBb);
    embed_kernel<<<dim3(1024, 4, 2), dim3(256), 0, stream>>>(x, TEMB, embedW, L2R, R2L);

    for (int d = 0; d < 2; ++d) {
        float* h = (d == 0) ? L2R : R2L;
        for (int l = 0; l < 2; ++l) {
            const int dl = d * 2 + l;
            ln_kernel<<<4096, 256, 0, stream>>>(h, nullptr, ln_s + (dl * 2 + 0) * 512,
                                                ln_b + (dl * 2 + 0) * 512, nullptr, Zb,
                                                512, nullptr, 1024);
            gemmb(stream, Zb, WT + wt_attn + (size_t)(dl * 4 + 0) * 262144,
                  attn_b + (dl * 4 + 0) * 512, nullptr, nullptr, Qb, 4096, 512, 512, 0.125f, 0);
            gemmb(stream, Zb, WT + wt_attn + (size_t)(dl * 4 + 1) * 262144,
                  attn_b + (dl * 4 + 1) * 512, nullptr, nullptr, Kb, 4096, 512, 512, 1.f, 0);
            gemmb(stream, Zb, WT + wt_attn + (size_t)(dl * 4 + 2) * 262144,
                  attn_b + (dl * 4 + 2) * 512, nullptr, nullptr, Vb, 4096, 512, 512, 1.f, 0);
            attn_mfma<<<dim3(16, 8, 4), dim3(256), 0, stream>>>(Qb, Kb, Vb, Ob, d);
            gemmb(stream, Ob, WT + wt_attn + (size_t)(dl * 4 + 3) * 262144,
                  attn_b + (dl * 4 + 3) * 512, h, h, nullptr, 4096, 512, 512, 1.f, 0);
            ln_kernel<<<4096, 256, 0, stream>>>(h, nullptr, ln_s + (dl * 2 + 1) * 512,
                                                ln_b + (dl * 2 + 1) * 512, nullptr, Zb,
                                                512, nullptr, 1024);
            gemmb(stream, Zb, WT + wt_mlp1 + (size_t)dl * 1048576, mlp_b1 + dl * 2048,
                  nullptr, nullptr, MIDb, 4096, 2048, 512, 1.f, 1);
            gemmb(stream, MIDb, WT + wt_mlp2 + (size_t)dl * 1048576, mlp_b2 + dl * 512,
                  h, h, nullptr, 4096, 512, 2048, 1.f, 0);
        }
    }

    add_kernel<<<2048, 256, 0, stream>>>(L2R, R2L, Z, 2097152);
    ln_kernel<<<4096, 256, 0, stream>>>(L2R, nullptr, ro1s, ro1b, nullptr, Qb, 512, nullptr, 1024);
    ln_kernel<<<4096, 256, 0, stream>>>(R2L, nullptr, ro2s, ro2b, nullptr, Kb, 512, nullptr, 1024);
    add_bf16<<<1024, 256, 0, stream>>>((const unsigned int*)Qb, (const unsigned int*)Kb,
                                       (unsigned int*)Vb, 1048576);
    build_allv_b<<<dim3(2049, 4), 64, 0, stream>>>(TEMBb, Qb, Kb, ALLVb);
    gemmb(stream, Vb, WT + wt_caq, nullptr, nullptr, nullptr, Zb, 4096, 512, 512, 0.125f, 0);
    gemmb(stream, ALLVb, WT + wt_cak, ca_bk, nullptr, nullptr, K2b, 8320, 512, 512, 1.f, 0);
    gemmb(stream, ALLVb, WT + wt_cav, ca_bv, nullptr, nullptr, V2b, 8320, 512, 512, 1.f, 0);
    attn_mfma<<<dim3(16, 8, 4), dim3(256), 0, stream>>>(Zb, K2b, V2b, Ob, 2);
    gemmb(stream, Ob, WT + wt_cao, ca_bo, Z, nullptr, Qb, 4096, 512, 512, 1.f, 0);

    // ---- t-MLP (M=4 skinny split-K) ----
    sgemm4(stream, TEMB, tm_W1, tm_b1, TM1, SKP, 2048, 512, 1);
    sgemm4(stream, TM1, tm_W2, tm_b2, T4, SKP, 2048, 2048, 0);

    gemmb(stream, Qb, WT + wt_in, in_b, nullptr, H2, H2b, 4096, 1024, 512, 1.f, 0);
    for (int i = 0; i < 2; ++i) {
        sgemm4(stream, T4, film_W + (size_t)i * 4194304, film_b + i * 2048,
               FILM, SKP, 2048, 2048, 0);
        gemmb(stream, H2b, WT + wt_res1 + (size_t)i * 2097152, res_b1 + i * 2048,
              nullptr, nullptr, MIDb, 4096, 2048, 1024, 1.f, 1);
        gemmb(stream, MIDb, WT + wt_res2 + (size_t)i * 2097152, res_b2 + i * 1024,
              nullptr, Z2, nullptr, 4096, 1024, 2048, 1.f, 0);
        ln_kernel<<<4096, 256, 0, stream>>>(H2, Z2, rls + i * 1024, rlb + i * 1024,
                                            H2, H2b, 1024, FILM, 1024);
    }

    gemmb(stream, H2b, WT + wt_out, out_b, nullptr, out, nullptr, 4096, 256, 1024, 1.f, 0);
}

// Round 6
// 1831.940 us; speedup vs baseline: 8.5388x; 1.0087x over previous
//
#include <hip/hip_runtime.h>
#include <hip/hip_bf16.h>

// ---------------------------------------------------------------------------
// B=4, L=1024, E=512, H=8, NL=2, M=2048, S=256, R=2, Dh=64
// ---------------------------------------------------------------------------

#define NEGF -3.4028235e38f
#define LOG2E 1.4426950408889634f

using bf16x8 = __attribute__((ext_vector_type(8))) short;
using f32x4  = __attribute__((ext_vector_type(4))) float;

__device__ inline float bf2f(unsigned short u) {
    return __uint_as_float(((unsigned int)u) << 16);
}
__device__ inline unsigned short f2b(float f) {
    unsigned int u = __float_as_uint(f);
    return (unsigned short)((u + 0x7fff + ((u >> 16) & 1)) >> 16);
}

// global -> LDS async copy, 16 B per lane
__device__ inline void gl_lds16(const void* g, void* l) {
    __builtin_amdgcn_global_load_lds(
        (const __attribute__((address_space(1))) void*)(uintptr_t)g,
        (__attribute__((address_space(3))) void*)(unsigned int)(uintptr_t)l,
        16, 0, 0);
}

// ---------------------------------------------------------------------------
// bf16 MFMA GEMM: C = epi(A[M,K] @ W[K,N]) with Wt = W^T stored [N][K] bf16.
// 128x128 tile, BK=32, 4 waves (2x2), wave tile 64x64 (4x4 16x16 frags).
// Optional outputs: Cf (f32 row-major), Cb (bf16 row-major),
// Ct (bf16 per-head transposed: (B,H=8,Dh=64,ldkv), row m -> b=m/ldkv,l=m%ldkv)
// ---------------------------------------------------------------------------
__global__ __launch_bounds__(256) void gemm_bf16(
    const unsigned short* __restrict__ A, const unsigned short* __restrict__ Wt,
    const float* __restrict__ bias, const float* __restrict__ res,
    float* __restrict__ Cf, unsigned short* __restrict__ Cb,
    unsigned short* __restrict__ Ct, int ldkv,
    int M, int N, int K, float alpha, int gelu_flag)
{
    __shared__ unsigned short As[4096];
    __shared__ unsigned short Bs[4096];
    const int tid  = threadIdx.x;
    const int wid  = tid >> 6, lane = tid & 63;
    const int wy   = wid >> 1, wx = wid & 1;
    const int koff = lane >> 4, l16 = lane & 15;
    const int m0 = blockIdx.y * 128, n0 = blockIdx.x * 128;

    const int c0 = tid, c1 = tid + 256;
    const int rA0 = ((c0 >> 6) << 4) | (c0 & 15), kA0 = ((c0 >> 4) & 3) << 3;
    const int rA1 = ((c1 >> 6) << 4) | (c1 & 15), kA1 = ((c1 >> 4) & 3) << 3;

    const unsigned short* a0 = A  + (size_t)(m0 + rA0) * K + kA0;
    const unsigned short* a1 = A  + (size_t)(m0 + rA1) * K + kA1;
    const unsigned short* b0 = Wt + (size_t)(n0 + rA0) * K + kA0;
    const unsigned short* b1 = Wt + (size_t)(n0 + rA1) * K + kA1;

    unsigned short* ldsA0 = As + (size_t)(wid * 64) * 8;
    unsigned short* ldsA1 = As + (size_t)(256 + wid * 64) * 8;
    unsigned short* ldsB0 = Bs + (size_t)(wid * 64) * 8;
    unsigned short* ldsB1 = Bs + (size_t)(256 + wid * 64) * 8;

    f32x4 acc[4][4] = {};

    for (int k0 = 0; k0 < K; k0 += 32) {
        gl_lds16(a0 + k0, ldsA0);
        gl_lds16(a1 + k0, ldsA1);
        gl_lds16(b0 + k0, ldsB0);
        gl_lds16(b1 + k0, ldsB1);
        __syncthreads();

        bf16x8 af[4], bfr[4];
        const int foff = (koff * 16 + l16) * 8;
        #pragma unroll
        for (int i = 0; i < 4; ++i)
            af[i] = *(const bf16x8*)(As + (size_t)((wy * 4 + i) * 64) * 8 + foff);
        #pragma unroll
        for (int j = 0; j < 4; ++j)
            bfr[j] = *(const bf16x8*)(Bs + (size_t)((wx * 4 + j) * 64) * 8 + foff);

        #pragma unroll
        for (int i = 0; i < 4; ++i)
            #pragma unroll
            for (int j = 0; j < 4; ++j)
                acc[i][j] = __builtin_amdgcn_mfma_f32_16x16x32_bf16(
                    af[i], bfr[j], acc[i][j], 0, 0, 0);
        __syncthreads();
    }

    #pragma unroll
    for (int i = 0; i < 4; ++i) {
        const int rbase = m0 + wy * 64 + i * 16 + koff * 4;
        #pragma unroll
        for (int j = 0; j < 4; ++j) {
            const int gn = n0 + wx * 64 + j * 16 + l16;
            const float bs = bias ? bias[gn] : 0.f;
            float vr[4];
            #pragma unroll
            for (int r = 0; r < 4; ++r) {
                float v = (acc[i][j][r] + bs) * alpha;
                if (gelu_flag) v = 0.5f * v * (1.0f + erff(v * 0.70710678118654752f));
                const size_t idx = (size_t)(rbase + r) * N + gn;
                if (res) v += res[idx];
                if (Cf) Cf[idx] = v;
                if (Cb) Cb[idx] = f2b(v);
                vr[r] = v;
            }
            if (Ct) {
                const int hh = gn >> 6, dh = gn & 63;
                const int bb = rbase / ldkv;
                const int l0 = rbase - bb * ldkv;
                ushort4 o4;
                o4.x = f2b(vr[0]); o4.y = f2b(vr[1]);
                o4.z = f2b(vr[2]); o4.w = f2b(vr[3]);
                *(ushort4*)(Ct + ((size_t)(bb * 8 + hh) * 64 + dh) * ldkv + l0) = o4;
            }
        }
    }
}

// ---------------------------------------------------------------------------
// weight transpose-convert: src fp32 [K][N] -> dst bf16 [N][K]
// ---------------------------------------------------------------------------
__global__ __launch_bounds__(256) void wconv(
    const float* __restrict__ src, unsigned short* __restrict__ dst,
    int K, int N, long sstride, long dstride)
{
    __shared__ float t[64][65];
    const int n0 = blockIdx.x * 64, k0 = blockIdx.y * 64;
    const float* s = src + (size_t)blockIdx.z * sstride;
    unsigned short* d = dst + (size_t)blockIdx.z * dstride;
    const int tid = threadIdx.x;
    #pragma unroll
    for (int i = 0; i < 4; ++i) {
        int lin = i * 1024 + tid * 4;
        int r = lin >> 6, c = lin & 63;
        float4 v = *(const float4*)(s + (size_t)(k0 + r) * N + n0 + c);
        t[r][c] = v.x; t[r][c + 1] = v.y; t[r][c + 2] = v.z; t[r][c + 3] = v.w;
    }
    __syncthreads();
    #pragma unroll
    for (int i = 0; i < 8; ++i) {
        int lin = i * 512 + tid * 2;
        int rn = lin >> 6, ck = lin & 63;
        ushort2 o;
        o.x = f2b(t[ck][rn]); o.y = f2b(t[ck + 1][rn]);
        *(ushort2*)(d + (size_t)(n0 + rn) * K + k0 + ck) = o;
    }
}

// ---------------------------------------------------------------------------
// Skinny GEMM for M=4 (t-MLP / FiLM), split-K, deterministic
// ---------------------------------------------------------------------------
__global__ __launch_bounds__(256) void skinny_k(
    const float* __restrict__ A, const float* __restrict__ W,
    float* __restrict__ P, int N, int K)
{
    const int n = blockIdx.x * 256 + threadIdx.x;
    const int s = blockIdx.y;
    const int k0 = s * 32;
    float a0 = 0.f, a1 = 0.f, a2 = 0.f, a3 = 0.f;
    #pragma unroll 8
    for (int k = k0; k < k0 + 32; ++k) {
        float w = W[(size_t)k * N + n];
        a0 = fmaf(A[k], w, a0);
        a1 = fmaf(A[K + k], w, a1);
        a2 = fmaf(A[2 * K + k], w, a2);
        a3 = fmaf(A[3 * K + k], w, a3);
    }
    float* p = P + (size_t)s * 4 * N;
    p[n] = a0; p[N + n] = a1; p[2 * N + n] = a2; p[3 * N + n] = a3;
}

__global__ __launch_bounds__(256) void skinny_red(
    const float* __restrict__ P, const float* __restrict__ bias,
    float* __restrict__ C, int N, int nsplit, int gelu_flag)
{
    const int n = blockIdx.x * 256 + threadIdx.x;
    const int r = blockIdx.y;
    float acc = 0.f;
    for (int s = 0; s < nsplit; ++s) acc += P[((size_t)s * 4 + r) * N + n];
    float v = acc + (bias ? bias[n] : 0.f);
    if (gelu_flag) v = 0.5f * v * (1.0f + erff(v * 0.70710678118654752f));
    C[(size_t)r * N + n] = v;
}

// ---------------------------------------------------------------------------
// LayerNorm (+optional add, +optional FiLM); fp32 in, fp32 and/or bf16 out
// ---------------------------------------------------------------------------
__global__ __launch_bounds__(256) void ln_kernel(
    const float* __restrict__ X, const float* __restrict__ X2,
    const float* __restrict__ s, const float* __restrict__ b,
    float* __restrict__ Yf, unsigned short* __restrict__ Yb,
    int D, const float* __restrict__ film, int rows_per_batch)
{
    const int row = blockIdx.x;
    const int tid = threadIdx.x;
    const float* x = X + (size_t)row * D;
    const float* x2 = X2 ? X2 + (size_t)row * D : nullptr;

    float sum = 0.f, sq = 0.f;
    for (int c = tid; c < D; c += 256) {
        float v = x[c] + (x2 ? x2[c] : 0.f);
        sum += v; sq += v * v;
    }
    __shared__ float r1[4], r2[4];
    __shared__ float s_mean, s_rstd;
    for (int off = 32; off > 0; off >>= 1) {
        sum += __shfl_down(sum, off);
        sq  += __shfl_down(sq,  off);
    }
    if ((tid & 63) == 0) { r1[tid >> 6] = sum; r2[tid >> 6] = sq; }
    __syncthreads();
    if (tid == 0) {
        float ts = r1[0] + r1[1] + r1[2] + r1[3];
        float tq = r2[0] + r2[1] + r2[2] + r2[3];
        float mean = ts / (float)D;
        float var = tq / (float)D - mean * mean;
        s_mean = mean;
        s_rstd = rsqrtf(var + 1e-5f);
    }
    __syncthreads();
    const float mean = s_mean, rstd = s_rstd;
    const float* fa = nullptr; const float* fb = nullptr;
    if (film) {
        int batch = row / rows_per_batch;
        fa = film + (size_t)batch * 2 * D;
        fb = fa + D;
    }
    for (int c = tid; c < D; c += 256) {
        float v = x[c] + (x2 ? x2[c] : 0.f);
        float y = (v - mean) * rstd * s[c] + b[c];
        if (film) y = fa[c] * y + fb[c];
        if (Yf) Yf[(size_t)row * D + c] = y;
        if (Yb) Yb[(size_t)row * D + c] = f2b(y);
    }
}

__global__ void temb_kernel(const float* __restrict__ t, float* __restrict__ temb,
                            unsigned short* __restrict__ tembb)
{
    int b = blockIdx.x;
    int i = threadIdx.x;
    float f = expf((float)i * (-9.210340371976184f / 255.0f));
    float a = t[b] * f;
    float sv = sinf(a), cv = cosf(a);
    temb[b * 512 + i]        = sv;
    temb[b * 512 + 256 + i]  = cv;
    tembb[b * 512 + i]       = f2b(sv);
    tembb[b * 512 + 256 + i] = f2b(cv);
}

__global__ void embed_kernel(const int* __restrict__ x, const float* __restrict__ temb,
                             const float* __restrict__ embed,
                             float* __restrict__ l2r, float* __restrict__ r2l)
{
    const int i = blockIdx.x;
    const int b = blockIdx.y;
    const int d = blockIdx.z;
    float* out = (d == 0 ? l2r : r2l) + ((size_t)(b * 1024 + i) * 512);
    const float* src;
    if (d == 0) src = (i == 0)    ? temb + b * 512 : embed + (size_t)x[b * 1024 + (i - 1)] * 512;
    else        src = (i == 1023) ? temb + b * 512 : embed + (size_t)x[b * 1024 + (i + 1)] * 512;
    for (int e = threadIdx.x; e < 512; e += 256) {
        int j = e >> 1;
        float div = expf((float)(2 * j) * (-9.210340371976184f / 512.0f));
        float ang = (float)i * div;
        float pe = (e & 1) ? cosf(ang) : sinf(ang);
        out[e] = src[e] + pe;
    }
}

__global__ void add_kernel(const float* __restrict__ A, const float* __restrict__ B,
                           float* __restrict__ C, int n)
{
    int i = blockIdx.x * blockDim.x + threadIdx.x;
    int stride = gridDim.x * blockDim.x;
    for (; i < n; i += stride) C[i] = A[i] + B[i];
}

__global__ void add_bf16(const unsigned int* __restrict__ A,
                         const unsigned int* __restrict__ B,
                         unsigned int* __restrict__ C, int nwords)
{
    int i = blockIdx.x * blockDim.x + threadIdx.x;
    int stride = gridDim.x * blockDim.x;
    for (; i < nwords; i += stride) {
        unsigned int a = A[i], b = B[i];
        float lo = __uint_as_float(a << 16) + __uint_as_float(b << 16);
        float hi = __uint_as_float(a & 0xffff0000u) + __uint_as_float(b & 0xffff0000u);
        C[i] = (unsigned int)f2b(lo) | ((unsigned int)f2b(hi) << 16);
    }
}

__global__ void build_allv_b(const unsigned short* __restrict__ tembb,
                             const unsigned short* __restrict__ l2rn,
                             const unsigned short* __restrict__ r2ln,
                             unsigned short* __restrict__ allv)
{
    const int k = blockIdx.x;
    const int b = blockIdx.y;
    unsigned short* out = allv + ((size_t)b * 2080 + k) * 512;
    const unsigned short* src;
    if (k == 0)         src = tembb + b * 512;
    else if (k <= 1024) src = l2rn + ((size_t)(b * 1024 + (k - 1)) * 512);
    else                src = r2ln + ((size_t)(b * 1024 + (k - 1025)) * 512);
    ((uint4*)out)[threadIdx.x] = ((const uint4*)src)[threadIdx.x];
}

// ---------------------------------------------------------------------------
// MFMA flash attention, bf16 in/out, fp32 accumulate.
// Grid: flat 512 blocks, XCD-chunked swizzle (w=(id&7)*64+id/8) so each XCD
// owns all q-tiles of 4 (b,h) pairs -> K/V stay L2-resident.
// Q,K: (B, L(KP), E) row-major head slice. Vt: (B, H, 64, LKP) pre-transposed.
// LDS packed 16B chunks: idx = c*64 + r (c = 8-elem chunk, r = row) ->
// staging writes and ds_read_b128 fragments are bank-conflict-free.
// mode 0: k<=q; mode 1: k>=q; mode 2: cross (2049 keys, stride 2080)
// ---------------------------------------------------------------------------
__global__ __launch_bounds__(256) void attn_mfma(
    const unsigned short* __restrict__ Q, const unsigned short* __restrict__ K,
    const unsigned short* __restrict__ Vt, unsigned short* __restrict__ O, int mode)
{
    const int E = 512;
    const int LKP = (mode == 2) ? 2080 : 1024;
    const int idf = blockIdx.x;
    const int w = (idf & 7) * 64 + (idf >> 3);
    const int qt = w & 15, h = (w >> 4) & 7, b = w >> 7;
    const int q0 = qt * 64;
    const int tid = threadIdx.x;
    const int wid = tid >> 6, lane = tid & 63;
    const int fr = lane & 15;
    const int fs = lane >> 4;
    const int wq0 = q0 + wid * 16;

    __shared__ unsigned short Qs[4096];
    __shared__ unsigned short Ks[4096];
    __shared__ unsigned short Vs[4096];
    __shared__ unsigned short Ps[4][16][72];

    // ---- stage Q tile (chunk idx = c*64 + r) ----
    {
        const unsigned short* Qbase = Q + ((size_t)b * 1024 + q0) * E + h * 64;
        #pragma unroll
        for (int it = 0; it < 2; ++it) {
            int i = tid + it * 256;
            int r = i & 63, c = i >> 6;
            *(uint4*)&Qs[(size_t)(c * 64 + r) * 8] =
                *(const uint4*)(Qbase + (size_t)r * E + c * 8);
        }
    }
    __syncthreads();
    const bf16x8 aq0 = *(const bf16x8*)&Qs[(size_t)(fs * 64 + wid * 16 + fr) * 8];
    const bf16x8 aq1 = *(const bf16x8*)&Qs[(size_t)((fs + 4) * 64 + wid * 16 + fr) * 8];

    float m_r[4], l_r[4];
    f32x4 o_acc[4] = {};
    #pragma unroll
    for (int r = 0; r < 4; ++r) { m_r[r] = NEGF; l_r[r] = 0.f; }

    int kt0, kt1;
    if (mode == 0)      { kt0 = 0;  kt1 = qt; }
    else if (mode == 1) { kt0 = qt; kt1 = 15; }
    else                { kt0 = 0;  kt1 = 31; }

    const unsigned short* Kb0 = K + ((size_t)b * LKP) * E + h * 64;
    const unsigned short* Vb0 = Vt + (size_t)(b * 8 + h) * 64 * LKP;

    for (int kt = kt0; kt <= kt1; ++kt) {
        if (mode == 2) {
            if (kt >= 1 && kt <= 15 && 64 * kt + 62 <= q0) continue;
            if (kt >= 17 && 64 * kt - 1025 >= q0 + 63) continue;
        }
        const int k0 = kt * 64;

        __syncthreads();   // previous tile's reads complete

        {
            const unsigned short* Kbase = Kb0 + (size_t)k0 * E;
            const unsigned short* Vbase = Vb0 + k0;
            #pragma unroll
            for (int it = 0; it < 2; ++it) {
                int i = tid + it * 256;
                int r = i & 63, c = i >> 6;
                *(uint4*)&Ks[(size_t)(c * 64 + r) * 8] =
                    *(const uint4*)(Kbase + (size_t)r * E + c * 8);
                *(uint4*)&Vs[(size_t)(c * 64 + r) * 8] =
                    *(const uint4*)(Vbase + (size_t)r * LKP + c * 8);
            }
        }
        __syncthreads();

        // ---- S = Q K^T ----
        f32x4 s[4] = {};
        #pragma unroll
        for (int t = 0; t < 4; ++t) {
            bf16x8 bk0 = *(const bf16x8*)&Ks[(size_t)(fs * 64 + t * 16 + fr) * 8];
            bf16x8 bk1 = *(const bf16x8*)&Ks[(size_t)((fs + 4) * 64 + t * 16 + fr) * 8];
            s[t] = __builtin_amdgcn_mfma_f32_16x16x32_bf16(aq0, bk0, s[t], 0, 0, 0);
            s[t] = __builtin_amdgcn_mfma_f32_16x16x32_bf16(aq1, bk1, s[t], 0, 0, 0);
        }

        // ---- mask ----
        #pragma unroll
        for (int t = 0; t < 4; ++t) {
            #pragma unroll
            for (int r = 0; r < 4; ++r) {
                int q = wq0 + fs * 4 + r;
                int k = k0 + t * 16 + fr;
                bool valid;
                if (mode == 0)      valid = (k <= q);
                else if (mode == 1) valid = (k >= q);
                else valid = (k == 0) || (k <= 1024 ? (k - 1) > q : (k - 1025) < q);
                if (!valid) s[t][r] = NEGF;
            }
        }

        // ---- online softmax ----
        float c_[4], rs[4];
        #pragma unroll
        for (int r = 0; r < 4; ++r) {
            float v = fmaxf(fmaxf(s[0][r], s[1][r]), fmaxf(s[2][r], s[3][r]));
            v = fmaxf(v, __shfl_xor(v, 1));
            v = fmaxf(v, __shfl_xor(v, 2));
            v = fmaxf(v, __shfl_xor(v, 4));
            v = fmaxf(v, __shfl_xor(v, 8));
            float mnew = fmaxf(m_r[r], v);
            c_[r] = exp2f((m_r[r] - mnew) * LOG2E);
            m_r[r] = mnew;
            rs[r] = 0.f;
        }
        #pragma unroll
        for (int t = 0; t < 4; ++t) {
            #pragma unroll
            for (int r = 0; r < 4; ++r) {
                float p = exp2f((s[t][r] - m_r[r]) * LOG2E);
                s[t][r] = p;
                rs[r] += p;
            }
        }
        #pragma unroll
        for (int r = 0; r < 4; ++r) {
            float v = rs[r];
            v += __shfl_xor(v, 1);
            v += __shfl_xor(v, 2);
            v += __shfl_xor(v, 4);
            v += __shfl_xor(v, 8);
            l_r[r] = l_r[r] * c_[r] + v;
            o_acc[0][r] *= c_[r]; o_acc[1][r] *= c_[r];
            o_acc[2][r] *= c_[r]; o_acc[3][r] *= c_[r];
        }

        // ---- P -> bf16, re-fragment via wave-private LDS ----
        #pragma unroll
        for (int t = 0; t < 4; ++t)
            #pragma unroll
            for (int r = 0; r < 4; ++r)
                Ps[wid][fs * 4 + r][t * 16 + fr] = f2b(s[t][r]);
        __syncthreads();

        // ---- O += P V ----
        bf16x8 pa0 = *(const bf16x8*)&Ps[wid][fr][fs * 8];
        bf16x8 pa1 = *(const bf16x8*)&Ps[wid][fr][fs * 8 + 32];
        #pragma unroll
        for (int t = 0; t < 4; ++t) {
            bf16x8 bv0 = *(const bf16x8*)&Vs[(size_t)(fs * 64 + t * 16 + fr) * 8];
            bf16x8 bv1 = *(const bf16x8*)&Vs[(size_t)((fs + 4) * 64 + t * 16 + fr) * 8];
            o_acc[t] = __builtin_amdgcn_mfma_f32_16x16x32_bf16(pa0, bv0, o_acc[t], 0, 0, 0);
            o_acc[t] = __builtin_amdgcn_mfma_f32_16x16x32_bf16(pa1, bv1, o_acc[t], 0, 0, 0);
        }
    }

    // ---- epilogue: O = acc / l ----
    unsigned short* Obase = O + ((size_t)b * 1024 + q0) * E + h * 64;
    float invl[4];
    #pragma unroll
    for (int r = 0; r < 4; ++r) invl[r] = 1.f / l_r[r];
    #pragma unroll
    for (int t = 0; t < 4; ++t)
        #pragma unroll
        for (int r = 0; r < 4; ++r)
            Obase[(size_t)(wid * 16 + fs * 4 + r) * E + t * 16 + fr] =
                f2b(o_acc[t][r] * invl[r]);
}

// ---------------------------------------------------------------------------

static inline void gemmb(hipStream_t st, const unsigned short* A, const unsigned short* Wt,
                         const float* bias, const float* res, float* Cf,
                         unsigned short* Cb, unsigned short* Ct, int ldkv,
                         int M, int N, int K, float alpha, int gelu)
{
    dim3 g(N / 128, M / 128);
    gemm_bf16<<<g, dim3(256), 0, st>>>(A, Wt, bias, res, Cf, Cb, Ct, ldkv,
                                       M, N, K, alpha, gelu);
}

static inline void sgemm4(hipStream_t st, const float* A, const float* W,
                          const float* bias, float* C, float* P,
                          int N, int K, int gelu)
{
    const int nsplit = K / 32;
    skinny_k<<<dim3(N / 256, nsplit), 256, 0, st>>>(A, W, P, N, K);
    skinny_red<<<dim3(N / 256, 4), 256, 0, st>>>(P, bias, C, N, nsplit, gelu);
}

extern "C" void kernel_launch(void* const* d_in, const int* in_sizes, int n_in,
                              void* d_out, int out_size, void* d_ws, size_t ws_size,
                              hipStream_t stream)
{
    const int*   x      = (const int*)  d_in[0];
    const float* t      = (const float*)d_in[1];
    const float* embedW = (const float*)d_in[2];
    const float* attn_W = (const float*)d_in[3];
    const float* attn_b = (const float*)d_in[4];
    const float* ln_s   = (const float*)d_in[5];
    const float* ln_b   = (const float*)d_in[6];
    const float* mlp_W1 = (const float*)d_in[7];
    const float* mlp_b1 = (const float*)d_in[8];
    const float* mlp_W2 = (const float*)d_in[9];
    const float* mlp_b2 = (const float*)d_in[10];
    const float* ca_Wq  = (const float*)d_in[11];
    const float* ca_Wk  = (const float*)d_in[12];
    const float* ca_bk  = (const float*)d_in[13];
    const float* ca_Wv  = (const float*)d_in[14];
    const float* ca_bv  = (const float*)d_in[15];
    const float* ca_Wo  = (const float*)d_in[16];
    const float* ca_bo  = (const float*)d_in[17];
    const float* ro1s   = (const float*)d_in[18];
    const float* ro1b   = (const float*)d_in[19];
    const float* ro2s   = (const float*)d_in[20];
    const float* ro2b   = (const float*)d_in[21];
    const float* in_W   = (const float*)d_in[22];
    const float* in_b   = (const float*)d_in[23];
    const float* tm_W1  = (const float*)d_in[24];
    const float* tm_b1  = (const float*)d_in[25];
    const float* tm_W2  = (const float*)d_in[26];
    const float* tm_b2  = (const float*)d_in[27];
    const float* res_W1 = (const float*)d_in[28];
    const float* res_b1 = (const float*)d_in[29];
    const float* res_W2 = (const float*)d_in[30];
    const float* res_b2 = (const float*)d_in[31];
    const float* rls    = (const float*)d_in[32];
    const float* rlb    = (const float*)d_in[33];
    const float* film_W = (const float*)d_in[34];
    const float* film_b = (const float*)d_in[35];
    const float* out_W  = (const float*)d_in[36];
    const float* out_b  = (const float*)d_in[37];
    float* out = (float*)d_out;
    (void)ws_size; (void)in_sizes; (void)n_in; (void)out_size;

    char* base = (char*)d_ws;
    size_t off = 0;
    auto alloc = [&](size_t bytes) -> char* {
        char* p = base + off;
        off = (off + bytes + 255) & ~(size_t)255;
        return p;
    };
    float* TEMB  = (float*)alloc(8192);
    float* TM1   = (float*)alloc(32768);
    float* T4    = (float*)alloc(32768);
    float* FILM  = (float*)alloc(32768);
    unsigned short* TEMBb = (unsigned short*)alloc(4096);
    float* SKP   = (float*)alloc(2097152);

    float* L2R = (float*)alloc(8388608);
    float* R2L = (float*)alloc(8388608);
    float* Z   = (float*)alloc(8388608);
    float* H2  = (float*)alloc(16777216);
    float* Z2  = (float*)alloc(16777216);

    unsigned short* Zb  = (unsigned short*)alloc(4194304);
    unsigned short* Qb  = (unsigned short*)alloc(4194304);
    unsigned short* Kb  = (unsigned short*)alloc(4194304);
    unsigned short* Vb  = (unsigned short*)alloc(4194304);   // self V^T / readout temp
    unsigned short* Ob  = (unsigned short*)alloc(4194304);
    unsigned short* H2b = (unsigned short*)alloc(8388608);

    unsigned short* BIG = (unsigned short*)alloc(25559040);
    unsigned short* MIDb  = BIG;                 // 4096x2048 (blocks / res-MLP)
    unsigned short* ALLVb = BIG;                 // 8320x512 (readout)
    unsigned short* K2b   = BIG + 4259840;       // 8320x512
    unsigned short* V2T   = BIG + 8519680;       // (4,8,64,2080) = 4,259,840 shorts

    unsigned short* WT = (unsigned short*)alloc(45613056);
    const size_t wt_attn = 0,        wt_mlp1 = 4194304, wt_mlp2 = 8388608;
    const size_t wt_caq = 12582912,  wt_cak = 12845056, wt_cav = 13107200,
                 wt_cao = 13369344,  wt_in  = 13631488;
    const size_t wt_res1 = 14155776, wt_res2 = 18350080, wt_out = 22544384;

    wconv<<<dim3(8, 8, 16), 256, 0, stream>>>(attn_W, WT + wt_attn, 512, 512, 262144, 262144);
    wconv<<<dim3(32, 8, 4), 256, 0, stream>>>(mlp_W1, WT + wt_mlp1, 512, 2048, 1048576, 1048576);
    wconv<<<dim3(8, 32, 4), 256, 0, stream>>>(mlp_W2, WT + wt_mlp2, 2048, 512, 1048576, 1048576);
    wconv<<<dim3(8, 8), 256, 0, stream>>>(ca_Wq, WT + wt_caq, 512, 512, 0, 0);
    wconv<<<dim3(8, 8), 256, 0, stream>>>(ca_Wk, WT + wt_cak, 512, 512, 0, 0);
    wconv<<<dim3(8, 8), 256, 0, stream>>>(ca_Wv, WT + wt_cav, 512, 512, 0, 0);
    wconv<<<dim3(8, 8), 256, 0, stream>>>(ca_Wo, WT + wt_cao, 512, 512, 0, 0);
    wconv<<<dim3(16, 8), 256, 0, stream>>>(in_W, WT + wt_in, 512, 1024, 0, 0);
    wconv<<<dim3(32, 16, 2), 256, 0, stream>>>(res_W1, WT + wt_res1, 1024, 2048, 2097152, 2097152);
    wconv<<<dim3(16, 32, 2), 256, 0, stream>>>(res_W2, WT + wt_res2, 2048, 1024, 2097152, 2097152);
    wconv<<<dim3(4, 16), 256, 0, stream>>>(out_W, WT + wt_out, 1024, 256, 0, 0);

    temb_kernel<<<dim3(4), dim3(256), 0, stream>>>(t, TEMB, TEMBb);
    embed_kernel<<<dim3(1024, 4, 2), dim3(256), 0, stream>>>(x, TEMB, embedW, L2R, R2L);

    for (int d = 0; d < 2; ++d) {
        float* h = (d == 0) ? L2R : R2L;
        for (int l = 0; l < 2; ++l) {
            const int dl = d * 2 + l;
            ln_kernel<<<4096, 256, 0, stream>>>(h, nullptr, ln_s + (dl * 2 + 0) * 512,
                                                ln_b + (dl * 2 + 0) * 512, nullptr, Zb,
                                                512, nullptr, 1024);
            gemmb(stream, Zb, WT + wt_attn + (size_t)(dl * 4 + 0) * 262144,
                  attn_b + (dl * 4 + 0) * 512, nullptr, nullptr, Qb, nullptr, 1,
                  4096, 512, 512, 0.125f, 0);
            gemmb(stream, Zb, WT + wt_attn + (size_t)(dl * 4 + 1) * 262144,
                  attn_b + (dl * 4 + 1) * 512, nullptr, nullptr, Kb, nullptr, 1,
                  4096, 512, 512, 1.f, 0);
            gemmb(stream, Zb, WT + wt_attn + (size_t)(dl * 4 + 2) * 262144,
                  attn_b + (dl * 4 + 2) * 512, nullptr, nullptr, nullptr, Vb, 1024,
                  4096, 512, 512, 1.f, 0);
            attn_mfma<<<dim3(512), dim3(256), 0, stream>>>(Qb, Kb, Vb, Ob, d);
            gemmb(stream, Ob, WT + wt_attn + (size_t)(dl * 4 + 3) * 262144,
                  attn_b + (dl * 4 + 3) * 512, h, h, nullptr, nullptr, 1,
                  4096, 512, 512, 1.f, 0);
            ln_kernel<<<4096, 256, 0, stream>>>(h, nullptr, ln_s + (dl * 2 + 1) * 512,
                                                ln_b + (dl * 2 + 1) * 512, nullptr, Zb,
                                                512, nullptr, 1024);
            gemmb(stream, Zb, WT + wt_mlp1 + (size_t)dl * 1048576, mlp_b1 + dl * 2048,
                  nullptr, nullptr, MIDb, nullptr, 1, 4096, 2048, 512, 1.f, 1);
            gemmb(stream, MIDb, WT + wt_mlp2 + (size_t)dl * 1048576, mlp_b2 + dl * 512,
                  h, h, nullptr, nullptr, 1, 4096, 512, 2048, 1.f, 0);
        }
    }

    add_kernel<<<2048, 256, 0, stream>>>(L2R, R2L, Z, 2097152);
    ln_kernel<<<4096, 256, 0, stream>>>(L2R, nullptr, ro1s, ro1b, nullptr, Qb, 512, nullptr, 1024);
    ln_kernel<<<4096, 256, 0, stream>>>(R2L, nullptr, ro2s, ro2b, nullptr, Kb, 512, nullptr, 1024);
    add_bf16<<<1024, 256, 0, stream>>>((const unsigned int*)Qb, (const unsigned int*)Kb,
                                       (unsigned int*)Vb, 1048576);
    build_allv_b<<<dim3(2049, 4), 64, 0, stream>>>(TEMBb, Qb, Kb, ALLVb);
    gemmb(stream, Vb, WT + wt_caq, nullptr, nullptr, nullptr, Zb, nullptr, 1,
          4096, 512, 512, 0.125f, 0);
    gemmb(stream, ALLVb, WT + wt_cak, ca_bk, nullptr, nullptr, K2b, nullptr, 1,
          8320, 512, 512, 1.f, 0);
    gemmb(stream, ALLVb, WT + wt_cav, ca_bv, nullptr, nullptr, nullptr, V2T, 2080,
          8320, 512, 512, 1.f, 0);
    attn_mfma<<<dim3(512), dim3(256), 0, stream>>>(Zb, K2b, V2T, Ob, 2);
    gemmb(stream, Ob, WT + wt_cao, ca_bo, Z, nullptr, Qb, nullptr, 1,
          4096, 512, 512, 1.f, 0);

    sgemm4(stream, TEMB, tm_W1, tm_b1, TM1, SKP, 2048, 512, 1);
    sgemm4(stream, TM1, tm_W2, tm_b2, T4, SKP, 2048, 2048, 0);

    gemmb(stream, Qb, WT + wt_in, in_b, nullptr, H2, H2b, nullptr, 1,
          4096, 1024, 512, 1.f, 0);
    for (int i = 0; i < 2; ++i) {
        sgemm4(stream, T4, film_W + (size_t)i * 4194304, film_b + i * 2048,
               FILM, SKP, 2048, 2048, 0);
        gemmb(stream, H2b, WT + wt_res1 + (size_t)i * 2097152, res_b1 + i * 2048,
              nullptr, nullptr, MIDb, nullptr, 1, 4096, 2048, 1024, 1.f, 1);
        gemmb(stream, MIDb, WT + wt_res2 + (size_t)i * 2097152, res_b2 + i * 1024,
              nullptr, Z2, nullptr, nullptr, 1, 4096, 1024, 2048, 1.f, 0);
        ln_kernel<<<4096, 256, 0, stream>>>(H2, Z2, rls + i * 1024, rlb + i * 1024,
                                            H2, H2b, 1024, FILM, 1024);
    }

    gemmb(stream, H2b, WT + wt_out, out_b, nullptr, out, nullptr, nullptr, 1,
          4096, 256, 1024, 1.f, 0);
}

// Round 7
// 1514.105 us; speedup vs baseline: 10.3313x; 1.2099x over previous
//
#include <hip/hip_runtime.h>
#include <hip/hip_bf16.h>

// ---------------------------------------------------------------------------
// B=4, L=1024, E=512, H=8, NL=2, M=2048, S=256, R=2, Dh=64
// ---------------------------------------------------------------------------

#define NEGF -3.4028235e38f
#define LOG2E 1.4426950408889634f

using bf16x8 = __attribute__((ext_vector_type(8))) short;
using f32x4  = __attribute__((ext_vector_type(4))) float;

__device__ inline float bf2f(unsigned short u) {
    return __uint_as_float(((unsigned int)u) << 16);
}
__device__ inline unsigned short f2b(float f) {
    unsigned int u = __float_as_uint(f);
    return (unsigned short)((u + 0x7fff + ((u >> 16) & 1)) >> 16);
}

// global -> LDS async copy, 16 B per lane
__device__ inline void gl_lds16(const void* g, void* l) {
    __builtin_amdgcn_global_load_lds(
        (const __attribute__((address_space(1))) void*)(uintptr_t)g,
        (__attribute__((address_space(3))) void*)(unsigned int)(uintptr_t)l,
        16, 0, 0);
}

// ---------------------------------------------------------------------------
// bf16 MFMA GEMM, template BM in {64,128}, BN=128, BK=32, 4 waves (2x2),
// 2-phase double-buffered staging (issue next tile's loads before MFMA).
// Wt = W^T stored [N][K] bf16.
// Outputs (qkv==0): Cf f32, Cb bf16, Ct per-head transposed (B,8,64,ldkv).
// qkv==1 (N=1536, fused QKV): cols 0-511 -> Cb (Q, alpha .125), 512-1023 ->
// CbK (K), 1024-1535 -> Ct (V per-head transposed, ldkv=1024).
// ---------------------------------------------------------------------------
template<int BM>
__global__ __launch_bounds__(256) void gemm_bf16_k(
    const unsigned short* __restrict__ A, const unsigned short* __restrict__ Wt,
    const float* __restrict__ bias, const float* __restrict__ res,
    float* __restrict__ Cf, unsigned short* __restrict__ Cb,
    unsigned short* __restrict__ CbK, unsigned short* __restrict__ Ct, int ldkv,
    int M, int N, int K, float alpha, int gelu_flag, int qkv)
{
    constexpr int MF  = BM / 32;          // m-frags per wave (2 or 4)
    constexpr int NAC = BM * 4 / 256;     // A-staging iterations (1 or 2)
    __shared__ unsigned short As[2][BM * 32];
    __shared__ unsigned short Bs[2][4096];
    const int tid  = threadIdx.x;
    const int wid  = tid >> 6;
    const int lane = tid & 63;
    const int wy   = wid >> 1, wx = wid & 1;
    const int koff = lane >> 4, l16 = lane & 15;
    const int m0 = blockIdx.y * BM, n0 = blockIdx.x * 128;

    // chunk c -> row 16*(c>>6)+(c&15), k-offset ((c>>4)&3)*8
    const unsigned short* aG[NAC];
    const unsigned short* bG[2];
    #pragma unroll
    for (int i = 0; i < NAC; ++i) {
        int c = tid + i * 256;
        int r = ((c >> 6) << 4) | (c & 15), kk = ((c >> 4) & 3) << 3;
        aG[i] = A + (size_t)(m0 + r) * K + kk;
    }
    #pragma unroll
    for (int i = 0; i < 2; ++i) {
        int c = tid + i * 256;
        int r = ((c >> 6) << 4) | (c & 15), kk = ((c >> 4) & 3) << 3;
        bG[i] = Wt + (size_t)(n0 + r) * K + kk;
    }

    f32x4 acc[MF][4] = {};
    const int nk = K >> 5;

    auto stage = [&](int buf, int k0) {
        #pragma unroll
        for (int i = 0; i < NAC; ++i)
            gl_lds16(aG[i] + k0, &As[buf][(size_t)(i * 256 + wid * 64) * 8]);
        #pragma unroll
        for (int i = 0; i < 2; ++i)
            gl_lds16(bG[i] + k0, &Bs[buf][(size_t)(i * 256 + wid * 64) * 8]);
    };

    stage(0, 0);
    __syncthreads();
    int cur = 0;
    for (int it = 0; it < nk; ++it) {
        if (it + 1 < nk) stage(cur ^ 1, (it + 1) << 5);   // prefetch overlaps MFMA
        bf16x8 af[MF], bfr[4];
        const int foff = (koff * 16 + l16) * 8;
        #pragma unroll
        for (int i = 0; i < MF; ++i)
            af[i] = *(const bf16x8*)&As[cur][(size_t)((wy * MF + i) * 64) * 8 + foff];
        #pragma unroll
        for (int j = 0; j < 4; ++j)
            bfr[j] = *(const bf16x8*)&Bs[cur][(size_t)((wx * 4 + j) * 64) * 8 + foff];
        #pragma unroll
        for (int i = 0; i < MF; ++i)
            #pragma unroll
            for (int j = 0; j < 4; ++j)
                acc[i][j] = __builtin_amdgcn_mfma_f32_16x16x32_bf16(
                    af[i], bfr[j], acc[i][j], 0, 0, 0);
        __syncthreads();
        cur ^= 1;
    }

    #pragma unroll
    for (int i = 0; i < MF; ++i) {
        const int rbase = m0 + wy * (MF * 16) + i * 16 + koff * 4;
        #pragma unroll
        for (int j = 0; j < 4; ++j) {
            const int gn = n0 + wx * 64 + j * 16 + l16;
            const float bs = bias ? bias[gn] : 0.f;
            if (qkv) {
                const int seg = gn >> 9, gnl = gn & 511;
                const float av = (seg == 0) ? 0.125f : 1.0f;
                unsigned short o[4];
                #pragma unroll
                for (int r = 0; r < 4; ++r) o[r] = f2b((acc[i][j][r] + bs) * av);
                if (seg == 0) {
                    #pragma unroll
                    for (int r = 0; r < 4; ++r)
                        Cb[(size_t)(rbase + r) * 512 + gnl] = o[r];
                } else if (seg == 1) {
                    #pragma unroll
                    for (int r = 0; r < 4; ++r)
                        CbK[(size_t)(rbase + r) * 512 + gnl] = o[r];
                } else {
                    const int hh = gnl >> 6, dh = gnl & 63;
                    const int bb = rbase >> 10, l0 = rbase & 1023;
                    *(ushort4*)(Ct + ((size_t)(bb * 8 + hh) * 64 + dh) * 1024 + l0) =
                        make_ushort4(o[0], o[1], o[2], o[3]);
                }
            } else {
                float vr[4];
                #pragma unroll
                for (int r = 0; r < 4; ++r) {
                    float v = (acc[i][j][r] + bs) * alpha;
                    if (gelu_flag) v = 0.5f * v * (1.0f + erff(v * 0.70710678118654752f));
                    const size_t idx = (size_t)(rbase + r) * N + gn;
                    if (res) v += res[idx];
                    if (Cf) Cf[idx] = v;
                    if (Cb) Cb[idx] = f2b(v);
                    vr[r] = v;
                }
                if (Ct) {
                    const int hh = gn >> 6, dh = gn & 63;
                    const int bb = rbase / ldkv;
                    const int l0 = rbase - bb * ldkv;
                    *(ushort4*)(Ct + ((size_t)(bb * 8 + hh) * 64 + dh) * ldkv + l0) =
                        make_ushort4(f2b(vr[0]), f2b(vr[1]), f2b(vr[2]), f2b(vr[3]));
                }
            }
        }
    }
}

// ---------------------------------------------------------------------------
// weight transpose-convert: src fp32 [K][N] -> dst bf16 [N][K]
// ---------------------------------------------------------------------------
__global__ __launch_bounds__(256) void wconv(
    const float* __restrict__ src, unsigned short* __restrict__ dst,
    int K, int N, long sstride, long dstride)
{
    __shared__ float t[64][65];
    const int n0 = blockIdx.x * 64, k0 = blockIdx.y * 64;
    const float* s = src + (size_t)blockIdx.z * sstride;
    unsigned short* d = dst + (size_t)blockIdx.z * dstride;
    const int tid = threadIdx.x;
    #pragma unroll
    for (int i = 0; i < 4; ++i) {
        int lin = i * 1024 + tid * 4;
        int r = lin >> 6, c = lin & 63;
        float4 v = *(const float4*)(s + (size_t)(k0 + r) * N + n0 + c);
        t[r][c] = v.x; t[r][c + 1] = v.y; t[r][c + 2] = v.z; t[r][c + 3] = v.w;
    }
    __syncthreads();
    #pragma unroll
    for (int i = 0; i < 8; ++i) {
        int lin = i * 512 + tid * 2;
        int rn = lin >> 6, ck = lin & 63;
        ushort2 o;
        o.x = f2b(t[ck][rn]); o.y = f2b(t[ck + 1][rn]);
        *(ushort2*)(d + (size_t)(n0 + rn) * K + k0 + ck) = o;
    }
}

// ---------------------------------------------------------------------------
// Skinny GEMM for M=4 (t-MLP / FiLM), split-K, deterministic
// ---------------------------------------------------------------------------
__global__ __launch_bounds__(256) void skinny_k(
    const float* __restrict__ A, const float* __restrict__ W,
    float* __restrict__ P, int N, int K)
{
    const int n = blockIdx.x * 256 + threadIdx.x;
    const int s = blockIdx.y;
    const int k0 = s * 32;
    float a0 = 0.f, a1 = 0.f, a2 = 0.f, a3 = 0.f;
    #pragma unroll 8
    for (int k = k0; k < k0 + 32; ++k) {
        float w = W[(size_t)k * N + n];
        a0 = fmaf(A[k], w, a0);
        a1 = fmaf(A[K + k], w, a1);
        a2 = fmaf(A[2 * K + k], w, a2);
        a3 = fmaf(A[3 * K + k], w, a3);
    }
    float* p = P + (size_t)s * 4 * N;
    p[n] = a0; p[N + n] = a1; p[2 * N + n] = a2; p[3 * N + n] = a3;
}

__global__ __launch_bounds__(256) void skinny_red(
    const float* __restrict__ P, const float* __restrict__ bias,
    float* __restrict__ C, int N, int nsplit, int gelu_flag)
{
    const int n = blockIdx.x * 256 + threadIdx.x;
    const int r = blockIdx.y;
    float acc = 0.f;
    for (int s = 0; s < nsplit; ++s) acc += P[((size_t)s * 4 + r) * N + n];
    float v = acc + (bias ? bias[n] : 0.f);
    if (gelu_flag) v = 0.5f * v * (1.0f + erff(v * 0.70710678118654752f));
    C[(size_t)r * N + n] = v;
}

// ---------------------------------------------------------------------------
// LayerNorm (+optional add, +optional FiLM); fp32 in, fp32 and/or bf16 out
// ---------------------------------------------------------------------------
__global__ __launch_bounds__(256) void ln_kernel(
    const float* __restrict__ X, const float* __restrict__ X2,
    const float* __restrict__ s, const float* __restrict__ b,
    float* __restrict__ Yf, unsigned short* __restrict__ Yb,
    int D, const float* __restrict__ film, int rows_per_batch)
{
    const int row = blockIdx.x;
    const int tid = threadIdx.x;
    const float* x = X + (size_t)row * D;
    const float* x2 = X2 ? X2 + (size_t)row * D : nullptr;

    float sum = 0.f, sq = 0.f;
    for (int c = tid; c < D; c += 256) {
        float v = x[c] + (x2 ? x2[c] : 0.f);
        sum += v; sq += v * v;
    }
    __shared__ float r1[4], r2[4];
    __shared__ float s_mean, s_rstd;
    for (int off = 32; off > 0; off >>= 1) {
        sum += __shfl_down(sum, off);
        sq  += __shfl_down(sq,  off);
    }
    if ((tid & 63) == 0) { r1[tid >> 6] = sum; r2[tid >> 6] = sq; }
    __syncthreads();
    if (tid == 0) {
        float ts = r1[0] + r1[1] + r1[2] + r1[3];
        float tq = r2[0] + r2[1] + r2[2] + r2[3];
        float mean = ts / (float)D;
        float var = tq / (float)D - mean * mean;
        s_mean = mean;
        s_rstd = rsqrtf(var + 1e-5f);
    }
    __syncthreads();
    const float mean = s_mean, rstd = s_rstd;
    const float* fa = nullptr; const float* fb = nullptr;
    if (film) {
        int batch = row / rows_per_batch;
        fa = film + (size_t)batch * 2 * D;
        fb = fa + D;
    }
    for (int c = tid; c < D; c += 256) {
        float v = x[c] + (x2 ? x2[c] : 0.f);
        float y = (v - mean) * rstd * s[c] + b[c];
        if (film) y = fa[c] * y + fb[c];
        if (Yf) Yf[(size_t)row * D + c] = y;
        if (Yb) Yb[(size_t)row * D + c] = f2b(y);
    }
}

__global__ void temb_kernel(const float* __restrict__ t, float* __restrict__ temb,
                            unsigned short* __restrict__ tembb)
{
    int b = blockIdx.x;
    int i = threadIdx.x;
    float f = expf((float)i * (-9.210340371976184f / 255.0f));
    float a = t[b] * f;
    float sv = sinf(a), cv = cosf(a);
    temb[b * 512 + i]        = sv;
    temb[b * 512 + 256 + i]  = cv;
    tembb[b * 512 + i]       = f2b(sv);
    tembb[b * 512 + 256 + i] = f2b(cv);
}

__global__ void embed_kernel(const int* __restrict__ x, const float* __restrict__ temb,
                             const float* __restrict__ embed,
                             float* __restrict__ l2r, float* __restrict__ r2l)
{
    const int i = blockIdx.x;
    const int b = blockIdx.y;
    const int d = blockIdx.z;
    float* out = (d == 0 ? l2r : r2l) + ((size_t)(b * 1024 + i) * 512);
    const float* src;
    if (d == 0) src = (i == 0)    ? temb + b * 512 : embed + (size_t)x[b * 1024 + (i - 1)] * 512;
    else        src = (i == 1023) ? temb + b * 512 : embed + (size_t)x[b * 1024 + (i + 1)] * 512;
    for (int e = threadIdx.x; e < 512; e += 256) {
        int j = e >> 1;
        float div = expf((float)(2 * j) * (-9.210340371976184f / 512.0f));
        float ang = (float)i * div;
        float pe = (e & 1) ? cosf(ang) : sinf(ang);
        out[e] = src[e] + pe;
    }
}

__global__ void add_kernel(const float* __restrict__ A, const float* __restrict__ B,
                           float* __restrict__ C, int n)
{
    int i = blockIdx.x * blockDim.x + threadIdx.x;
    int stride = gridDim.x * blockDim.x;
    for (; i < n; i += stride) C[i] = A[i] + B[i];
}

__global__ void add_bf16(const unsigned int* __restrict__ A,
                         const unsigned int* __restrict__ B,
                         unsigned int* __restrict__ C, int nwords)
{
    int i = blockIdx.x * blockDim.x + threadIdx.x;
    int stride = gridDim.x * blockDim.x;
    for (; i < nwords; i += stride) {
        unsigned int a = A[i], b = B[i];
        float lo = __uint_as_float(a << 16) + __uint_as_float(b << 16);
        float hi = __uint_as_float(a & 0xffff0000u) + __uint_as_float(b & 0xffff0000u);
        C[i] = (unsigned int)f2b(lo) | ((unsigned int)f2b(hi) << 16);
    }
}

__global__ void build_allv_b(const unsigned short* __restrict__ tembb,
                             const unsigned short* __restrict__ l2rn,
                             const unsigned short* __restrict__ r2ln,
                             unsigned short* __restrict__ allv)
{
    const int k = blockIdx.x;
    const int b = blockIdx.y;
    unsigned short* out = allv + ((size_t)b * 2080 + k) * 512;
    const unsigned short* src;
    if (k == 0)         src = tembb + b * 512;
    else if (k <= 1024) src = l2rn + ((size_t)(b * 1024 + (k - 1)) * 512);
    else                src = r2ln + ((size_t)(b * 1024 + (k - 1025)) * 512);
    ((uint4*)out)[threadIdx.x] = ((const uint4*)src)[threadIdx.x];
}

// ---------------------------------------------------------------------------
// MFMA flash attention, bf16 in/out, fp32 accumulate. (unchanged from R6)
// ---------------------------------------------------------------------------
__global__ __launch_bounds__(256) void attn_mfma(
    const unsigned short* __restrict__ Q, const unsigned short* __restrict__ K,
    const unsigned short* __restrict__ Vt, unsigned short* __restrict__ O, int mode)
{
    const int E = 512;
    const int LKP = (mode == 2) ? 2080 : 1024;
    const int idf = blockIdx.x;
    const int w = (idf & 7) * 64 + (idf >> 3);
    const int qt = w & 15, h = (w >> 4) & 7, b = w >> 7;
    const int q0 = qt * 64;
    const int tid = threadIdx.x;
    const int wid = tid >> 6, lane = tid & 63;
    const int fr = lane & 15;
    const int fs = lane >> 4;
    const int wq0 = q0 + wid * 16;

    __shared__ unsigned short Qs[4096];
    __shared__ unsigned short Ks[4096];
    __shared__ unsigned short Vs[4096];
    __shared__ unsigned short Ps[4][16][72];

    {
        const unsigned short* Qbase = Q + ((size_t)b * 1024 + q0) * E + h * 64;
        #pragma unroll
        for (int it = 0; it < 2; ++it) {
            int i = tid + it * 256;
            int r = i & 63, c = i >> 6;
            *(uint4*)&Qs[(size_t)(c * 64 + r) * 8] =
                *(const uint4*)(Qbase + (size_t)r * E + c * 8);
        }
    }
    __syncthreads();
    const bf16x8 aq0 = *(const bf16x8*)&Qs[(size_t)(fs * 64 + wid * 16 + fr) * 8];
    const bf16x8 aq1 = *(const bf16x8*)&Qs[(size_t)((fs + 4) * 64 + wid * 16 + fr) * 8];

    float m_r[4], l_r[4];
    f32x4 o_acc[4] = {};
    #pragma unroll
    for (int r = 0; r < 4; ++r) { m_r[r] = NEGF; l_r[r] = 0.f; }

    int kt0, kt1;
    if (mode == 0)      { kt0 = 0;  kt1 = qt; }
    else if (mode == 1) { kt0 = qt; kt1 = 15; }
    else                { kt0 = 0;  kt1 = 31; }

    const unsigned short* Kb0 = K + ((size_t)b * LKP) * E + h * 64;
    const unsigned short* Vb0 = Vt + (size_t)(b * 8 + h) * 64 * LKP;

    for (int kt = kt0; kt <= kt1; ++kt) {
        if (mode == 2) {
            if (kt >= 1 && kt <= 15 && 64 * kt + 62 <= q0) continue;
            if (kt >= 17 && 64 * kt - 1025 >= q0 + 63) continue;
        }
        const int k0 = kt * 64;

        __syncthreads();

        {
            const unsigned short* Kbase = Kb0 + (size_t)k0 * E;
            const unsigned short* Vbase = Vb0 + k0;
            #pragma unroll
            for (int it = 0; it < 2; ++it) {
                int i = tid + it * 256;
                int r = i & 63, c = i >> 6;
                *(uint4*)&Ks[(size_t)(c * 64 + r) * 8] =
                    *(const uint4*)(Kbase + (size_t)r * E + c * 8);
                *(uint4*)&Vs[(size_t)(c * 64 + r) * 8] =
                    *(const uint4*)(Vbase + (size_t)r * LKP + c * 8);
            }
        }
        __syncthreads();

        f32x4 s[4] = {};
        #pragma unroll
        for (int t = 0; t < 4; ++t) {
            bf16x8 bk0 = *(const bf16x8*)&Ks[(size_t)(fs * 64 + t * 16 + fr) * 8];
            bf16x8 bk1 = *(const bf16x8*)&Ks[(size_t)((fs + 4) * 64 + t * 16 + fr) * 8];
            s[t] = __builtin_amdgcn_mfma_f32_16x16x32_bf16(aq0, bk0, s[t], 0, 0, 0);
            s[t] = __builtin_amdgcn_mfma_f32_16x16x32_bf16(aq1, bk1, s[t], 0, 0, 0);
        }

        #pragma unroll
        for (int t = 0; t < 4; ++t) {
            #pragma unroll
            for (int r = 0; r < 4; ++r) {
                int q = wq0 + fs * 4 + r;
                int k = k0 + t * 16 + fr;
                bool valid;
                if (mode == 0)      valid = (k <= q);
                else if (mode == 1) valid = (k >= q);
                else valid = (k == 0) || (k <= 1024 ? (k - 1) > q : (k - 1025) < q);
                if (!valid) s[t][r] = NEGF;
            }
        }

        float c_[4], rs[4];
        #pragma unroll
        for (int r = 0; r < 4; ++r) {
            float v = fmaxf(fmaxf(s[0][r], s[1][r]), fmaxf(s[2][r], s[3][r]));
            v = fmaxf(v, __shfl_xor(v, 1));
            v = fmaxf(v, __shfl_xor(v, 2));
            v = fmaxf(v, __shfl_xor(v, 4));
            v = fmaxf(v, __shfl_xor(v, 8));
            float mnew = fmaxf(m_r[r], v);
            c_[r] = exp2f((m_r[r] - mnew) * LOG2E);
            m_r[r] = mnew;
            rs[r] = 0.f;
        }
        #pragma unroll
        for (int t = 0; t < 4; ++t) {
            #pragma unroll
            for (int r = 0; r < 4; ++r) {
                float p = exp2f((s[t][r] - m_r[r]) * LOG2E);
                s[t][r] = p;
                rs[r] += p;
            }
        }
        #pragma unroll
        for (int r = 0; r < 4; ++r) {
            float v = rs[r];
            v += __shfl_xor(v, 1);
            v += __shfl_xor(v, 2);
            v += __shfl_xor(v, 4);
            v += __shfl_xor(v, 8);
            l_r[r] = l_r[r] * c_[r] + v;
            o_acc[0][r] *= c_[r]; o_acc[1][r] *= c_[r];
            o_acc[2][r] *= c_[r]; o_acc[3][r] *= c_[r];
        }

        #pragma unroll
        for (int t = 0; t < 4; ++t)
            #pragma unroll
            for (int r = 0; r < 4; ++r)
                Ps[wid][fs * 4 + r][t * 16 + fr] = f2b(s[t][r]);
        __syncthreads();

        bf16x8 pa0 = *(const bf16x8*)&Ps[wid][fr][fs * 8];
        bf16x8 pa1 = *(const bf16x8*)&Ps[wid][fr][fs * 8 + 32];
        #pragma unroll
        for (int t = 0; t < 4; ++t) {
            bf16x8 bv0 = *(const bf16x8*)&Vs[(size_t)(fs * 64 + t * 16 + fr) * 8];
            bf16x8 bv1 = *(const bf16x8*)&Vs[(size_t)((fs + 4) * 64 + t * 16 + fr) * 8];
            o_acc[t] = __builtin_amdgcn_mfma_f32_16x16x32_bf16(pa0, bv0, o_acc[t], 0, 0, 0);
            o_acc[t] = __builtin_amdgcn_mfma_f32_16x16x32_bf16(pa1, bv1, o_acc[t], 0, 0, 0);
        }
    }

    unsigned short* Obase = O + ((size_t)b * 1024 + q0) * E + h * 64;
    float invl[4];
    #pragma unroll
    for (int r = 0; r < 4; ++r) invl[r] = 1.f / l_r[r];
    #pragma unroll
    for (int t = 0; t < 4; ++t)
        #pragma unroll
        for (int r = 0; r < 4; ++r)
            Obase[(size_t)(wid * 16 + fs * 4 + r) * E + t * 16 + fr] =
                f2b(o_acc[t][r] * invl[r]);
}

// ---------------------------------------------------------------------------

static inline void gemmb(hipStream_t st, int BM, const unsigned short* A,
                         const unsigned short* Wt, const float* bias,
                         const float* res, float* Cf, unsigned short* Cb,
                         unsigned short* CbK, unsigned short* Ct, int ldkv,
                         int M, int N, int K, float alpha, int gelu, int qkv)
{
    dim3 g(N / 128, M / BM);
    if (BM == 128)
        gemm_bf16_k<128><<<g, dim3(256), 0, st>>>(A, Wt, bias, res, Cf, Cb, CbK,
                                                  Ct, ldkv, M, N, K, alpha, gelu, qkv);
    else
        gemm_bf16_k<64><<<g, dim3(256), 0, st>>>(A, Wt, bias, res, Cf, Cb, CbK,
                                                 Ct, ldkv, M, N, K, alpha, gelu, qkv);
}

static inline void sgemm4(hipStream_t st, const float* A, const float* W,
                          const float* bias, float* C, float* P,
                          int N, int K, int gelu)
{
    const int nsplit = K / 32;
    skinny_k<<<dim3(N / 256, nsplit), 256, 0, st>>>(A, W, P, N, K);
    skinny_red<<<dim3(N / 256, 4), 256, 0, st>>>(P, bias, C, N, nsplit, gelu);
}

extern "C" void kernel_launch(void* const* d_in, const int* in_sizes, int n_in,
                              void* d_out, int out_size, void* d_ws, size_t ws_size,
                              hipStream_t stream)
{
    const int*   x      = (const int*)  d_in[0];
    const float* t      = (const float*)d_in[1];
    const float* embedW = (const float*)d_in[2];
    const float* attn_W = (const float*)d_in[3];
    const float* attn_b = (const float*)d_in[4];
    const float* ln_s   = (const float*)d_in[5];
    const float* ln_b   = (const float*)d_in[6];
    const float* mlp_W1 = (const float*)d_in[7];
    const float* mlp_b1 = (const float*)d_in[8];
    const float* mlp_W2 = (const float*)d_in[9];
    const float* mlp_b2 = (const float*)d_in[10];
    const float* ca_Wq  = (const float*)d_in[11];
    const float* ca_Wk  = (const float*)d_in[12];
    const float* ca_bk  = (const float*)d_in[13];
    const float* ca_Wv  = (const float*)d_in[14];
    const float* ca_bv  = (const float*)d_in[15];
    const float* ca_Wo  = (const float*)d_in[16];
    const float* ca_bo  = (const float*)d_in[17];
    const float* ro1s   = (const float*)d_in[18];
    const float* ro1b   = (const float*)d_in[19];
    const float* ro2s   = (const float*)d_in[20];
    const float* ro2b   = (const float*)d_in[21];
    const float* in_W   = (const float*)d_in[22];
    const float* in_b   = (const float*)d_in[23];
    const float* tm_W1  = (const float*)d_in[24];
    const float* tm_b1  = (const float*)d_in[25];
    const float* tm_W2  = (const float*)d_in[26];
    const float* tm_b2  = (const float*)d_in[27];
    const float* res_W1 = (const float*)d_in[28];
    const float* res_b1 = (const float*)d_in[29];
    const float* res_W2 = (const float*)d_in[30];
    const float* res_b2 = (const float*)d_in[31];
    const float* rls    = (const float*)d_in[32];
    const float* rlb    = (const float*)d_in[33];
    const float* film_W = (const float*)d_in[34];
    const float* film_b = (const float*)d_in[35];
    const float* out_W  = (const float*)d_in[36];
    const float* out_b  = (const float*)d_in[37];
    float* out = (float*)d_out;
    (void)ws_size; (void)in_sizes; (void)n_in; (void)out_size;

    char* base = (char*)d_ws;
    size_t off = 0;
    auto alloc = [&](size_t bytes) -> char* {
        char* p = base + off;
        off = (off + bytes + 255) & ~(size_t)255;
        return p;
    };
    float* TEMB  = (float*)alloc(8192);
    float* TM1   = (float*)alloc(32768);
    float* T4    = (float*)alloc(32768);
    float* FILM  = (float*)alloc(32768);
    unsigned short* TEMBb = (unsigned short*)alloc(4096);
    float* SKP   = (float*)alloc(2097152);

    float* L2R = (float*)alloc(8388608);
    float* R2L = (float*)alloc(8388608);
    float* Z   = (float*)alloc(8388608);
    float* H2  = (float*)alloc(16777216);
    float* Z2  = (float*)alloc(16777216);

    unsigned short* Zb  = (unsigned short*)alloc(4194304);
    unsigned short* Qb  = (unsigned short*)alloc(4194304);
    unsigned short* Kb  = (unsigned short*)alloc(4194304);
    unsigned short* Vb  = (unsigned short*)alloc(4194304);   // self V^T / readout temp
    unsigned short* Ob  = (unsigned short*)alloc(4194304);
    unsigned short* H2b = (unsigned short*)alloc(8388608);

    unsigned short* BIG = (unsigned short*)alloc(25559040);
    unsigned short* MIDb  = BIG;                 // 4096x2048 (blocks / res-MLP)
    unsigned short* ALLVb = BIG;                 // 8320x512 (readout)
    unsigned short* K2b   = BIG + 4259840;       // 8320x512
    unsigned short* V2T   = BIG + 8519680;       // (4,8,64,2080)

    unsigned short* WT = (unsigned short*)alloc(45613056);
    const size_t wt_attn = 0,        wt_mlp1 = 4194304, wt_mlp2 = 8388608;
    const size_t wt_caq = 12582912,  wt_cak = 12845056, wt_cav = 13107200,
                 wt_cao = 13369344,  wt_in  = 13631488;
    const size_t wt_res1 = 14155776, wt_res2 = 18350080, wt_out = 22544384;

    wconv<<<dim3(8, 8, 16), 256, 0, stream>>>(attn_W, WT + wt_attn, 512, 512, 262144, 262144);
    wconv<<<dim3(32, 8, 4), 256, 0, stream>>>(mlp_W1, WT + wt_mlp1, 512, 2048, 1048576, 1048576);
    wconv<<<dim3(8, 32, 4), 256, 0, stream>>>(mlp_W2, WT + wt_mlp2, 2048, 512, 1048576, 1048576);
    wconv<<<dim3(8, 8), 256, 0, stream>>>(ca_Wq, WT + wt_caq, 512, 512, 0, 0);
    wconv<<<dim3(8, 8), 256, 0, stream>>>(ca_Wk, WT + wt_cak, 512, 512, 0, 0);
    wconv<<<dim3(8, 8), 256, 0, stream>>>(ca_Wv, WT + wt_cav, 512, 512, 0, 0);
    wconv<<<dim3(8, 8), 256, 0, stream>>>(ca_Wo, WT + wt_cao, 512, 512, 0, 0);
    wconv<<<dim3(16, 8), 256, 0, stream>>>(in_W, WT + wt_in, 512, 1024, 0, 0);
    wconv<<<dim3(32, 16, 2), 256, 0, stream>>>(res_W1, WT + wt_res1, 1024, 2048, 2097152, 2097152);
    wconv<<<dim3(16, 32, 2), 256, 0, stream>>>(res_W2, WT + wt_res2, 2048, 1024, 2097152, 2097152);
    wconv<<<dim3(4, 16), 256, 0, stream>>>(out_W, WT + wt_out, 1024, 256, 0, 0);

    temb_kernel<<<dim3(4), dim3(256), 0, stream>>>(t, TEMB, TEMBb);
    embed_kernel<<<dim3(1024, 4, 2), dim3(256), 0, stream>>>(x, TEMB, embedW, L2R, R2L);

    for (int d = 0; d < 2; ++d) {
        float* h = (d == 0) ? L2R : R2L;
        for (int l = 0; l < 2; ++l) {
            const int dl = d * 2 + l;
            ln_kernel<<<4096, 256, 0, stream>>>(h, nullptr, ln_s + (dl * 2 + 0) * 512,
                                                ln_b + (dl * 2 + 0) * 512, nullptr, Zb,
                                                512, nullptr, 1024);
            // fused QKV: N=1536 (Wq^T|Wk^T|Wv^T contiguous in WT; biases contiguous)
            gemmb(stream, 64, Zb, WT + wt_attn + (size_t)dl * 4 * 262144,
                  attn_b + dl * 2048, nullptr, nullptr, Qb, Kb, Vb, 1024,
                  4096, 1536, 512, 1.f, 0, 1);
            attn_mfma<<<dim3(512), dim3(256), 0, stream>>>(Qb, Kb, Vb, Ob, d);
            gemmb(stream, 64, Ob, WT + wt_attn + (size_t)(dl * 4 + 3) * 262144,
                  attn_b + (dl * 4 + 3) * 512, h, h, nullptr, nullptr, nullptr, 1,
                  4096, 512, 512, 1.f, 0, 0);
            ln_kernel<<<4096, 256, 0, stream>>>(h, nullptr, ln_s + (dl * 2 + 1) * 512,
                                                ln_b + (dl * 2 + 1) * 512, nullptr, Zb,
                                                512, nullptr, 1024);
            gemmb(stream, 128, Zb, WT + wt_mlp1 + (size_t)dl * 1048576, mlp_b1 + dl * 2048,
                  nullptr, nullptr, MIDb, nullptr, nullptr, 1, 4096, 2048, 512, 1.f, 1, 0);
            gemmb(stream, 64, MIDb, WT + wt_mlp2 + (size_t)dl * 1048576, mlp_b2 + dl * 512,
                  h, h, nullptr, nullptr, nullptr, 1, 4096, 512, 2048, 1.f, 0, 0);
        }
    }

    add_kernel<<<2048, 256, 0, stream>>>(L2R, R2L, Z, 2097152);
    ln_kernel<<<4096, 256, 0, stream>>>(L2R, nullptr, ro1s, ro1b, nullptr, Qb, 512, nullptr, 1024);
    ln_kernel<<<4096, 256, 0, stream>>>(R2L, nullptr, ro2s, ro2b, nullptr, Kb, 512, nullptr, 1024);
    add_bf16<<<1024, 256, 0, stream>>>((const unsigned int*)Qb, (const unsigned int*)Kb,
                                       (unsigned int*)Vb, 1048576);
    build_allv_b<<<dim3(2049, 4), 64, 0, stream>>>(TEMBb, Qb, Kb, ALLVb);
    gemmb(stream, 64, Vb, WT + wt_caq, nullptr, nullptr, nullptr, Zb, nullptr, nullptr, 1,
          4096, 512, 512, 0.125f, 0, 0);
    gemmb(stream, 64, ALLVb, WT + wt_cak, ca_bk, nullptr, nullptr, K2b, nullptr, nullptr, 1,
          8320, 512, 512, 1.f, 0, 0);
    gemmb(stream, 64, ALLVb, WT + wt_cav, ca_bv, nullptr, nullptr, nullptr, nullptr, V2T, 2080,
          8320, 512, 512, 1.f, 0, 0);
    attn_mfma<<<dim3(512), dim3(256), 0, stream>>>(Zb, K2b, V2T, Ob, 2);
    gemmb(stream, 64, Ob, WT + wt_cao, ca_bo, Z, nullptr, Qb, nullptr, nullptr, 1,
          4096, 512, 512, 1.f, 0, 0);

    sgemm4(stream, TEMB, tm_W1, tm_b1, TM1, SKP, 2048, 512, 1);
    sgemm4(stream, TM1, tm_W2, tm_b2, T4, SKP, 2048, 2048, 0);

    gemmb(stream, 64, Qb, WT + wt_in, in_b, nullptr, H2, H2b, nullptr, nullptr, 1,
          4096, 1024, 512, 1.f, 0, 0);
    for (int i = 0; i < 2; ++i) {
        sgemm4(stream, T4, film_W + (size_t)i * 4194304, film_b + i * 2048,
               FILM, SKP, 2048, 2048, 0);
        gemmb(stream, 128, H2b, WT + wt_res1 + (size_t)i * 2097152, res_b1 + i * 2048,
              nullptr, nullptr, MIDb, nullptr, nullptr, 1, 4096, 2048, 1024, 1.f, 1, 0);
        gemmb(stream, 64, MIDb, WT + wt_res2 + (size_t)i * 2097152, res_b2 + i * 1024,
              nullptr, Z2, nullptr, nullptr, nullptr, 1, 4096, 1024, 2048, 1.f, 0, 0);
        ln_kernel<<<4096, 256, 0, stream>>>(H2, Z2, rls + i * 1024, rlb + i * 1024,
                                            H2, H2b, 1024, FILM, 1024);
    }

    gemmb(stream, 64, H2b, WT + wt_out, out_b, nullptr, out, nullptr, nullptr, nullptr, 1,
          4096, 256, 1024, 1.f, 0, 0);
}

// Round 8
// 1213.089 us; speedup vs baseline: 12.8949x; 1.2481x over previous
//
#include <hip/hip_runtime.h>
#include <hip/hip_bf16.h>

// ---------------------------------------------------------------------------
// B=4, L=1024, E=512, H=8, NL=2, M=2048, S=256, R=2, Dh=64
// Both transformer directions merged: residual stream HB has 8192 rows,
// row = d*4096 + b*1024 + i ; "bb" = row>>10 = d*4+b (8 merged batches).
// ---------------------------------------------------------------------------

#define NEGF -3.4028235e38f
#define LOG2E 1.4426950408889634f

using bf16x8 = __attribute__((ext_vector_type(8))) short;
using f32x4  = __attribute__((ext_vector_type(4))) float;

__device__ inline float bf2f(unsigned short u) {
    return __uint_as_float(((unsigned int)u) << 16);
}
__device__ inline unsigned short f2b(float f) {
    unsigned int u = __float_as_uint(f);
    return (unsigned short)((u + 0x7fff + ((u >> 16) & 1)) >> 16);
}

__device__ inline void gl_lds16(const void* g, void* l) {
    __builtin_amdgcn_global_load_lds(
        (const __attribute__((address_space(1))) void*)(uintptr_t)g,
        (__attribute__((address_space(3))) void*)(unsigned int)(uintptr_t)l,
        16, 0, 0);
}

// ---------------------------------------------------------------------------
// bf16 MFMA GEMM, BM in {64,128}, BN=128, BK=32, 4 waves, double-buffered.
// Two weight/bias pointers: rows >= mhalf use Wt1/bias1 (merged directions;
// BM divides mhalf so tiles never straddle).
// qkv==1 (N=1536): cols 0-511 -> Cb (Q, x0.125), 512-1023 -> CbK (K),
// 1024-1535 -> Ct (V per-head transposed (BB,8,64,1024), BB=rows/1024).
// qkv==0: Cf f32, Cb bf16, Ct per-head transposed with row-stride ldkv.
// ---------------------------------------------------------------------------
template<int BM>
__global__ __launch_bounds__(256) void gemm_bf16_k(
    const unsigned short* __restrict__ A,
    const unsigned short* __restrict__ Wt0, const unsigned short* __restrict__ Wt1,
    const float* __restrict__ bias0, const float* __restrict__ bias1, int mhalf,
    const float* __restrict__ res,
    float* __restrict__ Cf, unsigned short* __restrict__ Cb,
    unsigned short* __restrict__ CbK, unsigned short* __restrict__ Ct, int ldkv,
    int M, int N, int K, float alpha, int gelu_flag, int qkv)
{
    constexpr int MF  = BM / 32;
    constexpr int NAC = BM * 4 / 256;
    __shared__ unsigned short As[2][BM * 32];
    __shared__ unsigned short Bs[2][4096];
    const int tid  = threadIdx.x;
    const int wid  = tid >> 6;
    const int lane = tid & 63;
    const int wy   = wid >> 1, wx = wid & 1;
    const int koff = lane >> 4, l16 = lane & 15;
    const int m0 = blockIdx.y * BM, n0 = blockIdx.x * 128;

    const unsigned short* Wt = (m0 < mhalf) ? Wt0 : Wt1;
    const float* bias = (m0 < mhalf) ? bias0 : bias1;

    const unsigned short* aG[NAC];
    const unsigned short* bG[2];
    #pragma unroll
    for (int i = 0; i < NAC; ++i) {
        int c = tid + i * 256;
        int r = ((c >> 6) << 4) | (c & 15), kk = ((c >> 4) & 3) << 3;
        aG[i] = A + (size_t)(m0 + r) * K + kk;
    }
    #pragma unroll
    for (int i = 0; i < 2; ++i) {
        int c = tid + i * 256;
        int r = ((c >> 6) << 4) | (c & 15), kk = ((c >> 4) & 3) << 3;
        bG[i] = Wt + (size_t)(n0 + r) * K + kk;
    }

    f32x4 acc[MF][4] = {};
    const int nk = K >> 5;

    auto stage = [&](int buf, int k0) {
        #pragma unroll
        for (int i = 0; i < NAC; ++i)
            gl_lds16(aG[i] + k0, &As[buf][(size_t)(i * 256 + wid * 64) * 8]);
        #pragma unroll
        for (int i = 0; i < 2; ++i)
            gl_lds16(bG[i] + k0, &Bs[buf][(size_t)(i * 256 + wid * 64) * 8]);
    };

    stage(0, 0);
    __syncthreads();
    int cur = 0;
    for (int it = 0; it < nk; ++it) {
        if (it + 1 < nk) stage(cur ^ 1, (it + 1) << 5);
        bf16x8 af[MF], bfr[4];
        const int foff = (koff * 16 + l16) * 8;
        #pragma unroll
        for (int i = 0; i < MF; ++i)
            af[i] = *(const bf16x8*)&As[cur][(size_t)((wy * MF + i) * 64) * 8 + foff];
        #pragma unroll
        for (int j = 0; j < 4; ++j)
            bfr[j] = *(const bf16x8*)&Bs[cur][(size_t)((wx * 4 + j) * 64) * 8 + foff];
        #pragma unroll
        for (int i = 0; i < MF; ++i)
            #pragma unroll
            for (int j = 0; j < 4; ++j)
                acc[i][j] = __builtin_amdgcn_mfma_f32_16x16x32_bf16(
                    af[i], bfr[j], acc[i][j], 0, 0, 0);
        __syncthreads();
        cur ^= 1;
    }

    #pragma unroll
    for (int i = 0; i < MF; ++i) {
        const int rbase = m0 + wy * (MF * 16) + i * 16 + koff * 4;
        #pragma unroll
        for (int j = 0; j < 4; ++j) {
            const int gn = n0 + wx * 64 + j * 16 + l16;
            const float bs = bias ? bias[gn] : 0.f;
            if (qkv) {
                const int seg = gn >> 9, gnl = gn & 511;
                const float av = (seg == 0) ? 0.125f : 1.0f;
                unsigned short o[4];
                #pragma unroll
                for (int r = 0; r < 4; ++r) o[r] = f2b((acc[i][j][r] + bs) * av);
                if (seg == 0) {
                    #pragma unroll
                    for (int r = 0; r < 4; ++r)
                        Cb[(size_t)(rbase + r) * 512 + gnl] = o[r];
                } else if (seg == 1) {
                    #pragma unroll
                    for (int r = 0; r < 4; ++r)
                        CbK[(size_t)(rbase + r) * 512 + gnl] = o[r];
                } else {
                    const int hh = gnl >> 6, dh = gnl & 63;
                    const int bb = rbase >> 10, l0 = rbase & 1023;
                    *(ushort4*)(Ct + ((size_t)(bb * 8 + hh) * 64 + dh) * 1024 + l0) =
                        make_ushort4(o[0], o[1], o[2], o[3]);
                }
            } else {
                float vr[4];
                #pragma unroll
                for (int r = 0; r < 4; ++r) {
                    float v = (acc[i][j][r] + bs) * alpha;
                    if (gelu_flag) v = 0.5f * v * (1.0f + erff(v * 0.70710678118654752f));
                    const size_t idx = (size_t)(rbase + r) * N + gn;
                    if (res) v += res[idx];
                    if (Cf) Cf[idx] = v;
                    if (Cb) Cb[idx] = f2b(v);
                    vr[r] = v;
                }
                if (Ct) {
                    const int hh = gn >> 6, dh = gn & 63;
                    const int bb = rbase / ldkv;
                    const int l0 = rbase - bb * ldkv;
                    *(ushort4*)(Ct + ((size_t)(bb * 8 + hh) * 64 + dh) * ldkv + l0) =
                        make_ushort4(f2b(vr[0]), f2b(vr[1]), f2b(vr[2]), f2b(vr[3]));
                }
            }
        }
    }
}

// ---------------------------------------------------------------------------
// weight transpose-convert: src fp32 [K][N] -> dst bf16 [N][K]
// ---------------------------------------------------------------------------
__global__ __launch_bounds__(256) void wconv(
    const float* __restrict__ src, unsigned short* __restrict__ dst,
    int K, int N, long sstride, long dstride)
{
    __shared__ float t[64][65];
    const int n0 = blockIdx.x * 64, k0 = blockIdx.y * 64;
    const float* s = src + (size_t)blockIdx.z * sstride;
    unsigned short* d = dst + (size_t)blockIdx.z * dstride;
    const int tid = threadIdx.x;
    #pragma unroll
    for (int i = 0; i < 4; ++i) {
        int lin = i * 1024 + tid * 4;
        int r = lin >> 6, c = lin & 63;
        float4 v = *(const float4*)(s + (size_t)(k0 + r) * N + n0 + c);
        t[r][c] = v.x; t[r][c + 1] = v.y; t[r][c + 2] = v.z; t[r][c + 3] = v.w;
    }
    __syncthreads();
    #pragma unroll
    for (int i = 0; i < 8; ++i) {
        int lin = i * 512 + tid * 2;
        int rn = lin >> 6, ck = lin & 63;
        ushort2 o;
        o.x = f2b(t[ck][rn]); o.y = f2b(t[ck + 1][rn]);
        *(ushort2*)(d + (size_t)(n0 + rn) * K + k0 + ck) = o;
    }
}

// ---------------------------------------------------------------------------
// Skinny GEMM for M=4, split-K, deterministic
// ---------------------------------------------------------------------------
__global__ __launch_bounds__(256) void skinny_k(
    const float* __restrict__ A, const float* __restrict__ W,
    float* __restrict__ P, int N, int K)
{
    const int n = blockIdx.x * 256 + threadIdx.x;
    const int s = blockIdx.y;
    const int k0 = s * 32;
    float a0 = 0.f, a1 = 0.f, a2 = 0.f, a3 = 0.f;
    #pragma unroll 8
    for (int k = k0; k < k0 + 32; ++k) {
        float w = W[(size_t)k * N + n];
        a0 = fmaf(A[k], w, a0);
        a1 = fmaf(A[K + k], w, a1);
        a2 = fmaf(A[2 * K + k], w, a2);
        a3 = fmaf(A[3 * K + k], w, a3);
    }
    float* p = P + (size_t)s * 4 * N;
    p[n] = a0; p[N + n] = a1; p[2 * N + n] = a2; p[3 * N + n] = a3;
}

__global__ __launch_bounds__(256) void skinny_red(
    const float* __restrict__ P, const float* __restrict__ bias,
    float* __restrict__ C, int N, int nsplit, int gelu_flag)
{
    const int n = blockIdx.x * 256 + threadIdx.x;
    const int r = blockIdx.y;
    float acc = 0.f;
    for (int s = 0; s < nsplit; ++s) acc += P[((size_t)s * 4 + r) * N + n];
    float v = acc + (bias ? bias[n] : 0.f);
    if (gelu_flag) v = 0.5f * v * (1.0f + erff(v * 0.70710678118654752f));
    C[(size_t)r * N + n] = v;
}

// ---------------------------------------------------------------------------
// LayerNorm; per-4096-row param offset pstride (merged directions), optional
// add + FiLM; fp32 in, fp32 and/or bf16 out.
// ---------------------------------------------------------------------------
__global__ __launch_bounds__(256) void ln_kernel(
    const float* __restrict__ X, const float* __restrict__ X2,
    const float* __restrict__ s, const float* __restrict__ b,
    float* __restrict__ Yf, unsigned short* __restrict__ Yb,
    int D, const float* __restrict__ film, int rows_per_batch, long pstride)
{
    const int row = blockIdx.x;
    const int tid = threadIdx.x;
    const float* x = X + (size_t)row * D;
    const float* x2 = X2 ? X2 + (size_t)row * D : nullptr;
    const float* se = s + (size_t)(row >> 12) * pstride;
    const float* be = b + (size_t)(row >> 12) * pstride;

    float sum = 0.f, sq = 0.f;
    for (int c = tid; c < D; c += 256) {
        float v = x[c] + (x2 ? x2[c] : 0.f);
        sum += v; sq += v * v;
    }
    __shared__ float r1[4], r2[4];
    __shared__ float s_mean, s_rstd;
    for (int off = 32; off > 0; off >>= 1) {
        sum += __shfl_down(sum, off);
        sq  += __shfl_down(sq,  off);
    }
    if ((tid & 63) == 0) { r1[tid >> 6] = sum; r2[tid >> 6] = sq; }
    __syncthreads();
    if (tid == 0) {
        float ts = r1[0] + r1[1] + r1[2] + r1[3];
        float tq = r2[0] + r2[1] + r2[2] + r2[3];
        float mean = ts / (float)D;
        float var = tq / (float)D - mean * mean;
        s_mean = mean;
        s_rstd = rsqrtf(var + 1e-5f);
    }
    __syncthreads();
    const float mean = s_mean, rstd = s_rstd;
    const float* fa = nullptr; const float* fb = nullptr;
    if (film) {
        int batch = row / rows_per_batch;
        fa = film + (size_t)batch * 2 * D;
        fb = fa + D;
    }
    for (int c = tid; c < D; c += 256) {
        float v = x[c] + (x2 ? x2[c] : 0.f);
        float y = (v - mean) * rstd * se[c] + be[c];
        if (film) y = fa[c] * y + fb[c];
        if (Yf) Yf[(size_t)row * D + c] = y;
        if (Yb) Yb[(size_t)row * D + c] = f2b(y);
    }
}

__global__ void temb_kernel(const float* __restrict__ t, float* __restrict__ temb,
                            unsigned short* __restrict__ tembb)
{
    int b = blockIdx.x;
    int i = threadIdx.x;
    float f = expf((float)i * (-9.210340371976184f / 255.0f));
    float a = t[b] * f;
    float sv = sinf(a), cv = cosf(a);
    temb[b * 512 + i]        = sv;
    temb[b * 512 + 256 + i]  = cv;
    tembb[b * 512 + i]       = f2b(sv);
    tembb[b * 512 + 256 + i] = f2b(cv);
}

__global__ void embed_kernel(const int* __restrict__ x, const float* __restrict__ temb,
                             const float* __restrict__ embed,
                             float* __restrict__ l2r, float* __restrict__ r2l)
{
    const int i = blockIdx.x;
    const int b = blockIdx.y;
    const int d = blockIdx.z;
    float* out = (d == 0 ? l2r : r2l) + ((size_t)(b * 1024 + i) * 512);
    const float* src;
    if (d == 0) src = (i == 0)    ? temb + b * 512 : embed + (size_t)x[b * 1024 + (i - 1)] * 512;
    else        src = (i == 1023) ? temb + b * 512 : embed + (size_t)x[b * 1024 + (i + 1)] * 512;
    for (int e = threadIdx.x; e < 512; e += 256) {
        int j = e >> 1;
        float div = expf((float)(2 * j) * (-9.210340371976184f / 512.0f));
        float ang = (float)i * div;
        float pe = (e & 1) ? cosf(ang) : sinf(ang);
        out[e] = src[e] + pe;
    }
}

__global__ void add_kernel(const float* __restrict__ A, const float* __restrict__ B,
                           float* __restrict__ C, int n)
{
    int i = blockIdx.x * blockDim.x + threadIdx.x;
    int stride = gridDim.x * blockDim.x;
    for (; i < n; i += stride) C[i] = A[i] + B[i];
}

__global__ void add_bf16(const unsigned int* __restrict__ A,
                         const unsigned int* __restrict__ B,
                         unsigned int* __restrict__ C, int nwords)
{
    int i = blockIdx.x * blockDim.x + threadIdx.x;
    int stride = gridDim.x * blockDim.x;
    for (; i < nwords; i += stride) {
        unsigned int a = A[i], b = B[i];
        float lo = __uint_as_float(a << 16) + __uint_as_float(b << 16);
        float hi = __uint_as_float(a & 0xffff0000u) + __uint_as_float(b & 0xffff0000u);
        C[i] = (unsigned int)f2b(lo) | ((unsigned int)f2b(hi) << 16);
    }
}

__global__ void build_allv_b(const unsigned short* __restrict__ tembb,
                             const unsigned short* __restrict__ l2rn,
                             const unsigned short* __restrict__ r2ln,
                             unsigned short* __restrict__ allv)
{
    const int k = blockIdx.x;
    const int b = blockIdx.y;
    unsigned short* out = allv + ((size_t)b * 2080 + k) * 512;
    const unsigned short* src;
    if (k == 0)         src = tembb + b * 512;
    else if (k <= 1024) src = l2rn + ((size_t)(b * 1024 + (k - 1)) * 512);
    else                src = r2ln + ((size_t)(b * 1024 + (k - 1025)) * 512);
    ((uint4*)out)[threadIdx.x] = ((const uint4*)src)[threadIdx.x];
}

// ---------------------------------------------------------------------------
// MFMA flash attention, bf16 in/out, fp32 accumulate.
// mode -1 (merged self): grid 1024; bb = 0..7 (= d*4+b); causal dir = bb>>2.
// mode  2 (cross):       grid 512;  bb = 0..3; 2049 keys, stride 2080.
// XCD-chunked swizzle: chunk = gridDim.x/8 blocks per XCD.
// ---------------------------------------------------------------------------
__global__ __launch_bounds__(256) void attn_mfma(
    const unsigned short* __restrict__ Q, const unsigned short* __restrict__ K,
    const unsigned short* __restrict__ Vt, unsigned short* __restrict__ O, int mode)
{
    const int E = 512;
    const int LKP = (mode == 2) ? 2080 : 1024;
    const int idf = blockIdx.x;
    const int chunk = gridDim.x >> 3;
    const int w = (idf & 7) * chunk + (idf >> 3);
    const int qt = w & 15, h = (w >> 4) & 7, bb = w >> 7;
    const int dir = (mode == 2) ? 2 : (bb >> 2);
    const int q0 = qt * 64;
    const int tid = threadIdx.x;
    const int wid = tid >> 6, lane = tid & 63;
    const int fr = lane & 15;
    const int fs = lane >> 4;
    const int wq0 = q0 + wid * 16;

    __shared__ unsigned short Qs[4096];
    __shared__ unsigned short Ks[4096];
    __shared__ unsigned short Vs[4096];
    __shared__ unsigned short Ps[4][16][72];

    {
        const unsigned short* Qbase = Q + ((size_t)bb * 1024 + q0) * E + h * 64;
        #pragma unroll
        for (int it = 0; it < 2; ++it) {
            int i = tid + it * 256;
            int r = i & 63, c = i >> 6;
            *(uint4*)&Qs[(size_t)(c * 64 + r) * 8] =
                *(const uint4*)(Qbase + (size_t)r * E + c * 8);
        }
    }
    __syncthreads();
    const bf16x8 aq0 = *(const bf16x8*)&Qs[(size_t)(fs * 64 + wid * 16 + fr) * 8];
    const bf16x8 aq1 = *(const bf16x8*)&Qs[(size_t)((fs + 4) * 64 + wid * 16 + fr) * 8];

    float m_r[4], l_r[4];
    f32x4 o_acc[4] = {};
    #pragma unroll
    for (int r = 0; r < 4; ++r) { m_r[r] = NEGF; l_r[r] = 0.f; }

    int kt0, kt1;
    if (dir == 0)      { kt0 = 0;  kt1 = qt; }
    else if (dir == 1) { kt0 = qt; kt1 = 15; }
    else               { kt0 = 0;  kt1 = 31; }

    const unsigned short* Kb0 = K + ((size_t)bb * LKP) * E + h * 64;
    const unsigned short* Vb0 = Vt + (size_t)(bb * 8 + h) * 64 * LKP;

    for (int kt = kt0; kt <= kt1; ++kt) {
        if (dir == 2) {
            if (kt >= 1 && kt <= 15 && 64 * kt + 62 <= q0) continue;
            if (kt >= 17 && 64 * kt - 1025 >= q0 + 63) continue;
        }
        const int k0 = kt * 64;

        __syncthreads();

        {
            const unsigned short* Kbase = Kb0 + (size_t)k0 * E;
            const unsigned short* Vbase = Vb0 + k0;
            #pragma unroll
            for (int it = 0; it < 2; ++it) {
                int i = tid + it * 256;
                int r = i & 63, c = i >> 6;
                *(uint4*)&Ks[(size_t)(c * 64 + r) * 8] =
                    *(const uint4*)(Kbase + (size_t)r * E + c * 8);
                *(uint4*)&Vs[(size_t)(c * 64 + r) * 8] =
                    *(const uint4*)(Vbase + (size_t)r * LKP + c * 8);
            }
        }
        __syncthreads();

        f32x4 s[4] = {};
        #pragma unroll
        for (int t = 0; t < 4; ++t) {
            bf16x8 bk0 = *(const bf16x8*)&Ks[(size_t)(fs * 64 + t * 16 + fr) * 8];
            bf16x8 bk1 = *(const bf16x8*)&Ks[(size_t)((fs + 4) * 64 + t * 16 + fr) * 8];
            s[t] = __builtin_amdgcn_mfma_f32_16x16x32_bf16(aq0, bk0, s[t], 0, 0, 0);
            s[t] = __builtin_amdgcn_mfma_f32_16x16x32_bf16(aq1, bk1, s[t], 0, 0, 0);
        }

        #pragma unroll
        for (int t = 0; t < 4; ++t) {
            #pragma unroll
            for (int r = 0; r < 4; ++r) {
                int q = wq0 + fs * 4 + r;
                int k = k0 + t * 16 + fr;
                bool valid;
                if (dir == 0)      valid = (k <= q);
                else if (dir == 1) valid = (k >= q);
                else valid = (k == 0) || (k <= 1024 ? (k - 1) > q : (k - 1025) < q);
                if (!valid) s[t][r] = NEGF;
            }
        }

        float c_[4], rs[4];
        #pragma unroll
        for (int r = 0; r < 4; ++r) {
            float v = fmaxf(fmaxf(s[0][r], s[1][r]), fmaxf(s[2][r], s[3][r]));
            v = fmaxf(v, __shfl_xor(v, 1));
            v = fmaxf(v, __shfl_xor(v, 2));
            v = fmaxf(v, __shfl_xor(v, 4));
            v = fmaxf(v, __shfl_xor(v, 8));
            float mnew = fmaxf(m_r[r], v);
            c_[r] = exp2f((m_r[r] - mnew) * LOG2E);
            m_r[r] = mnew;
            rs[r] = 0.f;
        }
        #pragma unroll
        for (int t = 0; t < 4; ++t) {
            #pragma unroll
            for (int r = 0; r < 4; ++r) {
                float p = exp2f((s[t][r] - m_r[r]) * LOG2E);
                s[t][r] = p;
                rs[r] += p;
            }
        }
        #pragma unroll
        for (int r = 0; r < 4; ++r) {
            float v = rs[r];
            v += __shfl_xor(v, 1);
            v += __shfl_xor(v, 2);
            v += __shfl_xor(v, 4);
            v += __shfl_xor(v, 8);
            l_r[r] = l_r[r] * c_[r] + v;
            o_acc[0][r] *= c_[r]; o_acc[1][r] *= c_[r];
            o_acc[2][r] *= c_[r]; o_acc[3][r] *= c_[r];
        }

        #pragma unroll
        for (int t = 0; t < 4; ++t)
            #pragma unroll
            for (int r = 0; r < 4; ++r)
                Ps[wid][fs * 4 + r][t * 16 + fr] = f2b(s[t][r]);
        __syncthreads();

        bf16x8 pa0 = *(const bf16x8*)&Ps[wid][fr][fs * 8];
        bf16x8 pa1 = *(const bf16x8*)&Ps[wid][fr][fs * 8 + 32];
        #pragma unroll
        for (int t = 0; t < 4; ++t) {
            bf16x8 bv0 = *(const bf16x8*)&Vs[(size_t)(fs * 64 + t * 16 + fr) * 8];
            bf16x8 bv1 = *(const bf16x8*)&Vs[(size_t)((fs + 4) * 64 + t * 16 + fr) * 8];
            o_acc[t] = __builtin_amdgcn_mfma_f32_16x16x32_bf16(pa0, bv0, o_acc[t], 0, 0, 0);
            o_acc[t] = __builtin_amdgcn_mfma_f32_16x16x32_bf16(pa1, bv1, o_acc[t], 0, 0, 0);
        }
    }

    unsigned short* Obase = O + ((size_t)bb * 1024 + q0) * E + h * 64;
    float invl[4];
    #pragma unroll
    for (int r = 0; r < 4; ++r) invl[r] = 1.f / l_r[r];
    #pragma unroll
    for (int t = 0; t < 4; ++t)
        #pragma unroll
        for (int r = 0; r < 4; ++r)
            Obase[(size_t)(wid * 16 + fs * 4 + r) * E + t * 16 + fr] =
                f2b(o_acc[t][r] * invl[r]);
}

// ---------------------------------------------------------------------------

static inline void gemmb(hipStream_t st, int BM, const unsigned short* A,
                         const unsigned short* Wt0, const unsigned short* Wt1,
                         const float* bias0, const float* bias1, int mhalf,
                         const float* res, float* Cf, unsigned short* Cb,
                         unsigned short* CbK, unsigned short* Ct, int ldkv,
                         int M, int N, int K, float alpha, int gelu, int qkv)
{
    dim3 g(N / 128, M / BM);
    if (BM == 128)
        gemm_bf16_k<128><<<g, dim3(256), 0, st>>>(A, Wt0, Wt1, bias0, bias1, mhalf,
            res, Cf, Cb, CbK, Ct, ldkv, M, N, K, alpha, gelu, qkv);
    else
        gemm_bf16_k<64><<<g, dim3(256), 0, st>>>(A, Wt0, Wt1, bias0, bias1, mhalf,
            res, Cf, Cb, CbK, Ct, ldkv, M, N, K, alpha, gelu, qkv);
}

static inline void sgemm4(hipStream_t st, const float* A, const float* W,
                          const float* bias, float* C, float* P,
                          int N, int K, int gelu)
{
    const int nsplit = K / 32;
    skinny_k<<<dim3(N / 256, nsplit), 256, 0, st>>>(A, W, P, N, K);
    skinny_red<<<dim3(N / 256, 4), 256, 0, st>>>(P, bias, C, N, nsplit, gelu);
}

extern "C" void kernel_launch(void* const* d_in, const int* in_sizes, int n_in,
                              void* d_out, int out_size, void* d_ws, size_t ws_size,
                              hipStream_t stream)
{
    const int*   x      = (const int*)  d_in[0];
    const float* t      = (const float*)d_in[1];
    const float* embedW = (const float*)d_in[2];
    const float* attn_W = (const float*)d_in[3];
    const float* attn_b = (const float*)d_in[4];
    const float* ln_s   = (const float*)d_in[5];
    const float* ln_b   = (const float*)d_in[6];
    const float* mlp_W1 = (const float*)d_in[7];
    const float* mlp_b1 = (const float*)d_in[8];
    const float* mlp_W2 = (const float*)d_in[9];
    const float* mlp_b2 = (const float*)d_in[10];
    const float* ca_Wq  = (const float*)d_in[11];
    const float* ca_Wk  = (const float*)d_in[12];
    const float* ca_bk  = (const float*)d_in[13];
    const float* ca_Wv  = (const float*)d_in[14];
    const float* ca_bv  = (const float*)d_in[15];
    const float* ca_Wo  = (const float*)d_in[16];
    const float* ca_bo  = (const float*)d_in[17];
    const float* ro1s   = (const float*)d_in[18];
    const float* ro1b   = (const float*)d_in[19];
    const float* ro2s   = (const float*)d_in[20];
    const float* ro2b   = (const float*)d_in[21];
    const float* in_W   = (const float*)d_in[22];
    const float* in_b   = (const float*)d_in[23];
    const float* tm_W1  = (const float*)d_in[24];
    const float* tm_b1  = (const float*)d_in[25];
    const float* tm_W2  = (const float*)d_in[26];
    const float* tm_b2  = (const float*)d_in[27];
    const float* res_W1 = (const float*)d_in[28];
    const float* res_b1 = (const float*)d_in[29];
    const float* res_W2 = (const float*)d_in[30];
    const float* res_b2 = (const float*)d_in[31];
    const float* rls    = (const float*)d_in[32];
    const float* rlb    = (const float*)d_in[33];
    const float* film_W = (const float*)d_in[34];
    const float* film_b = (const float*)d_in[35];
    const float* out_W  = (const float*)d_in[36];
    const float* out_b  = (const float*)d_in[37];
    float* out = (float*)d_out;
    (void)ws_size; (void)in_sizes; (void)n_in; (void)out_size;

    char* base = (char*)d_ws;
    size_t off = 0;
    auto alloc = [&](size_t bytes) -> char* {
        char* p = base + off;
        off = (off + bytes + 255) & ~(size_t)255;
        return p;
    };
    float* TEMB  = (float*)alloc(8192);
    float* TM1   = (float*)alloc(32768);
    float* T4    = (float*)alloc(32768);
    float* FILM  = (float*)alloc(32768);
    unsigned short* TEMBb = (unsigned short*)alloc(4096);
    float* SKP   = (float*)alloc(2097152);

    float* HB  = (float*)alloc(16777216);        // merged residual stream (8192x512)
    float* L2R = HB;
    float* R2L = HB + 4096 * 512;
    float* Z   = (float*)alloc(8388608);
    float* H2  = (float*)alloc(16777216);
    float* Z2  = (float*)alloc(16777216);

    unsigned short* Zb  = (unsigned short*)alloc(8388608);   // 8192x512
    unsigned short* Qb  = (unsigned short*)alloc(8388608);
    unsigned short* Kb  = (unsigned short*)alloc(8388608);
    unsigned short* Vb  = (unsigned short*)alloc(8388608);   // V^T (8,8,64,1024)
    unsigned short* Ob  = (unsigned short*)alloc(8388608);
    unsigned short* H2b = (unsigned short*)alloc(8388608);

    unsigned short* BIG = (unsigned short*)alloc(33554432);
    unsigned short* MIDb  = BIG;                 // 8192x2048 bf16 (32 MB)
    unsigned short* ALLVb = BIG;                 // 8320x512 (readout)
    unsigned short* K2b   = BIG + 4259840;
    unsigned short* V2T   = BIG + 8519680;       // (4,8,64,2080)

    unsigned short* WT = (unsigned short*)alloc(45613056);
    const size_t wt_attn = 0,        wt_mlp1 = 4194304, wt_mlp2 = 8388608;
    const size_t wt_caq = 12582912,  wt_cak = 12845056, wt_cav = 13107200,
                 wt_cao = 13369344,  wt_in  = 13631488;
    const size_t wt_res1 = 14155776, wt_res2 = 18350080, wt_out = 22544384;

    wconv<<<dim3(8, 8, 16), 256, 0, stream>>>(attn_W, WT + wt_attn, 512, 512, 262144, 262144);
    wconv<<<dim3(32, 8, 4), 256, 0, stream>>>(mlp_W1, WT + wt_mlp1, 512, 2048, 1048576, 1048576);
    wconv<<<dim3(8, 32, 4), 256, 0, stream>>>(mlp_W2, WT + wt_mlp2, 2048, 512, 1048576, 1048576);
    wconv<<<dim3(8, 8), 256, 0, stream>>>(ca_Wq, WT + wt_caq, 512, 512, 0, 0);
    wconv<<<dim3(8, 8), 256, 0, stream>>>(ca_Wk, WT + wt_cak, 512, 512, 0, 0);
    wconv<<<dim3(8, 8), 256, 0, stream>>>(ca_Wv, WT + wt_cav, 512, 512, 0, 0);
    wconv<<<dim3(8, 8), 256, 0, stream>>>(ca_Wo, WT + wt_cao, 512, 512, 0, 0);
    wconv<<<dim3(16, 8), 256, 0, stream>>>(in_W, WT + wt_in, 512, 1024, 0, 0);
    wconv<<<dim3(32, 16, 2), 256, 0, stream>>>(res_W1, WT + wt_res1, 1024, 2048, 2097152, 2097152);
    wconv<<<dim3(16, 32, 2), 256, 0, stream>>>(res_W2, WT + wt_res2, 2048, 1024, 2097152, 2097152);
    wconv<<<dim3(4, 16), 256, 0, stream>>>(out_W, WT + wt_out, 1024, 256, 0, 0);

    temb_kernel<<<dim3(4), dim3(256), 0, stream>>>(t, TEMB, TEMBb);
    embed_kernel<<<dim3(1024, 4, 2), dim3(256), 0, stream>>>(x, TEMB, embedW, L2R, R2L);

    // ---- transformer blocks, both directions merged (M=8192) ----
    for (int l = 0; l < 2; ++l) {
        const size_t d1 = 2 + l;   // dl for d=1
        ln_kernel<<<8192, 256, 0, stream>>>(HB, nullptr,
            ln_s + (l * 2 + 0) * 512, ln_b + (l * 2 + 0) * 512,
            nullptr, Zb, 512, nullptr, 1024, 2048);
        gemmb(stream, 64, Zb,
              WT + wt_attn + (size_t)l * 1048576, WT + wt_attn + d1 * 1048576,
              attn_b + l * 2048, attn_b + d1 * 2048, 4096,
              nullptr, nullptr, Qb, Kb, Vb, 1024, 8192, 1536, 512, 1.f, 0, 1);
        attn_mfma<<<dim3(1024), dim3(256), 0, stream>>>(Qb, Kb, Vb, Ob, -1);
        gemmb(stream, 64, Ob,
              WT + wt_attn + (size_t)(l * 4 + 3) * 262144,
              WT + wt_attn + (d1 * 4 + 3) * 262144,
              attn_b + (l * 4 + 3) * 512, attn_b + (d1 * 4 + 3) * 512, 4096,
              HB, HB, nullptr, nullptr, nullptr, 1, 8192, 512, 512, 1.f, 0, 0);
        ln_kernel<<<8192, 256, 0, stream>>>(HB, nullptr,
            ln_s + (l * 2 + 1) * 512, ln_b + (l * 2 + 1) * 512,
            nullptr, Zb, 512, nullptr, 1024, 2048);
        gemmb(stream, 64, Zb,
              WT + wt_mlp1 + (size_t)l * 1048576, WT + wt_mlp1 + d1 * 1048576,
              mlp_b1 + l * 2048, mlp_b1 + d1 * 2048, 4096,
              nullptr, nullptr, MIDb, nullptr, nullptr, 1, 8192, 2048, 512, 1.f, 1, 0);
        gemmb(stream, 64, MIDb,
              WT + wt_mlp2 + (size_t)l * 1048576, WT + wt_mlp2 + d1 * 1048576,
              mlp_b2 + l * 512, mlp_b2 + d1 * 512, 4096,
              HB, HB, nullptr, nullptr, nullptr, 1, 8192, 512, 2048, 1.f, 0, 0);
    }

    // ---- readout / cross-attention (M=4096) ----
    add_kernel<<<2048, 256, 0, stream>>>(L2R, R2L, Z, 2097152);
    ln_kernel<<<4096, 256, 0, stream>>>(L2R, nullptr, ro1s, ro1b, nullptr, Qb, 512, nullptr, 1024, 0);
    ln_kernel<<<4096, 256, 0, stream>>>(R2L, nullptr, ro2s, ro2b, nullptr, Kb, 512, nullptr, 1024, 0);
    add_bf16<<<1024, 256, 0, stream>>>((const unsigned int*)Qb, (const unsigned int*)Kb,
                                       (unsigned int*)Vb, 1048576);
    build_allv_b<<<dim3(2049, 4), 64, 0, stream>>>(TEMBb, Qb, Kb, ALLVb);
    gemmb(stream, 64, Vb, WT + wt_caq, WT + wt_caq, nullptr, nullptr, 1 << 30,
          nullptr, nullptr, Zb, nullptr, nullptr, 1, 4096, 512, 512, 0.125f, 0, 0);
    gemmb(stream, 64, ALLVb, WT + wt_cak, WT + wt_cak, ca_bk, ca_bk, 1 << 30,
          nullptr, nullptr, K2b, nullptr, nullptr, 1, 8320, 512, 512, 1.f, 0, 0);
    gemmb(stream, 64, ALLVb, WT + wt_cav, WT + wt_cav, ca_bv, ca_bv, 1 << 30,
          nullptr, nullptr, nullptr, nullptr, V2T, 2080, 8320, 512, 512, 1.f, 0, 0);
    attn_mfma<<<dim3(512), dim3(256), 0, stream>>>(Zb, K2b, V2T, Ob, 2);
    gemmb(stream, 64, Ob, WT + wt_cao, WT + wt_cao, ca_bo, ca_bo, 1 << 30,
          Z, nullptr, Qb, nullptr, nullptr, 1, 4096, 512, 512, 1.f, 0, 0);

    sgemm4(stream, TEMB, tm_W1, tm_b1, TM1, SKP, 2048, 512, 1);
    sgemm4(stream, TM1, tm_W2, tm_b2, T4, SKP, 2048, 2048, 0);

    gemmb(stream, 64, Qb, WT + wt_in, WT + wt_in, in_b, in_b, 1 << 30,
          nullptr, H2, H2b, nullptr, nullptr, 1, 4096, 1024, 512, 1.f, 0, 0);
    for (int i = 0; i < 2; ++i) {
        sgemm4(stream, T4, film_W + (size_t)i * 4194304, film_b + i * 2048,
               FILM, SKP, 2048, 2048, 0);
        gemmb(stream, 64, H2b, WT + wt_res1 + (size_t)i * 2097152,
              WT + wt_res1 + (size_t)i * 2097152,
              res_b1 + i * 2048, res_b1 + i * 2048, 1 << 30,
              nullptr, nullptr, MIDb, nullptr, nullptr, 1, 4096, 2048, 1024, 1.f, 1, 0);
        gemmb(stream, 64, MIDb, WT + wt_res2 + (size_t)i * 2097152,
              WT + wt_res2 + (size_t)i * 2097152,
              res_b2 + i * 1024, res_b2 + i * 1024, 1 << 30,
              nullptr, Z2, nullptr, nullptr, nullptr, 1, 4096, 1024, 2048, 1.f, 0, 0);
        ln_kernel<<<4096, 256, 0, stream>>>(H2, Z2, rls + i * 1024, rlb + i * 1024,
                                            H2, H2b, 1024, FILM, 1024, 0);
    }

    gemmb(stream, 64, H2b, WT + wt_out, WT + wt_out, out_b, out_b, 1 << 30,
          nullptr, out, nullptr, nullptr, nullptr, 1, 4096, 256, 1024, 1.f, 0, 0);
}

// Round 9
// 1136.179 us; speedup vs baseline: 13.7678x; 1.0677x over previous
//
#include <hip/hip_runtime.h>
#include <hip/hip_bf16.h>

// ---------------------------------------------------------------------------
// B=4, L=1024, E=512, H=8, NL=2, M=2048, S=256, R=2, Dh=64
// Both transformer directions merged: residual stream HB has 8192 rows,
// row = d*4096 + b*1024 + i ; "bb" = row>>10 = d*4+b (8 merged batches).
// ---------------------------------------------------------------------------

#define NEGF -3.4028235e38f
#define LOG2E 1.4426950408889634f

using bf16x8 = __attribute__((ext_vector_type(8))) short;
using f32x4  = __attribute__((ext_vector_type(4))) float;

__device__ inline float bf2f(unsigned short u) {
    return __uint_as_float(((unsigned int)u) << 16);
}
__device__ inline unsigned short f2b(float f) {
    unsigned int u = __float_as_uint(f);
    return (unsigned short)((u + 0x7fff + ((u >> 16) & 1)) >> 16);
}

__device__ inline void gl_lds16(const void* g, void* l) {
    __builtin_amdgcn_global_load_lds(
        (const __attribute__((address_space(1))) void*)(uintptr_t)g,
        (__attribute__((address_space(3))) void*)(unsigned int)(uintptr_t)l,
        16, 0, 0);
}

// ---------------------------------------------------------------------------
// bf16 MFMA GEMM, BM in {64,128}, BN=128, BK=32, 4 waves, double-buffered
// with COUNTED vmcnt (prefetch stays in flight across the barrier; only the
// last iteration drains). Raw s_barrier, no compiler vmcnt(0) drain.
// Two weight/bias pointers: rows >= mhalf use Wt1/bias1 (merged directions).
// qkv==1 (N=1536): cols 0-511 -> Cb (Q, x0.125), 512-1023 -> CbK (K),
// 1024-1535 -> Ct (V per-head transposed (BB,8,64,1024)).
// qkv==0: Cf f32, Cb bf16, Ct per-head transposed with row-stride ldkv.
// ---------------------------------------------------------------------------
template<int BM>
__global__ __launch_bounds__(256) void gemm_bf16_k(
    const unsigned short* __restrict__ A,
    const unsigned short* __restrict__ Wt0, const unsigned short* __restrict__ Wt1,
    const float* __restrict__ bias0, const float* __restrict__ bias1, int mhalf,
    const float* __restrict__ res,
    float* __restrict__ Cf, unsigned short* __restrict__ Cb,
    unsigned short* __restrict__ CbK, unsigned short* __restrict__ Ct, int ldkv,
    int M, int N, int K, float alpha, int gelu_flag, int qkv)
{
    constexpr int MF  = BM / 32;
    constexpr int NAC = BM * 4 / 256;
    __shared__ unsigned short As[2][BM * 32];
    __shared__ unsigned short Bs[2][4096];
    const int tid  = threadIdx.x;
    const int wid  = tid >> 6;
    const int lane = tid & 63;
    const int wy   = wid >> 1, wx = wid & 1;
    const int koff = lane >> 4, l16 = lane & 15;
    const int m0 = blockIdx.y * BM, n0 = blockIdx.x * 128;

    const unsigned short* Wt = (m0 < mhalf) ? Wt0 : Wt1;
    const float* bias = (m0 < mhalf) ? bias0 : bias1;

    const unsigned short* aG[NAC];
    const unsigned short* bG[2];
    #pragma unroll
    for (int i = 0; i < NAC; ++i) {
        int c = tid + i * 256;
        int r = ((c >> 6) << 4) | (c & 15), kk = ((c >> 4) & 3) << 3;
        aG[i] = A + (size_t)(m0 + r) * K + kk;
    }
    #pragma unroll
    for (int i = 0; i < 2; ++i) {
        int c = tid + i * 256;
        int r = ((c >> 6) << 4) | (c & 15), kk = ((c >> 4) & 3) << 3;
        bG[i] = Wt + (size_t)(n0 + r) * K + kk;
    }

    f32x4 acc[MF][4] = {};
    const int nk = K >> 5;

    auto stage = [&](int buf, int k0) {
        #pragma unroll
        for (int i = 0; i < NAC; ++i)
            gl_lds16(aG[i] + k0, &As[buf][(size_t)(i * 256 + wid * 64) * 8]);
        #pragma unroll
        for (int i = 0; i < 2; ++i)
            gl_lds16(bG[i] + k0, &Bs[buf][(size_t)(i * 256 + wid * 64) * 8]);
    };

    stage(0, 0);
    int cur = 0;
    for (int it = 0; it < nk; ++it) {
        if (it + 1 < nk) {
            stage(cur ^ 1, (it + 1) << 5);
            // wait current tile landed; keep the PF prefetch loads in flight
            if constexpr (BM == 128)
                asm volatile("s_waitcnt vmcnt(4)" ::: "memory");
            else
                asm volatile("s_waitcnt vmcnt(3)" ::: "memory");
        } else {
            asm volatile("s_waitcnt vmcnt(0)" ::: "memory");
        }
        __builtin_amdgcn_s_barrier();

        bf16x8 af[MF], bfr[4];
        const int foff = (koff * 16 + l16) * 8;
        #pragma unroll
        for (int i = 0; i < MF; ++i)
            af[i] = *(const bf16x8*)&As[cur][(size_t)((wy * MF + i) * 64) * 8 + foff];
        #pragma unroll
        for (int j = 0; j < 4; ++j)
            bfr[j] = *(const bf16x8*)&Bs[cur][(size_t)((wx * 4 + j) * 64) * 8 + foff];
        #pragma unroll
        for (int i = 0; i < MF; ++i)
            #pragma unroll
            for (int j = 0; j < 4; ++j)
                acc[i][j] = __builtin_amdgcn_mfma_f32_16x16x32_bf16(
                    af[i], bfr[j], acc[i][j], 0, 0, 0);

        asm volatile("" ::: "memory");
        __builtin_amdgcn_s_barrier();   // reads of buf[cur] done before overwrite
        cur ^= 1;
    }

    #pragma unroll
    for (int i = 0; i < MF; ++i) {
        const int rbase = m0 + wy * (MF * 16) + i * 16 + koff * 4;
        #pragma unroll
        for (int j = 0; j < 4; ++j) {
            const int gn = n0 + wx * 64 + j * 16 + l16;
            const float bs = bias ? bias[gn] : 0.f;
            if (qkv) {
                const int seg = gn >> 9, gnl = gn & 511;
                const float av = (seg == 0) ? 0.125f : 1.0f;
                unsigned short o[4];
                #pragma unroll
                for (int r = 0; r < 4; ++r) o[r] = f2b((acc[i][j][r] + bs) * av);
                if (seg == 0) {
                    #pragma unroll
                    for (int r = 0; r < 4; ++r)
                        Cb[(size_t)(rbase + r) * 512 + gnl] = o[r];
                } else if (seg == 1) {
                    #pragma unroll
                    for (int r = 0; r < 4; ++r)
                        CbK[(size_t)(rbase + r) * 512 + gnl] = o[r];
                } else {
                    const int hh = gnl >> 6, dh = gnl & 63;
                    const int bb = rbase >> 10, l0 = rbase & 1023;
                    *(ushort4*)(Ct + ((size_t)(bb * 8 + hh) * 64 + dh) * 1024 + l0) =
                        make_ushort4(o[0], o[1], o[2], o[3]);
                }
            } else {
                float vr[4];
                #pragma unroll
                for (int r = 0; r < 4; ++r) {
                    float v = (acc[i][j][r] + bs) * alpha;
                    if (gelu_flag) v = 0.5f * v * (1.0f + erff(v * 0.70710678118654752f));
                    const size_t idx = (size_t)(rbase + r) * N + gn;
                    if (res) v += res[idx];
                    if (Cf) Cf[idx] = v;
                    if (Cb) Cb[idx] = f2b(v);
                    vr[r] = v;
                }
                if (Ct) {
                    const int hh = gn >> 6, dh = gn & 63;
                    const int bb = rbase / ldkv;
                    const int l0 = rbase - bb * ldkv;
                    *(ushort4*)(Ct + ((size_t)(bb * 8 + hh) * 64 + dh) * ldkv + l0) =
                        make_ushort4(f2b(vr[0]), f2b(vr[1]), f2b(vr[2]), f2b(vr[3]));
                }
            }
        }
    }
}

// ---------------------------------------------------------------------------
// weight transpose-convert: src fp32 [K][N] -> dst bf16 [N][K]
// ---------------------------------------------------------------------------
__global__ __launch_bounds__(256) void wconv(
    const float* __restrict__ src, unsigned short* __restrict__ dst,
    int K, int N, long sstride, long dstride)
{
    __shared__ float t[64][65];
    const int n0 = blockIdx.x * 64, k0 = blockIdx.y * 64;
    const float* s = src + (size_t)blockIdx.z * sstride;
    unsigned short* d = dst + (size_t)blockIdx.z * dstride;
    const int tid = threadIdx.x;
    #pragma unroll
    for (int i = 0; i < 4; ++i) {
        int lin = i * 1024 + tid * 4;
        int r = lin >> 6, c = lin & 63;
        float4 v = *(const float4*)(s + (size_t)(k0 + r) * N + n0 + c);
        t[r][c] = v.x; t[r][c + 1] = v.y; t[r][c + 2] = v.z; t[r][c + 3] = v.w;
    }
    __syncthreads();
    #pragma unroll
    for (int i = 0; i < 8; ++i) {
        int lin = i * 512 + tid * 2;
        int rn = lin >> 6, ck = lin & 63;
        ushort2 o;
        o.x = f2b(t[ck][rn]); o.y = f2b(t[ck + 1][rn]);
        *(ushort2*)(d + (size_t)(n0 + rn) * K + k0 + ck) = o;
    }
}

// ---------------------------------------------------------------------------
// Skinny GEMM for M=4, split-K, deterministic
// ---------------------------------------------------------------------------
__global__ __launch_bounds__(256) void skinny_k(
    const float* __restrict__ A, const float* __restrict__ W,
    float* __restrict__ P, int N, int K)
{
    const int n = blockIdx.x * 256 + threadIdx.x;
    const int s = blockIdx.y;
    const int k0 = s * 32;
    float a0 = 0.f, a1 = 0.f, a2 = 0.f, a3 = 0.f;
    #pragma unroll 8
    for (int k = k0; k < k0 + 32; ++k) {
        float w = W[(size_t)k * N + n];
        a0 = fmaf(A[k], w, a0);
        a1 = fmaf(A[K + k], w, a1);
        a2 = fmaf(A[2 * K + k], w, a2);
        a3 = fmaf(A[3 * K + k], w, a3);
    }
    float* p = P + (size_t)s * 4 * N;
    p[n] = a0; p[N + n] = a1; p[2 * N + n] = a2; p[3 * N + n] = a3;
}

__global__ __launch_bounds__(256) void skinny_red(
    const float* __restrict__ P, const float* __restrict__ bias,
    float* __restrict__ C, int N, int nsplit, int gelu_flag)
{
    const int n = blockIdx.x * 256 + threadIdx.x;
    const int r = blockIdx.y;
    float acc = 0.f;
    for (int s = 0; s < nsplit; ++s) acc += P[((size_t)s * 4 + r) * N + n];
    float v = acc + (bias ? bias[n] : 0.f);
    if (gelu_flag) v = 0.5f * v * (1.0f + erff(v * 0.70710678118654752f));
    C[(size_t)r * N + n] = v;
}

// ---------------------------------------------------------------------------
// LayerNorm; per-4096-row param offset pstride (merged directions), optional
// add + FiLM; fp32 in, fp32 and/or bf16 out.
// ---------------------------------------------------------------------------
__global__ __launch_bounds__(256) void ln_kernel(
    const float* __restrict__ X, const float* __restrict__ X2,
    const float* __restrict__ s, const float* __restrict__ b,
    float* __restrict__ Yf, unsigned short* __restrict__ Yb,
    int D, const float* __restrict__ film, int rows_per_batch, long pstride)
{
    const int row = blockIdx.x;
    const int tid = threadIdx.x;
    const float* x = X + (size_t)row * D;
    const float* x2 = X2 ? X2 + (size_t)row * D : nullptr;
    const float* se = s + (size_t)(row >> 12) * pstride;
    const float* be = b + (size_t)(row >> 12) * pstride;

    float sum = 0.f, sq = 0.f;
    for (int c = tid; c < D; c += 256) {
        float v = x[c] + (x2 ? x2[c] : 0.f);
        sum += v; sq += v * v;
    }
    __shared__ float r1[4], r2[4];
    __shared__ float s_mean, s_rstd;
    for (int off = 32; off > 0; off >>= 1) {
        sum += __shfl_down(sum, off);
        sq  += __shfl_down(sq,  off);
    }
    if ((tid & 63) == 0) { r1[tid >> 6] = sum; r2[tid >> 6] = sq; }
    __syncthreads();
    if (tid == 0) {
        float ts = r1[0] + r1[1] + r1[2] + r1[3];
        float tq = r2[0] + r2[1] + r2[2] + r2[3];
        float mean = ts / (float)D;
        float var = tq / (float)D - mean * mean;
        s_mean = mean;
        s_rstd = rsqrtf(var + 1e-5f);
    }
    __syncthreads();
    const float mean = s_mean, rstd = s_rstd;
    const float* fa = nullptr; const float* fb = nullptr;
    if (film) {
        int batch = row / rows_per_batch;
        fa = film + (size_t)batch * 2 * D;
        fb = fa + D;
    }
    for (int c = tid; c < D; c += 256) {
        float v = x[c] + (x2 ? x2[c] : 0.f);
        float y = (v - mean) * rstd * se[c] + be[c];
        if (film) y = fa[c] * y + fb[c];
        if (Yf) Yf[(size_t)row * D + c] = y;
        if (Yb) Yb[(size_t)row * D + c] = f2b(y);
    }
}

__global__ void temb_kernel(const float* __restrict__ t, float* __restrict__ temb,
                            unsigned short* __restrict__ tembb)
{
    int b = blockIdx.x;
    int i = threadIdx.x;
    float f = expf((float)i * (-9.210340371976184f / 255.0f));
    float a = t[b] * f;
    float sv = sinf(a), cv = cosf(a);
    temb[b * 512 + i]        = sv;
    temb[b * 512 + 256 + i]  = cv;
    tembb[b * 512 + i]       = f2b(sv);
    tembb[b * 512 + 256 + i] = f2b(cv);
}

__global__ void embed_kernel(const int* __restrict__ x, const float* __restrict__ temb,
                             const float* __restrict__ embed,
                             float* __restrict__ l2r, float* __restrict__ r2l)
{
    const int i = blockIdx.x;
    const int b = blockIdx.y;
    const int d = blockIdx.z;
    float* out = (d == 0 ? l2r : r2l) + ((size_t)(b * 1024 + i) * 512);
    const float* src;
    if (d == 0) src = (i == 0)    ? temb + b * 512 : embed + (size_t)x[b * 1024 + (i - 1)] * 512;
    else        src = (i == 1023) ? temb + b * 512 : embed + (size_t)x[b * 1024 + (i + 1)] * 512;
    for (int e = threadIdx.x; e < 512; e += 256) {
        int j = e >> 1;
        float div = expf((float)(2 * j) * (-9.210340371976184f / 512.0f));
        float ang = (float)i * div;
        float pe = (e & 1) ? cosf(ang) : sinf(ang);
        out[e] = src[e] + pe;
    }
}

__global__ void add_kernel(const float* __restrict__ A, const float* __restrict__ B,
                           float* __restrict__ C, int n)
{
    int i = blockIdx.x * blockDim.x + threadIdx.x;
    int stride = gridDim.x * blockDim.x;
    for (; i < n; i += stride) C[i] = A[i] + B[i];
}

__global__ void add_bf16(const unsigned int* __restrict__ A,
                         const unsigned int* __restrict__ B,
                         unsigned int* __restrict__ C, int nwords)
{
    int i = blockIdx.x * blockDim.x + threadIdx.x;
    int stride = gridDim.x * blockDim.x;
    for (; i < nwords; i += stride) {
        unsigned int a = A[i], b = B[i];
        float lo = __uint_as_float(a << 16) + __uint_as_float(b << 16);
        float hi = __uint_as_float(a & 0xffff0000u) + __uint_as_float(b & 0xffff0000u);
        C[i] = (unsigned int)f2b(lo) | ((unsigned int)f2b(hi) << 16);
    }
}

__global__ void build_allv_b(const unsigned short* __restrict__ tembb,
                             const unsigned short* __restrict__ l2rn,
                             const unsigned short* __restrict__ r2ln,
                             unsigned short* __restrict__ allv)
{
    const int k = blockIdx.x;
    const int b = blockIdx.y;
    unsigned short* out = allv + ((size_t)b * 2080 + k) * 512;
    const unsigned short* src;
    if (k == 0)         src = tembb + b * 512;
    else if (k <= 1024) src = l2rn + ((size_t)(b * 1024 + (k - 1)) * 512);
    else                src = r2ln + ((size_t)(b * 1024 + (k - 1025)) * 512);
    ((uint4*)out)[threadIdx.x] = ((const uint4*)src)[threadIdx.x];
}

// ---------------------------------------------------------------------------
// MFMA flash attention, bf16 in/out, fp32 accumulate.
// mode -1 (merged self): grid 1024; bb = 0..7; causal dir = bb>>2.
// mode  2 (cross):       grid 512;  bb = 0..3; 2049 keys, stride 2080.
// XCD-chunked swizzle. setprio around MFMA clusters; mask only on tiles that
// need it (diagonal for causal; segment edges for cross).
// ---------------------------------------------------------------------------
__global__ __launch_bounds__(256) void attn_mfma(
    const unsigned short* __restrict__ Q, const unsigned short* __restrict__ K,
    const unsigned short* __restrict__ Vt, unsigned short* __restrict__ O, int mode)
{
    const int E = 512;
    const int LKP = (mode == 2) ? 2080 : 1024;
    const int idf = blockIdx.x;
    const int chunk = gridDim.x >> 3;
    const int w = (idf & 7) * chunk + (idf >> 3);
    const int qt = w & 15, h = (w >> 4) & 7, bb = w >> 7;
    const int dir = (mode == 2) ? 2 : (bb >> 2);
    const int q0 = qt * 64;
    const int tid = threadIdx.x;
    const int wid = tid >> 6, lane = tid & 63;
    const int fr = lane & 15;
    const int fs = lane >> 4;
    const int wq0 = q0 + wid * 16;

    __shared__ unsigned short Qs[4096];
    __shared__ unsigned short Ks[4096];
    __shared__ unsigned short Vs[4096];
    __shared__ unsigned short Ps[4][16][72];

    {
        const unsigned short* Qbase = Q + ((size_t)bb * 1024 + q0) * E + h * 64;
        #pragma unroll
        for (int it = 0; it < 2; ++it) {
            int i = tid + it * 256;
            int r = i & 63, c = i >> 6;
            *(uint4*)&Qs[(size_t)(c * 64 + r) * 8] =
                *(const uint4*)(Qbase + (size_t)r * E + c * 8);
        }
    }
    __syncthreads();
    const bf16x8 aq0 = *(const bf16x8*)&Qs[(size_t)(fs * 64 + wid * 16 + fr) * 8];
    const bf16x8 aq1 = *(const bf16x8*)&Qs[(size_t)((fs + 4) * 64 + wid * 16 + fr) * 8];

    float m_r[4], l_r[4];
    f32x4 o_acc[4] = {};
    #pragma unroll
    for (int r = 0; r < 4; ++r) { m_r[r] = NEGF; l_r[r] = 0.f; }

    int kt0, kt1;
    if (dir == 0)      { kt0 = 0;  kt1 = qt; }
    else if (dir == 1) { kt0 = qt; kt1 = 15; }
    else               { kt0 = 0;  kt1 = 31; }

    const unsigned short* Kb0 = K + ((size_t)bb * LKP) * E + h * 64;
    const unsigned short* Vb0 = Vt + (size_t)(bb * 8 + h) * 64 * LKP;

    for (int kt = kt0; kt <= kt1; ++kt) {
        if (dir == 2) {
            if (kt >= 1 && kt <= 15 && 64 * kt + 62 <= q0) continue;
            if (kt >= 17 && 64 * kt - 1025 >= q0 + 63) continue;
        }
        const int k0 = kt * 64;

        __syncthreads();

        {
            const unsigned short* Kbase = Kb0 + (size_t)k0 * E;
            const unsigned short* Vbase = Vb0 + k0;
            #pragma unroll
            for (int it = 0; it < 2; ++it) {
                int i = tid + it * 256;
                int r = i & 63, c = i >> 6;
                *(uint4*)&Ks[(size_t)(c * 64 + r) * 8] =
                    *(const uint4*)(Kbase + (size_t)r * E + c * 8);
                *(uint4*)&Vs[(size_t)(c * 64 + r) * 8] =
                    *(const uint4*)(Vbase + (size_t)r * LKP + c * 8);
            }
        }
        __syncthreads();

        f32x4 s[4] = {};
        __builtin_amdgcn_s_setprio(1);
        #pragma unroll
        for (int t = 0; t < 4; ++t) {
            bf16x8 bk0 = *(const bf16x8*)&Ks[(size_t)(fs * 64 + t * 16 + fr) * 8];
            bf16x8 bk1 = *(const bf16x8*)&Ks[(size_t)((fs + 4) * 64 + t * 16 + fr) * 8];
            s[t] = __builtin_amdgcn_mfma_f32_16x16x32_bf16(aq0, bk0, s[t], 0, 0, 0);
            s[t] = __builtin_amdgcn_mfma_f32_16x16x32_bf16(aq1, bk1, s[t], 0, 0, 0);
        }
        __builtin_amdgcn_s_setprio(0);

        // mask only where needed
        bool need_mask;
        if (dir != 2) need_mask = (kt == qt);
        else if (kt >= 1 && kt <= 15) need_mask = !((64 * kt - 1) > (q0 + 63));
        else if (kt >= 17)            need_mask = !((64 * kt + 63 - 1025) < q0);
        else                          need_mask = true;   // kt==0 or kt==16 mixed
        if (need_mask) {
            #pragma unroll
            for (int t = 0; t < 4; ++t) {
                #pragma unroll
                for (int r = 0; r < 4; ++r) {
                    int q = wq0 + fs * 4 + r;
                    int k = k0 + t * 16 + fr;
                    bool valid;
                    if (dir == 0)      valid = (k <= q);
                    else if (dir == 1) valid = (k >= q);
                    else valid = (k == 0) || (k <= 1024 ? (k - 1) > q : (k - 1025) < q);
                    if (!valid) s[t][r] = NEGF;
                }
            }
        }

        float c_[4], rs[4];
        #pragma unroll
        for (int r = 0; r < 4; ++r) {
            float v = fmaxf(fmaxf(s[0][r], s[1][r]), fmaxf(s[2][r], s[3][r]));
            v = fmaxf(v, __shfl_xor(v, 1));
            v = fmaxf(v, __shfl_xor(v, 2));
            v = fmaxf(v, __shfl_xor(v, 4));
            v = fmaxf(v, __shfl_xor(v, 8));
            float mnew = fmaxf(m_r[r], v);
            c_[r] = exp2f((m_r[r] - mnew) * LOG2E);
            m_r[r] = mnew;
            rs[r] = 0.f;
        }
        #pragma unroll
        for (int t = 0; t < 4; ++t) {
            #pragma unroll
            for (int r = 0; r < 4; ++r) {
                float p = exp2f((s[t][r] - m_r[r]) * LOG2E);
                s[t][r] = p;
                rs[r] += p;
            }
        }
        #pragma unroll
        for (int r = 0; r < 4; ++r) {
            float v = rs[r];
            v += __shfl_xor(v, 1);
            v += __shfl_xor(v, 2);
            v += __shfl_xor(v, 4);
            v += __shfl_xor(v, 8);
            l_r[r] = l_r[r] * c_[r] + v;
            o_acc[0][r] *= c_[r]; o_acc[1][r] *= c_[r];
            o_acc[2][r] *= c_[r]; o_acc[3][r] *= c_[r];
        }

        #pragma unroll
        for (int t = 0; t < 4; ++t)
            #pragma unroll
            for (int r = 0; r < 4; ++r)
                Ps[wid][fs * 4 + r][t * 16 + fr] = f2b(s[t][r]);
        __syncthreads();

        bf16x8 pa0 = *(const bf16x8*)&Ps[wid][fr][fs * 8];
        bf16x8 pa1 = *(const bf16x8*)&Ps[wid][fr][fs * 8 + 32];
        __builtin_amdgcn_s_setprio(1);
        #pragma unroll
        for (int t = 0; t < 4; ++t) {
            bf16x8 bv0 = *(const bf16x8*)&Vs[(size_t)(fs * 64 + t * 16 + fr) * 8];
            bf16x8 bv1 = *(const bf16x8*)&Vs[(size_t)((fs + 4) * 64 + t * 16 + fr) * 8];
            o_acc[t] = __builtin_amdgcn_mfma_f32_16x16x32_bf16(pa0, bv0, o_acc[t], 0, 0, 0);
            o_acc[t] = __builtin_amdgcn_mfma_f32_16x16x32_bf16(pa1, bv1, o_acc[t], 0, 0, 0);
        }
        __builtin_amdgcn_s_setprio(0);
    }

    unsigned short* Obase = O + ((size_t)bb * 1024 + q0) * E + h * 64;
    float invl[4];
    #pragma unroll
    for (int r = 0; r < 4; ++r) invl[r] = 1.f / l_r[r];
    #pragma unroll
    for (int t = 0; t < 4; ++t)
        #pragma unroll
        for (int r = 0; r < 4; ++r)
            Obase[(size_t)(wid * 16 + fs * 4 + r) * E + t * 16 + fr] =
                f2b(o_acc[t][r] * invl[r]);
}

// ---------------------------------------------------------------------------

static inline void gemmb(hipStream_t st, int BM, const unsigned short* A,
                         const unsigned short* Wt0, const unsigned short* Wt1,
                         const float* bias0, const float* bias1, int mhalf,
                         const float* res, float* Cf, unsigned short* Cb,
                         unsigned short* CbK, unsigned short* Ct, int ldkv,
                         int M, int N, int K, float alpha, int gelu, int qkv)
{
    dim3 g(N / 128, M / BM);
    if (BM == 128)
        gemm_bf16_k<128><<<g, dim3(256), 0, st>>>(A, Wt0, Wt1, bias0, bias1, mhalf,
            res, Cf, Cb, CbK, Ct, ldkv, M, N, K, alpha, gelu, qkv);
    else
        gemm_bf16_k<64><<<g, dim3(256), 0, st>>>(A, Wt0, Wt1, bias0, bias1, mhalf,
            res, Cf, Cb, CbK, Ct, ldkv, M, N, K, alpha, gelu, qkv);
}

static inline void sgemm4(hipStream_t st, const float* A, const float* W,
                          const float* bias, float* C, float* P,
                          int N, int K, int gelu)
{
    const int nsplit = K / 32;
    skinny_k<<<dim3(N / 256, nsplit), 256, 0, st>>>(A, W, P, N, K);
    skinny_red<<<dim3(N / 256, 4), 256, 0, st>>>(P, bias, C, N, nsplit, gelu);
}

extern "C" void kernel_launch(void* const* d_in, const int* in_sizes, int n_in,
                              void* d_out, int out_size, void* d_ws, size_t ws_size,
                              hipStream_t stream)
{
    const int*   x      = (const int*)  d_in[0];
    const float* t      = (const float*)d_in[1];
    const float* embedW = (const float*)d_in[2];
    const float* attn_W = (const float*)d_in[3];
    const float* attn_b = (const float*)d_in[4];
    const float* ln_s   = (const float*)d_in[5];
    const float* ln_b   = (const float*)d_in[6];
    const float* mlp_W1 = (const float*)d_in[7];
    const float* mlp_b1 = (const float*)d_in[8];
    const float* mlp_W2 = (const float*)d_in[9];
    const float* mlp_b2 = (const float*)d_in[10];
    const float* ca_Wq  = (const float*)d_in[11];
    const float* ca_Wk  = (const float*)d_in[12];
    const float* ca_bk  = (const float*)d_in[13];
    const float* ca_Wv  = (const float*)d_in[14];
    const float* ca_bv  = (const float*)d_in[15];
    const float* ca_Wo  = (const float*)d_in[16];
    const float* ca_bo  = (const float*)d_in[17];
    const float* ro1s   = (const float*)d_in[18];
    const float* ro1b   = (const float*)d_in[19];
    const float* ro2s   = (const float*)d_in[20];
    const float* ro2b   = (const float*)d_in[21];
    const float* in_W   = (const float*)d_in[22];
    const float* in_b   = (const float*)d_in[23];
    const float* tm_W1  = (const float*)d_in[24];
    const float* tm_b1  = (const float*)d_in[25];
    const float* tm_W2  = (const float*)d_in[26];
    const float* tm_b2  = (const float*)d_in[27];
    const float* res_W1 = (const float*)d_in[28];
    const float* res_b1 = (const float*)d_in[29];
    const float* res_W2 = (const float*)d_in[30];
    const float* res_b2 = (const float*)d_in[31];
    const float* rls    = (const float*)d_in[32];
    const float* rlb    = (const float*)d_in[33];
    const float* film_W = (const float*)d_in[34];
    const float* film_b = (const float*)d_in[35];
    const float* out_W  = (const float*)d_in[36];
    const float* out_b  = (const float*)d_in[37];
    float* out = (float*)d_out;
    (void)ws_size; (void)in_sizes; (void)n_in; (void)out_size;

    char* base = (char*)d_ws;
    size_t off = 0;
    auto alloc = [&](size_t bytes) -> char* {
        char* p = base + off;
        off = (off + bytes + 255) & ~(size_t)255;
        return p;
    };
    float* TEMB  = (float*)alloc(8192);
    float* TM1   = (float*)alloc(32768);
    float* T4    = (float*)alloc(32768);
    float* FILM  = (float*)alloc(32768);
    unsigned short* TEMBb = (unsigned short*)alloc(4096);
    float* SKP   = (float*)alloc(2097152);

    float* HB  = (float*)alloc(16777216);        // merged residual stream (8192x512)
    float* L2R = HB;
    float* R2L = HB + 4096 * 512;
    float* Z   = (float*)alloc(8388608);
    float* H2  = (float*)alloc(16777216);
    float* Z2  = (float*)alloc(16777216);

    unsigned short* Zb  = (unsigned short*)alloc(8388608);   // 8192x512
    unsigned short* Qb  = (unsigned short*)alloc(8388608);
    unsigned short* Kb  = (unsigned short*)alloc(8388608);
    unsigned short* Vb  = (unsigned short*)alloc(8388608);   // V^T (8,8,64,1024)
    unsigned short* Ob  = (unsigned short*)alloc(8388608);
    unsigned short* H2b = (unsigned short*)alloc(8388608);

    unsigned short* BIG = (unsigned short*)alloc(33554432);
    unsigned short* MIDb  = BIG;                 // 8192x2048 bf16 (32 MB)
    unsigned short* ALLVb = BIG;                 // 8320x512 (readout)
    unsigned short* K2b   = BIG + 4259840;
    unsigned short* V2T   = BIG + 8519680;       // (4,8,64,2080)

    unsigned short* WT = (unsigned short*)alloc(45613056);
    const size_t wt_attn = 0,        wt_mlp1 = 4194304, wt_mlp2 = 8388608;
    const size_t wt_caq = 12582912,  wt_cak = 12845056, wt_cav = 13107200,
                 wt_cao = 13369344,  wt_in  = 13631488;
    const size_t wt_res1 = 14155776, wt_res2 = 18350080, wt_out = 22544384;

    wconv<<<dim3(8, 8, 16), 256, 0, stream>>>(attn_W, WT + wt_attn, 512, 512, 262144, 262144);
    wconv<<<dim3(32, 8, 4), 256, 0, stream>>>(mlp_W1, WT + wt_mlp1, 512, 2048, 1048576, 1048576);
    wconv<<<dim3(8, 32, 4), 256, 0, stream>>>(mlp_W2, WT + wt_mlp2, 2048, 512, 1048576, 1048576);
    wconv<<<dim3(8, 8), 256, 0, stream>>>(ca_Wq, WT + wt_caq, 512, 512, 0, 0);
    wconv<<<dim3(8, 8), 256, 0, stream>>>(ca_Wk, WT + wt_cak, 512, 512, 0, 0);
    wconv<<<dim3(8, 8), 256, 0, stream>>>(ca_Wv, WT + wt_cav, 512, 512, 0, 0);
    wconv<<<dim3(8, 8), 256, 0, stream>>>(ca_Wo, WT + wt_cao, 512, 512, 0, 0);
    wconv<<<dim3(16, 8), 256, 0, stream>>>(in_W, WT + wt_in, 512, 1024, 0, 0);
    wconv<<<dim3(32, 16, 2), 256, 0, stream>>>(res_W1, WT + wt_res1, 1024, 2048, 2097152, 2097152);
    wconv<<<dim3(16, 32, 2), 256, 0, stream>>>(res_W2, WT + wt_res2, 2048, 1024, 2097152, 2097152);
    wconv<<<dim3(4, 16), 256, 0, stream>>>(out_W, WT + wt_out, 1024, 256, 0, 0);

    temb_kernel<<<dim3(4), dim3(256), 0, stream>>>(t, TEMB, TEMBb);
    embed_kernel<<<dim3(1024, 4, 2), dim3(256), 0, stream>>>(x, TEMB, embedW, L2R, R2L);

    // ---- transformer blocks, both directions merged (M=8192) ----
    for (int l = 0; l < 2; ++l) {
        const size_t d1 = 2 + l;   // dl for d=1
        ln_kernel<<<8192, 256, 0, stream>>>(HB, nullptr,
            ln_s + (l * 2 + 0) * 512, ln_b + (l * 2 + 0) * 512,
            nullptr, Zb, 512, nullptr, 1024, 2048);
        gemmb(stream, 64, Zb,
              WT + wt_attn + (size_t)l * 1048576, WT + wt_attn + d1 * 1048576,
              attn_b + l * 2048, attn_b + d1 * 2048, 4096,
              nullptr, nullptr, Qb, Kb, Vb, 1024, 8192, 1536, 512, 1.f, 0, 1);
        attn_mfma<<<dim3(1024), dim3(256), 0, stream>>>(Qb, Kb, Vb, Ob, -1);
        gemmb(stream, 64, Ob,
              WT + wt_attn + (size_t)(l * 4 + 3) * 262144,
              WT + wt_attn + (d1 * 4 + 3) * 262144,
              attn_b + (l * 4 + 3) * 512, attn_b + (d1 * 4 + 3) * 512, 4096,
              HB, HB, nullptr, nullptr, nullptr, 1, 8192, 512, 512, 1.f, 0, 0);
        ln_kernel<<<8192, 256, 0, stream>>>(HB, nullptr,
            ln_s + (l * 2 + 1) * 512, ln_b + (l * 2 + 1) * 512,
            nullptr, Zb, 512, nullptr, 1024, 2048);
        gemmb(stream, 64, Zb,
              WT + wt_mlp1 + (size_t)l * 1048576, WT + wt_mlp1 + d1 * 1048576,
              mlp_b1 + l * 2048, mlp_b1 + d1 * 2048, 4096,
              nullptr, nullptr, MIDb, nullptr, nullptr, 1, 8192, 2048, 512, 1.f, 1, 0);
        gemmb(stream, 64, MIDb,
              WT + wt_mlp2 + (size_t)l * 1048576, WT + wt_mlp2 + d1 * 1048576,
              mlp_b2 + l * 512, mlp_b2 + d1 * 512, 4096,
              HB, HB, nullptr, nullptr, nullptr, 1, 8192, 512, 2048, 1.f, 0, 0);
    }

    // ---- readout / cross-attention (M=4096) ----
    add_kernel<<<2048, 256, 0, stream>>>(L2R, R2L, Z, 2097152);
    ln_kernel<<<4096, 256, 0, stream>>>(L2R, nullptr, ro1s, ro1b, nullptr, Qb, 512, nullptr, 1024, 0);
    ln_kernel<<<4096, 256, 0, stream>>>(R2L, nullptr, ro2s, ro2b, nullptr, Kb, 512, nullptr, 1024, 0);
    add_bf16<<<1024, 256, 0, stream>>>((const unsigned int*)Qb, (const unsigned int*)Kb,
                                       (unsigned int*)Vb, 1048576);
    build_allv_b<<<dim3(2049, 4), 64, 0, stream>>>(TEMBb, Qb, Kb, ALLVb);
    gemmb(stream, 64, Vb, WT + wt_caq, WT + wt_caq, nullptr, nullptr, 1 << 30,
          nullptr, nullptr, Zb, nullptr, nullptr, 1, 4096, 512, 512, 0.125f, 0, 0);
    gemmb(stream, 64, ALLVb, WT + wt_cak, WT + wt_cak, ca_bk, ca_bk, 1 << 30,
          nullptr, nullptr, K2b, nullptr, nullptr, 1, 8320, 512, 512, 1.f, 0, 0);
    gemmb(stream, 64, ALLVb, WT + wt_cav, WT + wt_cav, ca_bv, ca_bv, 1 << 30,
          nullptr, nullptr, nullptr, nullptr, V2T, 2080, 8320, 512, 512, 1.f, 0, 0);
    attn_mfma<<<dim3(512), dim3(256), 0, stream>>>(Zb, K2b, V2T, Ob, 2);
    gemmb(stream, 64, Ob, WT + wt_cao, WT + wt_cao, ca_bo, ca_bo, 1 << 30,
          Z, nullptr, Qb, nullptr, nullptr, 1, 4096, 512, 512, 1.f, 0, 0);

    sgemm4(stream, TEMB, tm_W1, tm_b1, TM1, SKP, 2048, 512, 1);
    sgemm4(stream, TM1, tm_W2, tm_b2, T4, SKP, 2048, 2048, 0);

    gemmb(stream, 64, Qb, WT + wt_in, WT + wt_in, in_b, in_b, 1 << 30,
          nullptr, H2, H2b, nullptr, nullptr, 1, 4096, 1024, 512, 1.f, 0, 0);
    for (int i = 0; i < 2; ++i) {
        sgemm4(stream, T4, film_W + (size_t)i * 4194304, film_b + i * 2048,
               FILM, SKP, 2048, 2048, 0);
        gemmb(stream, 64, H2b, WT + wt_res1 + (size_t)i * 2097152,
              WT + wt_res1 + (size_t)i * 2097152,
              res_b1 + i * 2048, res_b1 + i * 2048, 1 << 30,
              nullptr, nullptr, MIDb, nullptr, nullptr, 1, 4096, 2048, 1024, 1.f, 1, 0);
        gemmb(stream, 64, MIDb, WT + wt_res2 + (size_t)i * 2097152,
              WT + wt_res2 + (size_t)i * 2097152,
              res_b2 + i * 1024, res_b2 + i * 1024, 1 << 30,
              nullptr, Z2, nullptr, nullptr, nullptr, 1, 4096, 1024, 2048, 1.f, 0, 0);
        ln_kernel<<<4096, 256, 0, stream>>>(H2, Z2, rls + i * 1024, rlb + i * 1024,
                                            H2, H2b, 1024, FILM, 1024, 0);
    }

    gemmb(stream, 64, H2b, WT + wt_out, WT + wt_out, out_b, out_b, 1 << 30,
          nullptr, out, nullptr, nullptr, nullptr, 1, 4096, 256, 1024, 1.f, 0, 0);
}